// Round 4
// baseline (266.700 us; speedup 1.0000x reference)
//
#include <hip/hip_runtime.h>
#include <hip/hip_bf16.h>
#include <cmath>

#define H 8
#define D 128
#define HD 1024            // H*D
#define NMAX 1024
#define BS 32
#define NB 32
#define S_SEL 8
#define CHUNK 8            // kb blocks per slc_attn workgroup
#define MC 4               // max chunks per mtile (ceil(32/CHUNK))
#define KP 140             // K LDS row pitch (shorts): kills b128 bank conflicts (r3 evidence)
#define SCALE 0.08838834764831845f   // 1/sqrt(128)
#define SENT -3.0e38f

typedef __attribute__((ext_vector_type(8))) short short8;   // 8 bf16 = 4 VGPRs
typedef __attribute__((ext_vector_type(4))) float f32x4;    // MFMA acc

#define MFMA16(a, b, c) __builtin_amdgcn_mfma_f32_16x16x32_bf16(a, b, c, 0, 0, 0)

__device__ __forceinline__ float silu(float x) {
    return x / (1.f + expf(-x));
}
__device__ __forceinline__ unsigned short f2bf(float x) {
    return __builtin_bit_cast(unsigned short, __float2bfloat16(x));
}
__device__ __forceinline__ float bfup(unsigned short b) {
    unsigned u = (unsigned)b << 16;
    return __builtin_bit_cast(float, u);
}
// 3-term bf16 split: x ~= b0 + b1 + b2 with |err| ~ 2^-27 |x|
__device__ __forceinline__ void split3(float x, unsigned short& b0,
                                       unsigned short& b1, unsigned short& b2) {
    b0 = f2bf(x);
    float r1 = x - bfup(b0);
    b1 = f2bf(r1);
    float r2 = r1 - bfup(b1);
    b2 = f2bf(r2);
}

// ---------------------------------------------------------------------------
// K1 prep: per (b,h,nt) 32-token block:
//   - kb16[tok][h][d]   : bf16 copy of K (straight convert, coalesced)
//   - vt_blk[bh][nt][d][j]: bf16 V^T in 8KB contiguous blocks (LDS transpose)
//   - g[b,m,h,{0,1}]    : gates (8-lane reduction, lanes share (tok,h))
//   - kc0/1/2[bh][nt][d]: split3 bf16 planes of the K block-mean (fused-in
//     compress; bit-identical to fp32 mean + split3)
//   - vt_cmp[bh][d][nt] : bf16 V block-mean, transposed
// Invalid blocks (nt*BS >= len) zero their kc/vt_cmp slots (NaN safety).
// ---------------------------------------------------------------------------
__global__ __launch_bounds__(256) void prep_kernel(
    const float* __restrict__ q, const float* __restrict__ k,
    const float* __restrict__ v, const float* __restrict__ Wg,
    const float* __restrict__ bg, const int* __restrict__ offs,
    unsigned short* __restrict__ kb16, unsigned short* __restrict__ vt_blk,
    float* __restrict__ g, unsigned short* __restrict__ kc0,
    unsigned short* __restrict__ kc1, unsigned short* __restrict__ kc2,
    unsigned short* __restrict__ vt_cmp) {
    int x = blockIdx.x;
    int nt = x & (NB - 1);
    int h = (x >> 5) & 7;
    int b = x >> 8;
    int o0 = offs[b];
    int len = offs[b + 1] - o0;
    int tid = threadIdx.x;
    size_t bh = (size_t)(b * H + h);
    if (nt * BS >= len) {
        if (tid < 128) {
            kc0[(bh * NB + nt) * 128 + tid] = 0;
            kc1[(bh * NB + nt) * 128 + tid] = 0;
            kc2[(bh * NB + nt) * 128 + tid] = 0;
            vt_cmp[(bh * 128 + tid) * NB + nt] = 0;
        }
        return;
    }

    __shared__ __align__(16) unsigned short tile[128 * 40];
    __shared__ float redK[4][128];
    __shared__ float redV[4][128];
    int j = tid >> 3, dc = tid & 7;
    int w = tid >> 6, lane = tid & 63;
    size_t base = (size_t)(o0 + nt * BS + j) * HD + h * D + dc * 16;

    // K -> kb16 (bf16, same layout) + block-mean partial
    {
        float xv[16];
        *(float4*)(xv + 0)  = *(const float4*)(k + base);
        *(float4*)(xv + 4)  = *(const float4*)(k + base + 4);
        *(float4*)(xv + 8)  = *(const float4*)(k + base + 8);
        *(float4*)(xv + 12) = *(const float4*)(k + base + 12);
        short8 lo, hi;
#pragma unroll
        for (int i = 0; i < 8; i++) { lo[i] = (short)f2bf(xv[i]); hi[i] = (short)f2bf(xv[8 + i]); }
        *(short8*)(kb16 + base) = lo;
        *(short8*)(kb16 + base + 8) = hi;
        // butterfly over the wave's 8 j-lanes (lane bits 3,4,5)
#pragma unroll
        for (int i = 0; i < 16; i++) {
            float s = xv[i];
            s += __shfl_xor(s, 8); s += __shfl_xor(s, 16); s += __shfl_xor(s, 32);
            if (lane < 8) redK[w][lane * 16 + i] = s;
        }
    }
    // V -> LDS transpose tile[d][j] + block-mean partial
    {
        float xv[16];
        *(float4*)(xv + 0)  = *(const float4*)(v + base);
        *(float4*)(xv + 4)  = *(const float4*)(v + base + 4);
        *(float4*)(xv + 8)  = *(const float4*)(v + base + 8);
        *(float4*)(xv + 12) = *(const float4*)(v + base + 12);
#pragma unroll
        for (int i = 0; i < 16; i++) tile[(dc * 16 + i) * 40 + j] = f2bf(xv[i]);
#pragma unroll
        for (int i = 0; i < 16; i++) {
            float s = xv[i];
            s += __shfl_xor(s, 8); s += __shfl_xor(s, 16); s += __shfl_xor(s, 32);
            if (lane < 8) redV[w][lane * 16 + i] = s;
        }
    }
    // gates (dot over this thread's 16 dims, reduce across 8 dc-lanes)
    {
        float xv[16];
        *(float4*)(xv + 0)  = *(const float4*)(q + base);
        *(float4*)(xv + 4)  = *(const float4*)(q + base + 4);
        *(float4*)(xv + 8)  = *(const float4*)(q + base + 8);
        *(float4*)(xv + 12) = *(const float4*)(q + base + 12);
        float p0 = 0.f, p1 = 0.f;
#pragma unroll
        for (int i = 0; i < 16; i++) {
            int wb = (h * D + dc * 16 + i) * 3;
            p0 += xv[i] * Wg[wb + 0];
            p1 += xv[i] * Wg[wb + 1];
        }
#pragma unroll
        for (int off = 4; off > 0; off >>= 1) {
            p0 += __shfl_xor(p0, off);
            p1 += __shfl_xor(p1, off);
        }
        if (dc == 0) {
            float g0 = 1.f / (1.f + expf(-(p0 + bg[h * 3 + 0])));
            float g1 = 1.f / (1.f + expf(-(p1 + bg[h * 3 + 1])));
            float* gp = g + (size_t)((b * NMAX + nt * BS + j) * H + h) * 2;
            gp[0] = g0; gp[1] = g1;
        }
    }
    __syncthreads();
    // tile -> vt_blk (contiguous 8KB per (bh,nt))
    {
        int d = tid >> 1, hf = tid & 1;
        short8 a = *(const short8*)(tile + d * 40 + hf * 16);
        short8 c = *(const short8*)(tile + d * 40 + hf * 16 + 8);
        size_t ob = ((bh * NB + nt) * 128 + (size_t)d) * 32 + hf * 16;
        *(short8*)(vt_blk + ob) = a;
        *(short8*)(vt_blk + ob + 8) = c;
    }
    // means -> kc planes / vt_cmp
    if (tid < 128) {
        int d = tid;
        const float inv = 1.f / 32.f;
        float km = (redK[0][d] + redK[1][d] + redK[2][d] + redK[3][d]) * inv;
        float vm = (redV[0][d] + redV[1][d] + redV[2][d] + redV[3][d]) * inv;
        unsigned short e0, e1, e2;
        split3(km, e0, e1, e2);
        kc0[(bh * NB + nt) * 128 + d] = e0;
        kc1[(bh * NB + nt) * 128 + d] = e1;
        kc2[(bh * NB + nt) * 128 + d] = e2;
        vt_cmp[(bh * 128 + d) * NB + nt] = f2bf(vm);
    }
}

// ---------------------------------------------------------------------------
// K3a: compressed attention + top-8 selection, ONE 32-row q-block per WG.
// Staging is pure copies of precomputed bf16 planes (split3 done once in
// prep). 3-plane split-bf16 MFMA QK (fp32-equivalent selection scores),
// silu -> o_cmp PV, top-8 -> ms_g (global bitmask per row).
// MFMA layouts (m89/m120): A[m=lane&15][k=quad*8+j]; C/D col=lane&15,
// row=quad*4+reg.
// ---------------------------------------------------------------------------
__global__ __launch_bounds__(256) void cmp_attn(
    const float* __restrict__ q, const unsigned short* __restrict__ kc0,
    const unsigned short* __restrict__ kc1, const unsigned short* __restrict__ kc2,
    const unsigned short* __restrict__ vt_cmp, const float* __restrict__ g,
    const int* __restrict__ offs, unsigned* __restrict__ ms_g,
    float* __restrict__ o_cmp_j) {
    int x = blockIdx.x;                 // (b*H + h)*NB + qblk
    int qblk = x & (NB - 1);
    int h = (x >> 5) & 7;
    int b = x >> 8;
    int o0 = offs[b];
    int len = offs[b + 1] - o0;
    if (qblk * BS >= len) return;
    size_t bh = (size_t)(b * H + h);

    // pool: R0/R1/R2 k_cmp planes (32x136), R3 v_cmp^T (128x40), Ps (32x40)
    __shared__ __align__(16) unsigned short pool[19456];
    __shared__ float Ss[32 * 33];
    unsigned short* R0 = pool;           // 4352
    unsigned short* R1 = pool + 4352;    // 4352
    unsigned short* R2 = pool + 8704;    // 4352
    unsigned short* R3 = pool + 13056;   // 5120
    unsigned short* Ps = pool + 18176;   // 1280 (32x40)

    int tid = threadIdx.x;
    int w = tid >> 6, lane = tid & 63;
    int r = lane & 15, quad = lane >> 4;
    int mt = w >> 1, jt = w & 1;        // row-half / col-half quadrant
    int stg_j = tid >> 3, stg_dc = tid & 7;

    // ---- stage kc planes + vt_cmp (plain bf16 copies) ----
    {
        size_t src = (bh * NB + stg_j) * 128 + stg_dc * 16;
        int ofs = stg_j * 136 + stg_dc * 16;
        short8 a0 = *(const short8*)(kc0 + src);
        short8 b0 = *(const short8*)(kc0 + src + 8);
        short8 a1 = *(const short8*)(kc1 + src);
        short8 b1 = *(const short8*)(kc1 + src + 8);
        short8 a2 = *(const short8*)(kc2 + src);
        short8 b2 = *(const short8*)(kc2 + src + 8);
        *(short8*)(R0 + ofs) = a0; *(short8*)(R0 + ofs + 8) = b0;
        *(short8*)(R1 + ofs) = a1; *(short8*)(R1 + ofs + 8) = b1;
        *(short8*)(R2 + ofs) = a2; *(short8*)(R2 + ofs + 8) = b2;
        int d = tid >> 1, hf = tid & 1;
        short8 vv = *(const short8*)(vt_cmp + (bh * 128 + d) * NB + hf * 16);
        short8 vw = *(const short8*)(vt_cmp + (bh * 128 + d) * NB + hf * 16 + 8);
        *(short8*)(R3 + d * 40 + hf * 16) = vv;
        *(short8*)(R3 + d * 40 + hf * 16 + 8) = vw;
    }
    __syncthreads();

    // ---- Q fragments (3 planes), QK ----
    short8 qf0[4], qf1[4], qf2[4];
    {
        const float* qrow = q + (size_t)(o0 + qblk * BS + mt * 16 + r) * HD + h * D;
#pragma unroll
        for (int s = 0; s < 4; s++) {
            const float* p0 = qrow + s * 32 + quad * 8;
            float xv[8];
            *(float4*)(xv) = *(const float4*)p0;
            *(float4*)(xv + 4) = *(const float4*)(p0 + 4);
            short8 f0, f1, f2;
#pragma unroll
            for (int i = 0; i < 8; i++) {
                unsigned short e0, e1, e2;
                split3(xv[i], e0, e1, e2);
                f0[i] = (short)e0; f1[i] = (short)e1; f2[i] = (short)e2;
            }
            qf0[s] = f0; qf1[s] = f1; qf2[s] = f2;
        }
    }
    // QK: 6 product rounds, small terms first
    f32x4 sv = (f32x4){0.f, 0.f, 0.f, 0.f};
#pragma unroll
    for (int s = 0; s < 4; s++) {
        int ofs = (jt * 16 + r) * 136 + s * 32 + quad * 8;
        short8 k0 = *(const short8*)(R0 + ofs);
        short8 k1 = *(const short8*)(R1 + ofs);
        short8 k2 = *(const short8*)(R2 + ofs);
        sv = MFMA16(qf1[s], k1, sv);
        sv = MFMA16(qf0[s], k2, sv);
        sv = MFMA16(qf2[s], k0, sv);
        sv = MFMA16(qf0[s], k1, sv);
        sv = MFMA16(qf1[s], k0, sv);
        sv = MFMA16(qf0[s], k0, sv);
    }
    int colj = jt * 16 + r;
    bool causal = (colj <= qblk);
#pragma unroll
    for (int i = 0; i < 4; i++) {
        int mrow = mt * 16 + quad * 4 + i;      // 0..31
        float sc = sv[i] * SCALE;
        Ss[mrow * 33 + colj] = causal ? sc : SENT;
        Ps[mrow * 40 + colj] = f2bf(causal ? silu(sc) : 0.f);
    }
    __syncthreads();

    // ---- PV -> o_cmp ----
    f32x4 accC[2][2];
#pragma unroll
    for (int a = 0; a < 2; a++)
#pragma unroll
        for (int c = 0; c < 2; c++) accC[a][c] = (f32x4){0.f, 0.f, 0.f, 0.f};
    {
        short8 pf0 = *(const short8*)(Ps + r * 40 + quad * 8);
        short8 pf1 = *(const short8*)(Ps + (16 + r) * 40 + quad * 8);
        short8 vf0 = *(const short8*)(R3 + ((2 * w + 0) * 16 + r) * 40 + quad * 8);
        short8 vf1 = *(const short8*)(R3 + ((2 * w + 1) * 16 + r) * 40 + quad * 8);
        accC[0][0] = MFMA16(pf0, vf0, accC[0][0]);
        accC[0][1] = MFMA16(pf0, vf1, accC[0][1]);
        accC[1][0] = MFMA16(pf1, vf0, accC[1][0]);
        accC[1][1] = MFMA16(pf1, vf1, accC[1][1]);
    }
    // ---- selection -> ms_g ----
    size_t msbase = (bh << 10) + (size_t)qblk * BS;
    if (qblk < S_SEL) {
        if (tid < BS) ms_g[msbase + tid] = (1u << (qblk + 1)) - 1u;
    } else {
        int h2 = lane >> 5, l32 = lane & 31;
#pragma unroll
        for (int pass = 0; pass < 4; pass++) {
            int row = w * 8 + pass * 2 + h2;
            float val = Ss[row * 33 + l32];
            unsigned mask = 0;
            bool taken = false;
            for (int it = 0; it < S_SEL; it++) {
                float vv = taken ? SENT : val;
                int idx = l32;
#pragma unroll
                for (int off = 16; off > 0; off >>= 1) {
                    float ov = __shfl_xor(vv, off);
                    int oi = __shfl_xor(idx, off);
                    if (ov > vv || (ov == vv && oi < idx)) { vv = ov; idx = oi; }
                }
                if (vv > -2.9e38f) {
                    mask |= (1u << idx);
                    if (idx == l32) taken = true;
                }
            }
            if (l32 == 0) ms_g[msbase + row] = mask;
        }
    }
    // ---- epilogue o_cmp ----
#pragma unroll
    for (int mtl = 0; mtl < 2; mtl++) {
#pragma unroll
        for (int i = 0; i < 4; i++) {
            int mrow = mtl * 16 + quad * 4 + i;
            int gm = qblk * BS + mrow;
            float gc = g[(size_t)((b * NMAX + gm) * H + h) * 2];
            float* dst = o_cmp_j + (size_t)(o0 + gm) * HD + h * D;
            dst[(2 * w + 0) * 16 + r] = accC[mtl][0][i] * gc;
            dst[(2 * w + 1) * 16 + r] = accC[mtl][1][i] * gc;
        }
    }
}

// ---------------------------------------------------------------------------
// K3b: selected attention, CHUNKED over kb (round-2 structure, measured
// 67us: K+V double-buffered in LDS, register prefetch one FULL iteration
// ahead, 2 barriers/iter, cross-wave PV). Only change vs r2: K pitch 136
// -> KP=140 (r3 evidence: kills the 2.3M-cycle b128 bank conflicts).
// Block = (b,h,mtile,chunk): 64 q-rows x up to CHUNK=8 kb-blocks,
// fp32 partials -> atomicAdd into pre-zeroed o_slc_j (plain store when
// the whole mtile fits one chunk).
// ---------------------------------------------------------------------------
__global__ __launch_bounds__(256) void slc_attn(
    const float* __restrict__ q, const unsigned short* __restrict__ kb16,
    const unsigned short* __restrict__ vt_blk, const float* __restrict__ g,
    const int* __restrict__ offs, const unsigned* __restrict__ ms_g,
    float* __restrict__ o_slc_j) {
    int x = blockIdx.x;                 // (((b*H + h)*16 + mtile)*MC + chunk)
    int chunk = x & (MC - 1);
    int mtile = (x >> 2) & 15;
    int h = (x >> 6) & 7;
    int b = x >> 9;
    int o0 = offs[b];
    int len = offs[b + 1] - o0;
    if (mtile * 64 >= len) return;      // uniform exit (lens are multiples of 64)
    int qmax = 2 * mtile + 1;
    int kb0 = chunk * CHUNK;
    if (kb0 > qmax) return;
    int kend = min(qmax, kb0 + CHUNK - 1);

    // single pool: Kbuf0|Kbuf1 (32xKP each) | VTbuf0|VTbuf1 (128x40) | Ps (64x40)
    __shared__ __align__(16) unsigned short pool[2 * 32 * KP + 2 * 5120 + 2560];
    __shared__ unsigned Ms[64];
    unsigned short* Kst0 = pool;                      // 4480
    unsigned short* Kst1 = pool + 32 * KP;            // 4480
    unsigned short* Vst0 = pool + 2 * 32 * KP;        // 5120
    unsigned short* Vst1 = pool + 2 * 32 * KP + 5120; // 5120
    unsigned short* Ps   = pool + 2 * 32 * KP + 10240;// 2560

    int tid = threadIdx.x;
    int w = tid >> 6, lane = tid & 63;
    int r = lane & 15, quad = lane >> 4;
    int stg_j = tid >> 3, stg_dc = tid & 7;

    if (tid < 64)
        Ms[tid] = ms_g[((size_t)(b * H + h) << 10) + mtile * 64 + tid];

    // Q fragments (plane 0): wave w -> rows 16w + r
    short8 qs[4];
    {
        const float* qrow = q + (size_t)(o0 + mtile * 64 + w * 16 + r) * HD + h * D;
#pragma unroll
        for (int s = 0; s < 4; s++) {
            const float* p0 = qrow + s * 32 + quad * 8;
            float xv[8];
            *(float4*)(xv) = *(const float4*)p0;
            *(float4*)(xv + 4) = *(const float4*)(p0 + 4);
            short8 f;
#pragma unroll
            for (int i = 0; i < 8; i++) f[i] = (short)f2bf(xv[i]);
            qs[s] = f;
        }
    }
    f32x4 acc[4][2];
#pragma unroll
    for (int a = 0; a < 4; a++)
#pragma unroll
        for (int c = 0; c < 2; c++) acc[a][c] = (f32x4){0.f, 0.f, 0.f, 0.f};

    size_t vtbase = (size_t)((b * H + h) * NB) * 4096;
    int vd = tid >> 1, vhf = tid & 1;

    // prestage kb0 into Kst0 / Vst0
    {
        const unsigned short* ks = kb16 + (size_t)(o0 + kb0 * BS + stg_j) * HD + h * D + stg_dc * 16;
        short8 k0 = *(const short8*)ks;
        short8 k1 = *(const short8*)(ks + 8);
        *(short8*)(Kst0 + stg_j * KP + stg_dc * 16) = k0;
        *(short8*)(Kst0 + stg_j * KP + stg_dc * 16 + 8) = k1;
        const unsigned short* vs = vt_blk + vtbase + (size_t)kb0 * 4096 + tid * 16;
        short8 v0 = *(const short8*)vs;
        short8 v1 = *(const short8*)(vs + 8);
        *(short8*)(Vst0 + vd * 40 + vhf * 16) = v0;
        *(short8*)(Vst0 + vd * 40 + vhf * 16 + 8) = v1;
    }
    __syncthreads();

    int c = 0;
    for (int kb = kb0; kb <= kend; kb++) {
        short8 pk0, pk1, pv0, pv1;
        bool pf = (kb < kend);
        if (pf) {                       // prefetch kb+1 into registers
            const unsigned short* ks = kb16 + (size_t)(o0 + (kb + 1) * BS + stg_j) * HD + h * D + stg_dc * 16;
            pk0 = *(const short8*)ks;
            pk1 = *(const short8*)(ks + 8);
            const unsigned short* vs = vt_blk + vtbase + (size_t)(kb + 1) * 4096 + tid * 16;
            pv0 = *(const short8*)vs;
            pv1 = *(const short8*)(vs + 8);
        }
        // QK: wave w -> rows [16w,16w+16), both j-frags
        unsigned short* K = c ? Kst1 : Kst0;
        f32x4 s0 = (f32x4){0.f, 0.f, 0.f, 0.f};
        f32x4 s1 = (f32x4){0.f, 0.f, 0.f, 0.f};
#pragma unroll
        for (int s = 0; s < 4; s++) {
            short8 kf0 = *(const short8*)(K + r * KP + s * 32 + quad * 8);
            short8 kf1 = *(const short8*)(K + (16 + r) * KP + s * 32 + quad * 8);
            s0 = MFMA16(qs[s], kf0, s0);
            s1 = MFMA16(qs[s], kf1, s1);
        }
#pragma unroll
        for (int jf = 0; jf < 2; jf++) {
            f32x4 svv = jf ? s1 : s0;
            int colj = jf * 16 + r;
            int kpos = kb * BS + colj;
#pragma unroll
            for (int i = 0; i < 4; i++) {
                int mrow = w * 16 + quad * 4 + i;
                int mpos = mtile * 64 + mrow;
                float p = (((Ms[mrow] >> kb) & 1u) && (kpos <= mpos))
                          ? silu(svv[i] * SCALE) : 0.f;
                Ps[mrow * 40 + colj] = f2bf(p);
            }
        }
        __syncthreads();
        // PV: wave w -> d-frags {2w, 2w+1}, all 4 m-frags
        unsigned short* V = c ? Vst1 : Vst0;
        {
            short8 vf0 = *(const short8*)(V + ((2 * w + 0) * 16 + r) * 40 + quad * 8);
            short8 vf1 = *(const short8*)(V + ((2 * w + 1) * 16 + r) * 40 + quad * 8);
#pragma unroll
            for (int mf = 0; mf < 4; mf++) {
                short8 pf8 = *(const short8*)(Ps + (mf * 16 + r) * 40 + quad * 8);
                acc[mf][0] = MFMA16(pf8, vf0, acc[mf][0]);
                acc[mf][1] = MFMA16(pf8, vf1, acc[mf][1]);
            }
        }
        if (pf) {                       // commit prefetch into the other buffer
            unsigned short* Kn = c ? Kst0 : Kst1;
            unsigned short* Vn = c ? Vst0 : Vst1;
            *(short8*)(Kn + stg_j * KP + stg_dc * 16) = pk0;
            *(short8*)(Kn + stg_j * KP + stg_dc * 16 + 8) = pk1;
            *(short8*)(Vn + vd * 40 + vhf * 16) = pv0;
            *(short8*)(Vn + vd * 40 + vhf * 16 + 8) = pv1;
        }
        __syncthreads();
        c ^= 1;
    }

    // epilogue: partial o_slc (gated); single-chunk tiles store, else atomic
    bool single = (qmax < CHUNK);
#pragma unroll
    for (int mf = 0; mf < 4; mf++) {
#pragma unroll
        for (int i = 0; i < 4; i++) {
            int mrow = mf * 16 + quad * 4 + i;
            int gm = mtile * 64 + mrow;
            float gs = g[(size_t)((b * NMAX + gm) * H + h) * 2 + 1];
            float* dst = o_slc_j + (size_t)(o0 + gm) * HD + h * D;
            float v0 = acc[mf][0][i] * gs;
            float v1 = acc[mf][1][i] * gs;
            if (single) {
                dst[(2 * w + 0) * 16 + r] = v0;
                dst[(2 * w + 1) * 16 + r] = v1;
            } else {
                atomicAdd(dst + (2 * w + 0) * 16 + r, v0);
                atomicAdd(dst + (2 * w + 1) * 16 + r, v1);
            }
        }
    }
}

// ---------------------------------------------------------------------------
// K4: padded qp, kp (outputs 1,2) — runs AFTER attention (kp region may have
// been used as scratch for kb16/vt_blk when ws is small)
// ---------------------------------------------------------------------------
__global__ __launch_bounds__(256) void pad_qk_kernel(
    const float* __restrict__ q, const float* __restrict__ k,
    const int* __restrict__ offs,
    float* __restrict__ qp, float* __restrict__ kp) {
    int idx = blockIdx.x * 256 + threadIdx.x;       // float4 index over [B,n,H,D/4]
    int d4 = idx & 31;
    int h  = (idx >> 5) & 7;
    int m  = (idx >> 8) & (NMAX - 1);
    int b  = idx >> 18;
    int o0 = offs[b];
    int len = offs[b + 1] - o0;
    float4 qv = make_float4(0.f, 0.f, 0.f, 0.f);
    float4 kv = qv;
    if (m < len) {
        size_t src = (size_t)(o0 + m) * HD + h * D + d4 * 4;
        qv = *(const float4*)(q + src);
        kv = *(const float4*)(k + src);
    }
    *(float4*)(qp + (size_t)idx * 4) = qv;
    *(float4*)(kp + (size_t)idx * 4) = kv;
}

// ---------------------------------------------------------------------------
// K5: LayerNorm(1024) per stream, gate by u, sum -> out (oc may alias out)
// ---------------------------------------------------------------------------
__global__ __launch_bounds__(256) void ln_combine_kernel(
    const float* __restrict__ oc, const float* __restrict__ os,
    const float* __restrict__ u, float* __restrict__ out) {
    int t = blockIdx.x, tid = threadIdx.x;
    size_t base = (size_t)t * HD;
    float4 xc = *(const float4*)(oc + base + tid * 4);
    float4 xs = *(const float4*)(os + base + tid * 4);
    float4 uu = *(const float4*)(u + base + tid * 4);
    float s_c = xc.x + xc.y + xc.z + xc.w;
    float q_c = xc.x * xc.x + xc.y * xc.y + xc.z * xc.z + xc.w * xc.w;
    float s_s = xs.x + xs.y + xs.z + xs.w;
    float q_s = xs.x * xs.x + xs.y * xs.y + xs.z * xs.z + xs.w * xs.w;
#pragma unroll
    for (int off = 32; off > 0; off >>= 1) {
        s_c += __shfl_xor(s_c, off); q_c += __shfl_xor(q_c, off);
        s_s += __shfl_xor(s_s, off); q_s += __shfl_xor(q_s, off);
    }
    __shared__ float red[4][4];
    int w = tid >> 6, lane = tid & 63;
    if (lane == 0) {
        red[w][0] = s_c; red[w][1] = q_c; red[w][2] = s_s; red[w][3] = q_s;
    }
    __syncthreads();
    float tsc = red[0][0] + red[1][0] + red[2][0] + red[3][0];
    float tqc = red[0][1] + red[1][1] + red[2][1] + red[3][1];
    float tss = red[0][2] + red[1][2] + red[2][2] + red[3][2];
    float tqs = red[0][3] + red[1][3] + red[2][3] + red[3][3];
    const float inv = 1.f / 1024.f;
    float mc = tsc * inv, vc = tqc * inv - mc * mc;
    float ms = tss * inv, vs = tqs * inv - ms * ms;
    float rc = rsqrtf(vc + 1e-5f), rs = rsqrtf(vs + 1e-5f);
    float4 o;
    o.x = ((xc.x - mc) * rc + (xs.x - ms) * rs) * uu.x;
    o.y = ((xc.y - mc) * rc + (xs.y - ms) * rs) * uu.y;
    o.z = ((xc.z - mc) * rc + (xs.z - ms) * rs) * uu.z;
    o.w = ((xc.w - mc) * rc + (xs.w - ms) * rs) * uu.w;
    *(float4*)(out + base + tid * 4) = o;
}

// ---------------------------------------------------------------------------
extern "C" void kernel_launch(void* const* d_in, const int* in_sizes, int n_in,
                              void* d_out, int out_size, void* d_ws, size_t ws_size,
                              hipStream_t stream) {
    const float* q  = (const float*)d_in[0];
    const float* k  = (const float*)d_in[1];
    const float* v  = (const float*)d_in[2];
    const float* u  = (const float*)d_in[3];
    const float* Wg = (const float*)d_in[4];
    const float* bg = (const float*)d_in[5];
    const int* offs = (const int*)d_in[6];   // int32 (jnp default, x64 off)

    int B = in_sizes[6] - 1;
    int T = in_sizes[0] / HD;

    float* out = (float*)d_out;
    float* qp  = out + (size_t)T * HD;
    float* kp  = qp + (size_t)B * NMAX * HD;

    float* o_cmp_j = out;   // aliases final out (safe: see ln_combine)

    size_t plane = (size_t)B * H * NB * 128;        // elems per kc plane
    char* w = (char*)d_ws;
    unsigned short* kc0 = (unsigned short*)w;  w += plane * 2;
    unsigned short* kc1 = (unsigned short*)w;  w += plane * 2;
    unsigned short* kc2 = (unsigned short*)w;  w += plane * 2;
    unsigned short* vt_cmp = (unsigned short*)w; w += plane * 2;
    float* g     = (float*)w;            w += (size_t)B * NMAX * H * 2 * 4;
    unsigned* ms_g = (unsigned*)w;       w += (size_t)B * H * NMAX * 4;
    float* o_slc_j = (float*)w;          w += (size_t)T * HD * 4;

    // bf16 scratch: prefer ws tail; else use kp output region (rewritten after)
    size_t kb16_bytes = (size_t)T * HD * 2;
    size_t vt_bytes   = (size_t)B * H * NB * 128 * 32 * 2;
    size_t used = (size_t)(w - (char*)d_ws);
    char* scr = (used + kb16_bytes + vt_bytes <= ws_size) ? w : (char*)kp;
    unsigned short* kb16  = (unsigned short*)scr;
    unsigned short* vt_blk = (unsigned short*)(scr + kb16_bytes);

    int prepBlocks = B * H * NB;
    int cmpAttnBlocks = B * H * NB;
    int slcBlocks  = B * H * 16 * MC;
    int padBlocks  = (B * NMAX * HD / 4) / 256;

    (void)hipMemsetAsync(o_slc_j, 0, (size_t)T * HD * sizeof(float), stream);
    prep_kernel<<<prepBlocks, 256, 0, stream>>>(q, k, v, Wg, bg, offs, kb16, vt_blk,
                                                g, kc0, kc1, kc2, vt_cmp);
    cmp_attn<<<cmpAttnBlocks, 256, 0, stream>>>(q, kc0, kc1, kc2, vt_cmp, g,
                                                offs, ms_g, o_cmp_j);
    slc_attn<<<slcBlocks, 256, 0, stream>>>(q, kb16, vt_blk, g, offs, ms_g, o_slc_j);
    pad_qk_kernel<<<padBlocks, 256, 0, stream>>>(q, k, offs, qp, kp);
    ln_combine_kernel<<<T, 256, 0, stream>>>(o_cmp_j, o_slc_j, u, out);
}

// Round 5
// 237.984 us; speedup vs baseline: 1.1207x; 1.1207x over previous
//
#include <hip/hip_runtime.h>
#include <hip/hip_bf16.h>
#include <cmath>

#define H 8
#define D 128
#define HD 1024            // H*D
#define NMAX 1024
#define BS 32
#define NB 32
#define S_SEL 8
#define CHUNK 4            // kb blocks per slc_attn workgroup (more blocks -> hides tail)
#define MC 8               // chunks per mtile (NB/CHUNK)
#define KP 136             // K LDS pitch (shorts). MUST be mult of 8 (16B align for b128!)
#define SCALE 0.08838834764831845f   // 1/sqrt(128)
#define SENT -3.0e38f

typedef __attribute__((ext_vector_type(8))) short short8;   // 8 bf16 = 4 VGPRs
typedef __attribute__((ext_vector_type(4))) float f32x4;    // MFMA acc

#define MFMA16(a, b, c) __builtin_amdgcn_mfma_f32_16x16x32_bf16(a, b, c, 0, 0, 0)

__device__ __forceinline__ float silu(float x) {
    return x / (1.f + expf(-x));
}
__device__ __forceinline__ unsigned short f2bf(float x) {
    return __builtin_bit_cast(unsigned short, __float2bfloat16(x));
}
__device__ __forceinline__ float bfup(unsigned short b) {
    unsigned u = (unsigned)b << 16;
    return __builtin_bit_cast(float, u);
}
// 3-term bf16 split: x ~= b0 + b1 + b2 with |err| ~ 2^-27 |x|
__device__ __forceinline__ void split3(float x, unsigned short& b0,
                                       unsigned short& b1, unsigned short& b2) {
    b0 = f2bf(x);
    float r1 = x - bfup(b0);
    b1 = f2bf(r1);
    float r2 = r1 - bfup(b1);
    b2 = f2bf(r2);
}

// ---------------------------------------------------------------------------
// K1 prep: per (b,h,nt) 32-token block:
//   - kb16[tok][h][d]   : bf16 copy of K (straight convert, coalesced)
//   - vt_blk[bh][nt][d][j]: bf16 V^T in 8KB contiguous blocks (LDS transpose)
//   - g[b,m,h,{0,1}]    : gates (8-lane reduction, lanes share (tok,h))
//   - kc0/1/2[bh][nt][d]: split3 bf16 planes of the K block-mean (fused-in
//     compress; bit-identical to fp32 mean + split3)
//   - vt_cmp[bh][d][nt] : bf16 V block-mean, transposed
// Invalid blocks (nt*BS >= len) zero their kc/vt_cmp slots (NaN safety).
// ---------------------------------------------------------------------------
__global__ __launch_bounds__(256) void prep_kernel(
    const float* __restrict__ q, const float* __restrict__ k,
    const float* __restrict__ v, const float* __restrict__ Wg,
    const float* __restrict__ bg, const int* __restrict__ offs,
    unsigned short* __restrict__ kb16, unsigned short* __restrict__ vt_blk,
    float* __restrict__ g, unsigned short* __restrict__ kc0,
    unsigned short* __restrict__ kc1, unsigned short* __restrict__ kc2,
    unsigned short* __restrict__ vt_cmp) {
    int x = blockIdx.x;
    int nt = x & (NB - 1);
    int h = (x >> 5) & 7;
    int b = x >> 8;
    int o0 = offs[b];
    int len = offs[b + 1] - o0;
    int tid = threadIdx.x;
    size_t bh = (size_t)(b * H + h);
    if (nt * BS >= len) {
        if (tid < 128) {
            kc0[(bh * NB + nt) * 128 + tid] = 0;
            kc1[(bh * NB + nt) * 128 + tid] = 0;
            kc2[(bh * NB + nt) * 128 + tid] = 0;
            vt_cmp[(bh * 128 + tid) * NB + nt] = 0;
        }
        return;
    }

    __shared__ __align__(16) unsigned short tile[128 * 40];
    __shared__ float redK[4][128];
    __shared__ float redV[4][128];
    int j = tid >> 3, dc = tid & 7;
    int w = tid >> 6, lane = tid & 63;
    size_t base = (size_t)(o0 + nt * BS + j) * HD + h * D + dc * 16;

    // K -> kb16 (bf16, same layout) + block-mean partial
    {
        float xv[16];
        *(float4*)(xv + 0)  = *(const float4*)(k + base);
        *(float4*)(xv + 4)  = *(const float4*)(k + base + 4);
        *(float4*)(xv + 8)  = *(const float4*)(k + base + 8);
        *(float4*)(xv + 12) = *(const float4*)(k + base + 12);
        short8 lo, hi;
#pragma unroll
        for (int i = 0; i < 8; i++) { lo[i] = (short)f2bf(xv[i]); hi[i] = (short)f2bf(xv[8 + i]); }
        *(short8*)(kb16 + base) = lo;
        *(short8*)(kb16 + base + 8) = hi;
        // butterfly over the wave's 8 j-lanes (lane bits 3,4,5)
#pragma unroll
        for (int i = 0; i < 16; i++) {
            float s = xv[i];
            s += __shfl_xor(s, 8); s += __shfl_xor(s, 16); s += __shfl_xor(s, 32);
            if (lane < 8) redK[w][lane * 16 + i] = s;
        }
    }
    // V -> LDS transpose tile[d][j] + block-mean partial
    {
        float xv[16];
        *(float4*)(xv + 0)  = *(const float4*)(v + base);
        *(float4*)(xv + 4)  = *(const float4*)(v + base + 4);
        *(float4*)(xv + 8)  = *(const float4*)(v + base + 8);
        *(float4*)(xv + 12) = *(const float4*)(v + base + 12);
#pragma unroll
        for (int i = 0; i < 16; i++) tile[(dc * 16 + i) * 40 + j] = f2bf(xv[i]);
#pragma unroll
        for (int i = 0; i < 16; i++) {
            float s = xv[i];
            s += __shfl_xor(s, 8); s += __shfl_xor(s, 16); s += __shfl_xor(s, 32);
            if (lane < 8) redV[w][lane * 16 + i] = s;
        }
    }
    // gates (dot over this thread's 16 dims, reduce across 8 dc-lanes)
    {
        float xv[16];
        *(float4*)(xv + 0)  = *(const float4*)(q + base);
        *(float4*)(xv + 4)  = *(const float4*)(q + base + 4);
        *(float4*)(xv + 8)  = *(const float4*)(q + base + 8);
        *(float4*)(xv + 12) = *(const float4*)(q + base + 12);
        float p0 = 0.f, p1 = 0.f;
#pragma unroll
        for (int i = 0; i < 16; i++) {
            int wb = (h * D + dc * 16 + i) * 3;
            p0 += xv[i] * Wg[wb + 0];
            p1 += xv[i] * Wg[wb + 1];
        }
#pragma unroll
        for (int off = 4; off > 0; off >>= 1) {
            p0 += __shfl_xor(p0, off);
            p1 += __shfl_xor(p1, off);
        }
        if (dc == 0) {
            float g0 = 1.f / (1.f + expf(-(p0 + bg[h * 3 + 0])));
            float g1 = 1.f / (1.f + expf(-(p1 + bg[h * 3 + 1])));
            float* gp = g + (size_t)((b * NMAX + nt * BS + j) * H + h) * 2;
            gp[0] = g0; gp[1] = g1;
        }
    }
    __syncthreads();
    // tile -> vt_blk (contiguous 8KB per (bh,nt))
    {
        int d = tid >> 1, hf = tid & 1;
        short8 a = *(const short8*)(tile + d * 40 + hf * 16);
        short8 c = *(const short8*)(tile + d * 40 + hf * 16 + 8);
        size_t ob = ((bh * NB + nt) * 128 + (size_t)d) * 32 + hf * 16;
        *(short8*)(vt_blk + ob) = a;
        *(short8*)(vt_blk + ob + 8) = c;
    }
    // means -> kc planes / vt_cmp
    if (tid < 128) {
        int d = tid;
        const float inv = 1.f / 32.f;
        float km = (redK[0][d] + redK[1][d] + redK[2][d] + redK[3][d]) * inv;
        float vm = (redV[0][d] + redV[1][d] + redV[2][d] + redV[3][d]) * inv;
        unsigned short e0, e1, e2;
        split3(km, e0, e1, e2);
        kc0[(bh * NB + nt) * 128 + d] = e0;
        kc1[(bh * NB + nt) * 128 + d] = e1;
        kc2[(bh * NB + nt) * 128 + d] = e2;
        vt_cmp[(bh * 128 + d) * NB + nt] = f2bf(vm);
    }
}

// ---------------------------------------------------------------------------
// K3a: compressed attention + top-8 selection, ONE 32-row q-block per WG.
// Staging is pure copies of precomputed bf16 planes (split3 done once in
// prep; non-causal rows skipped — masked out downstream). Selection now
// RANK-BASED: rank_i = #{j: (vj,-j) > (vi,-i)}; top-8 <=> rank<8 — same set
// as iterative max-pick with idx tiebreak, but 31 independent shuffles
// instead of a serial 8x5-step reduce chain.
// MFMA layouts (m89/m120): A[m=lane&15][k=quad*8+j]; C/D col=lane&15,
// row=quad*4+reg.
// ---------------------------------------------------------------------------
__global__ __launch_bounds__(256) void cmp_attn(
    const float* __restrict__ q, const unsigned short* __restrict__ kc0,
    const unsigned short* __restrict__ kc1, const unsigned short* __restrict__ kc2,
    const unsigned short* __restrict__ vt_cmp, const float* __restrict__ g,
    const int* __restrict__ offs, unsigned* __restrict__ ms_g,
    float* __restrict__ o_cmp_j) {
    int x = blockIdx.x;                 // (b*H + h)*NB + qblk
    int qblk = x & (NB - 1);
    int h = (x >> 5) & 7;
    int b = x >> 8;
    int o0 = offs[b];
    int len = offs[b + 1] - o0;
    if (qblk * BS >= len) return;
    size_t bh = (size_t)(b * H + h);

    // pool: R0/R1/R2 k_cmp planes (32x136), R3 v_cmp^T (128x40), Ps (32x40)
    __shared__ __align__(16) unsigned short pool[19456];
    __shared__ float Ss[32 * 33];
    unsigned short* R0 = pool;           // 4352
    unsigned short* R1 = pool + 4352;    // 4352
    unsigned short* R2 = pool + 8704;    // 4352
    unsigned short* R3 = pool + 13056;   // 5120
    unsigned short* Ps = pool + 18176;   // 1280 (32x40)

    int tid = threadIdx.x;
    int w = tid >> 6, lane = tid & 63;
    int r = lane & 15, quad = lane >> 4;
    int mt = w >> 1, jt = w & 1;        // row-half / col-half quadrant
    int stg_j = tid >> 3, stg_dc = tid & 7;

    // ---- stage kc planes (causal rows only) + vt_cmp ----
    if (stg_j <= qblk) {
        size_t src = (bh * NB + stg_j) * 128 + stg_dc * 16;
        int ofs = stg_j * 136 + stg_dc * 16;
        short8 a0 = *(const short8*)(kc0 + src);
        short8 b0 = *(const short8*)(kc0 + src + 8);
        short8 a1 = *(const short8*)(kc1 + src);
        short8 b1 = *(const short8*)(kc1 + src + 8);
        short8 a2 = *(const short8*)(kc2 + src);
        short8 b2 = *(const short8*)(kc2 + src + 8);
        *(short8*)(R0 + ofs) = a0; *(short8*)(R0 + ofs + 8) = b0;
        *(short8*)(R1 + ofs) = a1; *(short8*)(R1 + ofs + 8) = b1;
        *(short8*)(R2 + ofs) = a2; *(short8*)(R2 + ofs + 8) = b2;
    }
    {
        int d = tid >> 1, hf = tid & 1;
        short8 vv = *(const short8*)(vt_cmp + (bh * 128 + d) * NB + hf * 16);
        short8 vw = *(const short8*)(vt_cmp + (bh * 128 + d) * NB + hf * 16 + 8);
        *(short8*)(R3 + d * 40 + hf * 16) = vv;
        *(short8*)(R3 + d * 40 + hf * 16 + 8) = vw;
    }
    __syncthreads();

    // ---- Q fragments (3 planes), QK ----
    short8 qf0[4], qf1[4], qf2[4];
    {
        const float* qrow = q + (size_t)(o0 + qblk * BS + mt * 16 + r) * HD + h * D;
#pragma unroll
        for (int s = 0; s < 4; s++) {
            const float* p0 = qrow + s * 32 + quad * 8;
            float xv[8];
            *(float4*)(xv) = *(const float4*)p0;
            *(float4*)(xv + 4) = *(const float4*)(p0 + 4);
            short8 f0, f1, f2;
#pragma unroll
            for (int i = 0; i < 8; i++) {
                unsigned short e0, e1, e2;
                split3(xv[i], e0, e1, e2);
                f0[i] = (short)e0; f1[i] = (short)e1; f2[i] = (short)e2;
            }
            qf0[s] = f0; qf1[s] = f1; qf2[s] = f2;
        }
    }
    // QK: 6 product rounds, small terms first
    f32x4 sv = (f32x4){0.f, 0.f, 0.f, 0.f};
#pragma unroll
    for (int s = 0; s < 4; s++) {
        int ofs = (jt * 16 + r) * 136 + s * 32 + quad * 8;
        short8 k0 = *(const short8*)(R0 + ofs);
        short8 k1 = *(const short8*)(R1 + ofs);
        short8 k2 = *(const short8*)(R2 + ofs);
        sv = MFMA16(qf1[s], k1, sv);
        sv = MFMA16(qf0[s], k2, sv);
        sv = MFMA16(qf2[s], k0, sv);
        sv = MFMA16(qf0[s], k1, sv);
        sv = MFMA16(qf1[s], k0, sv);
        sv = MFMA16(qf0[s], k0, sv);
    }
    int colj = jt * 16 + r;
    bool causal = (colj <= qblk);
#pragma unroll
    for (int i = 0; i < 4; i++) {
        int mrow = mt * 16 + quad * 4 + i;      // 0..31
        float sc = sv[i] * SCALE;
        Ss[mrow * 33 + colj] = causal ? sc : SENT;
        Ps[mrow * 40 + colj] = f2bf(causal ? silu(sc) : 0.f);
    }
    __syncthreads();

    // ---- PV -> o_cmp ----
    f32x4 accC[2][2];
#pragma unroll
    for (int a = 0; a < 2; a++)
#pragma unroll
        for (int c = 0; c < 2; c++) accC[a][c] = (f32x4){0.f, 0.f, 0.f, 0.f};
    {
        short8 pf0 = *(const short8*)(Ps + r * 40 + quad * 8);
        short8 pf1 = *(const short8*)(Ps + (16 + r) * 40 + quad * 8);
        short8 vf0 = *(const short8*)(R3 + ((2 * w + 0) * 16 + r) * 40 + quad * 8);
        short8 vf1 = *(const short8*)(R3 + ((2 * w + 1) * 16 + r) * 40 + quad * 8);
        accC[0][0] = MFMA16(pf0, vf0, accC[0][0]);
        accC[0][1] = MFMA16(pf0, vf1, accC[0][1]);
        accC[1][0] = MFMA16(pf1, vf0, accC[1][0]);
        accC[1][1] = MFMA16(pf1, vf1, accC[1][1]);
    }
    // ---- selection -> ms_g (rank + ballot) ----
    size_t msbase = (bh << 10) + (size_t)qblk * BS;
    if (qblk < S_SEL) {
        if (tid < BS) ms_g[msbase + tid] = (1u << (qblk + 1)) - 1u;
    } else {
        int h2 = lane >> 5, l32 = lane & 31;
#pragma unroll
        for (int pass = 0; pass < 4; pass++) {
            int row = w * 8 + pass * 2 + h2;
            float val = Ss[row * 33 + l32];
            int cnt = 0;
#pragma unroll
            for (int kk = 1; kk < 32; kk++) {
                int jj = (l32 + kk) & 31;
                float ov = __shfl(val, h2 * 32 + jj);
                if ((ov > val) || (ov == val && jj < l32)) cnt++;
            }
            bool sel = (cnt < S_SEL) && (val > -2.9e38f);
            unsigned long long bal = __ballot(sel);
            unsigned mask = (unsigned)(h2 ? (bal >> 32) : (bal & 0xffffffffULL));
            if (l32 == 0) ms_g[msbase + row] = mask;
        }
    }
    // ---- epilogue o_cmp ----
#pragma unroll
    for (int mtl = 0; mtl < 2; mtl++) {
#pragma unroll
        for (int i = 0; i < 4; i++) {
            int mrow = mtl * 16 + quad * 4 + i;
            int gm = qblk * BS + mrow;
            float gc = g[(size_t)((b * NMAX + gm) * H + h) * 2];
            float* dst = o_cmp_j + (size_t)(o0 + gm) * HD + h * D;
            dst[(2 * w + 0) * 16 + r] = accC[mtl][0][i] * gc;
            dst[(2 * w + 1) * 16 + r] = accC[mtl][1][i] * gc;
        }
    }
}

// ---------------------------------------------------------------------------
// K3b: selected attention — r2 structure verbatim (measured 67us: K+V
// double-buffered LDS, register prefetch one FULL iteration ahead, 2
// barriers/iter, cross-wave PV, KP=136 — 16B-aligned pitch). Changed vs r2:
// CHUNK 8->4, MC 4->8: active blocks 864->1520 (~6 queued/CU) so the 3
// resident blocks stay fed through the tail (r2 Occupancy was 11%).
// fp32 partials -> atomicAdd into pre-zeroed o_slc_j (plain store when the
// whole mtile fits one chunk).
// ---------------------------------------------------------------------------
__global__ __launch_bounds__(256) void slc_attn(
    const float* __restrict__ q, const unsigned short* __restrict__ kb16,
    const unsigned short* __restrict__ vt_blk, const float* __restrict__ g,
    const int* __restrict__ offs, const unsigned* __restrict__ ms_g,
    float* __restrict__ o_slc_j) {
    int x = blockIdx.x;                 // (((b*H + h)*16 + mtile)*MC + chunk)
    int chunk = x & (MC - 1);
    int mtile = (x >> 3) & 15;
    int h = (x >> 7) & 7;
    int b = x >> 10;
    int o0 = offs[b];
    int len = offs[b + 1] - o0;
    if (mtile * 64 >= len) return;      // uniform exit (lens are multiples of 64)
    int qmax = 2 * mtile + 1;
    int kb0 = chunk * CHUNK;
    if (kb0 > qmax) return;
    int kend = min(qmax, kb0 + CHUNK - 1);

    // single pool: Kbuf0|Kbuf1 (32xKP) | VTbuf0|VTbuf1 (128x40) | Ps (64x40)
    __shared__ __align__(16) unsigned short pool[2 * 32 * KP + 2 * 5120 + 2560];
    __shared__ unsigned Ms[64];
    unsigned short* Kst0 = pool;                      // 4352
    unsigned short* Kst1 = pool + 32 * KP;            // 4352
    unsigned short* Vst0 = pool + 2 * 32 * KP;        // 5120
    unsigned short* Vst1 = pool + 2 * 32 * KP + 5120; // 5120
    unsigned short* Ps   = pool + 2 * 32 * KP + 10240;// 2560

    int tid = threadIdx.x;
    int w = tid >> 6, lane = tid & 63;
    int r = lane & 15, quad = lane >> 4;
    int stg_j = tid >> 3, stg_dc = tid & 7;

    if (tid < 64)
        Ms[tid] = ms_g[((size_t)(b * H + h) << 10) + mtile * 64 + tid];

    // Q fragments (plane 0): wave w -> rows 16w + r
    short8 qs[4];
    {
        const float* qrow = q + (size_t)(o0 + mtile * 64 + w * 16 + r) * HD + h * D;
#pragma unroll
        for (int s = 0; s < 4; s++) {
            const float* p0 = qrow + s * 32 + quad * 8;
            float xv[8];
            *(float4*)(xv) = *(const float4*)p0;
            *(float4*)(xv + 4) = *(const float4*)(p0 + 4);
            short8 f;
#pragma unroll
            for (int i = 0; i < 8; i++) f[i] = (short)f2bf(xv[i]);
            qs[s] = f;
        }
    }
    f32x4 acc[4][2];
#pragma unroll
    for (int a = 0; a < 4; a++)
#pragma unroll
        for (int c = 0; c < 2; c++) acc[a][c] = (f32x4){0.f, 0.f, 0.f, 0.f};

    size_t vtbase = (size_t)((b * H + h) * NB) * 4096;
    int vd = tid >> 1, vhf = tid & 1;

    // prestage kb0 into Kst0 / Vst0
    {
        const unsigned short* ks = kb16 + (size_t)(o0 + kb0 * BS + stg_j) * HD + h * D + stg_dc * 16;
        short8 k0 = *(const short8*)ks;
        short8 k1 = *(const short8*)(ks + 8);
        *(short8*)(Kst0 + stg_j * KP + stg_dc * 16) = k0;
        *(short8*)(Kst0 + stg_j * KP + stg_dc * 16 + 8) = k1;
        const unsigned short* vs = vt_blk + vtbase + (size_t)kb0 * 4096 + tid * 16;
        short8 v0 = *(const short8*)vs;
        short8 v1 = *(const short8*)(vs + 8);
        *(short8*)(Vst0 + vd * 40 + vhf * 16) = v0;
        *(short8*)(Vst0 + vd * 40 + vhf * 16 + 8) = v1;
    }
    __syncthreads();

    int c = 0;
    for (int kb = kb0; kb <= kend; kb++) {
        short8 pk0, pk1, pv0, pv1;
        bool pf = (kb < kend);
        if (pf) {                       // prefetch kb+1 into registers
            const unsigned short* ks = kb16 + (size_t)(o0 + (kb + 1) * BS + stg_j) * HD + h * D + stg_dc * 16;
            pk0 = *(const short8*)ks;
            pk1 = *(const short8*)(ks + 8);
            const unsigned short* vs = vt_blk + vtbase + (size_t)(kb + 1) * 4096 + tid * 16;
            pv0 = *(const short8*)vs;
            pv1 = *(const short8*)(vs + 8);
        }
        // QK: wave w -> rows [16w,16w+16), both j-frags
        unsigned short* K = c ? Kst1 : Kst0;
        f32x4 s0 = (f32x4){0.f, 0.f, 0.f, 0.f};
        f32x4 s1 = (f32x4){0.f, 0.f, 0.f, 0.f};
#pragma unroll
        for (int s = 0; s < 4; s++) {
            short8 kf0 = *(const short8*)(K + r * KP + s * 32 + quad * 8);
            short8 kf1 = *(const short8*)(K + (16 + r) * KP + s * 32 + quad * 8);
            s0 = MFMA16(qs[s], kf0, s0);
            s1 = MFMA16(qs[s], kf1, s1);
        }
#pragma unroll
        for (int jf = 0; jf < 2; jf++) {
            f32x4 svv = jf ? s1 : s0;
            int colj = jf * 16 + r;
            int kpos = kb * BS + colj;
#pragma unroll
            for (int i = 0; i < 4; i++) {
                int mrow = w * 16 + quad * 4 + i;
                int mpos = mtile * 64 + mrow;
                float p = (((Ms[mrow] >> kb) & 1u) && (kpos <= mpos))
                          ? silu(svv[i] * SCALE) : 0.f;
                Ps[mrow * 40 + colj] = f2bf(p);
            }
        }
        __syncthreads();
        // PV: wave w -> d-frags {2w, 2w+1}, all 4 m-frags
        unsigned short* V = c ? Vst1 : Vst0;
        {
            short8 vf0 = *(const short8*)(V + ((2 * w + 0) * 16 + r) * 40 + quad * 8);
            short8 vf1 = *(const short8*)(V + ((2 * w + 1) * 16 + r) * 40 + quad * 8);
#pragma unroll
            for (int mf = 0; mf < 4; mf++) {
                short8 pf8 = *(const short8*)(Ps + (mf * 16 + r) * 40 + quad * 8);
                acc[mf][0] = MFMA16(pf8, vf0, acc[mf][0]);
                acc[mf][1] = MFMA16(pf8, vf1, acc[mf][1]);
            }
        }
        if (pf) {                       // commit prefetch into the other buffer
            unsigned short* Kn = c ? Kst0 : Kst1;
            unsigned short* Vn = c ? Vst0 : Vst1;
            *(short8*)(Kn + stg_j * KP + stg_dc * 16) = pk0;
            *(short8*)(Kn + stg_j * KP + stg_dc * 16 + 8) = pk1;
            *(short8*)(Vn + vd * 40 + vhf * 16) = pv0;
            *(short8*)(Vn + vd * 40 + vhf * 16 + 8) = pv1;
        }
        __syncthreads();
        c ^= 1;
    }

    // epilogue: partial o_slc (gated); single-chunk tiles store, else atomic
    bool single = (qmax < CHUNK);
#pragma unroll
    for (int mf = 0; mf < 4; mf++) {
#pragma unroll
        for (int i = 0; i < 4; i++) {
            int mrow = mf * 16 + quad * 4 + i;
            int gm = mtile * 64 + mrow;
            float gs = g[(size_t)((b * NMAX + gm) * H + h) * 2 + 1];
            float* dst = o_slc_j + (size_t)(o0 + gm) * HD + h * D;
            float v0 = acc[mf][0][i] * gs;
            float v1 = acc[mf][1][i] * gs;
            if (single) {
                dst[(2 * w + 0) * 16 + r] = v0;
                dst[(2 * w + 1) * 16 + r] = v1;
            } else {
                atomicAdd(dst + (2 * w + 0) * 16 + r, v0);
                atomicAdd(dst + (2 * w + 1) * 16 + r, v1);
            }
        }
    }
}

// ---------------------------------------------------------------------------
// K4: padded qp, kp (outputs 1,2) — runs AFTER attention (kp region may have
// been used as scratch for kb16/vt_blk when ws is small)
// ---------------------------------------------------------------------------
__global__ __launch_bounds__(256) void pad_qk_kernel(
    const float* __restrict__ q, const float* __restrict__ k,
    const int* __restrict__ offs,
    float* __restrict__ qp, float* __restrict__ kp) {
    int idx = blockIdx.x * 256 + threadIdx.x;       // float4 index over [B,n,H,D/4]
    int d4 = idx & 31;
    int h  = (idx >> 5) & 7;
    int m  = (idx >> 8) & (NMAX - 1);
    int b  = idx >> 18;
    int o0 = offs[b];
    int len = offs[b + 1] - o0;
    float4 qv = make_float4(0.f, 0.f, 0.f, 0.f);
    float4 kv = qv;
    if (m < len) {
        size_t src = (size_t)(o0 + m) * HD + h * D + d4 * 4;
        qv = *(const float4*)(q + src);
        kv = *(const float4*)(k + src);
    }
    *(float4*)(qp + (size_t)idx * 4) = qv;
    *(float4*)(kp + (size_t)idx * 4) = kv;
}

// ---------------------------------------------------------------------------
// K5: LayerNorm(1024) per stream, gate by u, sum -> out (oc may alias out)
// ---------------------------------------------------------------------------
__global__ __launch_bounds__(256) void ln_combine_kernel(
    const float* __restrict__ oc, const float* __restrict__ os,
    const float* __restrict__ u, float* __restrict__ out) {
    int t = blockIdx.x, tid = threadIdx.x;
    size_t base = (size_t)t * HD;
    float4 xc = *(const float4*)(oc + base + tid * 4);
    float4 xs = *(const float4*)(os + base + tid * 4);
    float4 uu = *(const float4*)(u + base + tid * 4);
    float s_c = xc.x + xc.y + xc.z + xc.w;
    float q_c = xc.x * xc.x + xc.y * xc.y + xc.z * xc.z + xc.w * xc.w;
    float s_s = xs.x + xs.y + xs.z + xs.w;
    float q_s = xs.x * xs.x + xs.y * xs.y + xs.z * xs.z + xs.w * xs.w;
#pragma unroll
    for (int off = 32; off > 0; off >>= 1) {
        s_c += __shfl_xor(s_c, off); q_c += __shfl_xor(q_c, off);
        s_s += __shfl_xor(s_s, off); q_s += __shfl_xor(q_s, off);
    }
    __shared__ float red[4][4];
    int w = tid >> 6, lane = tid & 63;
    if (lane == 0) {
        red[w][0] = s_c; red[w][1] = q_c; red[w][2] = s_s; red[w][3] = q_s;
    }
    __syncthreads();
    float tsc = red[0][0] + red[1][0] + red[2][0] + red[3][0];
    float tqc = red[0][1] + red[1][1] + red[2][1] + red[3][1];
    float tss = red[0][2] + red[1][2] + red[2][2] + red[3][2];
    float tqs = red[0][3] + red[1][3] + red[2][3] + red[3][3];
    const float inv = 1.f / 1024.f;
    float mc = tsc * inv, vc = tqc * inv - mc * mc;
    float ms = tss * inv, vs = tqs * inv - ms * ms;
    float rc = rsqrtf(vc + 1e-5f), rs = rsqrtf(vs + 1e-5f);
    float4 o;
    o.x = ((xc.x - mc) * rc + (xs.x - ms) * rs) * uu.x;
    o.y = ((xc.y - mc) * rc + (xs.y - ms) * rs) * uu.y;
    o.z = ((xc.z - mc) * rc + (xs.z - ms) * rs) * uu.z;
    o.w = ((xc.w - mc) * rc + (xs.w - ms) * rs) * uu.w;
    *(float4*)(out + base + tid * 4) = o;
}

// ---------------------------------------------------------------------------
extern "C" void kernel_launch(void* const* d_in, const int* in_sizes, int n_in,
                              void* d_out, int out_size, void* d_ws, size_t ws_size,
                              hipStream_t stream) {
    const float* q  = (const float*)d_in[0];
    const float* k  = (const float*)d_in[1];
    const float* v  = (const float*)d_in[2];
    const float* u  = (const float*)d_in[3];
    const float* Wg = (const float*)d_in[4];
    const float* bg = (const float*)d_in[5];
    const int* offs = (const int*)d_in[6];   // int32 (jnp default, x64 off)

    int B = in_sizes[6] - 1;
    int T = in_sizes[0] / HD;

    float* out = (float*)d_out;
    float* qp  = out + (size_t)T * HD;
    float* kp  = qp + (size_t)B * NMAX * HD;

    float* o_cmp_j = out;   // aliases final out (safe: see ln_combine)

    size_t plane = (size_t)B * H * NB * 128;        // elems per kc plane
    char* w = (char*)d_ws;
    unsigned short* kc0 = (unsigned short*)w;  w += plane * 2;
    unsigned short* kc1 = (unsigned short*)w;  w += plane * 2;
    unsigned short* kc2 = (unsigned short*)w;  w += plane * 2;
    unsigned short* vt_cmp = (unsigned short*)w; w += plane * 2;
    float* g     = (float*)w;            w += (size_t)B * NMAX * H * 2 * 4;
    unsigned* ms_g = (unsigned*)w;       w += (size_t)B * H * NMAX * 4;
    float* o_slc_j = (float*)w;          w += (size_t)T * HD * 4;

    // bf16 scratch: prefer ws tail; else use kp output region (rewritten after)
    size_t kb16_bytes = (size_t)T * HD * 2;
    size_t vt_bytes   = (size_t)B * H * NB * 128 * 32 * 2;
    size_t used = (size_t)(w - (char*)d_ws);
    char* scr = (used + kb16_bytes + vt_bytes <= ws_size) ? w : (char*)kp;
    unsigned short* kb16  = (unsigned short*)scr;
    unsigned short* vt_blk = (unsigned short*)(scr + kb16_bytes);

    int prepBlocks = B * H * NB;
    int cmpAttnBlocks = B * H * NB;
    int slcBlocks  = B * H * 16 * MC;
    int padBlocks  = (B * NMAX * HD / 4) / 256;

    (void)hipMemsetAsync(o_slc_j, 0, (size_t)T * HD * sizeof(float), stream);
    prep_kernel<<<prepBlocks, 256, 0, stream>>>(q, k, v, Wg, bg, offs, kb16, vt_blk,
                                                g, kc0, kc1, kc2, vt_cmp);
    cmp_attn<<<cmpAttnBlocks, 256, 0, stream>>>(q, kc0, kc1, kc2, vt_cmp, g,
                                                offs, ms_g, o_cmp_j);
    slc_attn<<<slcBlocks, 256, 0, stream>>>(q, kb16, vt_blk, g, offs, ms_g, o_slc_j);
    pad_qk_kernel<<<padBlocks, 256, 0, stream>>>(q, k, offs, qp, kp);
    ln_combine_kernel<<<T, 256, 0, stream>>>(o_cmp_j, o_slc_j, u, out);
}

// Round 6
// 213.308 us; speedup vs baseline: 1.2503x; 1.1157x over previous
//
#include <hip/hip_runtime.h>
#include <hip/hip_bf16.h>
#include <cmath>

#define H 8
#define D 128
#define HD 1024            // H*D
#define NMAX 1024
#define BS 32
#define NB 32
#define S_SEL 8
#define CHUNK 8            // kb blocks per slc_attn workgroup (r5 showed 4 doubles epilogue traffic)
#define MC 4               // chunks per mtile (NB/CHUNK)
#define KP 136             // K LDS pitch (shorts). MUST be mult of 8 (16B align for b128!)
#define SCALE 0.08838834764831845f   // 1/sqrt(128)
#define SENT -3.0e38f

typedef __attribute__((ext_vector_type(8))) short short8;   // 8 bf16 = 4 VGPRs
typedef __attribute__((ext_vector_type(4))) float f32x4;    // MFMA acc

#define MFMA16(a, b, c) __builtin_amdgcn_mfma_f32_16x16x32_bf16(a, b, c, 0, 0, 0)

__device__ __forceinline__ float silu(float x) {
    return x / (1.f + expf(-x));
}
__device__ __forceinline__ unsigned short f2bf(float x) {
    return __builtin_bit_cast(unsigned short, __float2bfloat16(x));
}
__device__ __forceinline__ float bfup(unsigned short b) {
    unsigned u = (unsigned)b << 16;
    return __builtin_bit_cast(float, u);
}
// 3-term bf16 split: x ~= b0 + b1 + b2 with |err| ~ 2^-27 |x|
__device__ __forceinline__ void split3(float x, unsigned short& b0,
                                       unsigned short& b1, unsigned short& b2) {
    b0 = f2bf(x);
    float r1 = x - bfup(b0);
    b1 = f2bf(r1);
    float r2 = r1 - bfup(b1);
    b2 = f2bf(r2);
}

// ---------------------------------------------------------------------------
// K1 prep: per (b,h,nt) 32-token block:
//   - kb16[tok][h][d]   : bf16 copy of K (straight convert, coalesced)
//   - vt_blk[bh][nt][d][j]: bf16 V^T in 8KB contiguous blocks (LDS transpose)
//   - g[b,m,h,{0,1}]    : gates (8-lane reduction, lanes share (tok,h))
//   - kc0/1/2[bh][nt][d]: split3 bf16 planes of the K block-mean (fused-in
//     compress; bit-identical to fp32 mean + split3)
//   - vt_cmp[bh][d][nt] : bf16 V block-mean, transposed
// Invalid blocks (nt*BS >= len) zero their kc/vt_cmp slots (NaN safety).
// ---------------------------------------------------------------------------
__global__ __launch_bounds__(256) void prep_kernel(
    const float* __restrict__ q, const float* __restrict__ k,
    const float* __restrict__ v, const float* __restrict__ Wg,
    const float* __restrict__ bg, const int* __restrict__ offs,
    unsigned short* __restrict__ kb16, unsigned short* __restrict__ vt_blk,
    float* __restrict__ g, unsigned short* __restrict__ kc0,
    unsigned short* __restrict__ kc1, unsigned short* __restrict__ kc2,
    unsigned short* __restrict__ vt_cmp) {
    int x = blockIdx.x;
    int nt = x & (NB - 1);
    int h = (x >> 5) & 7;
    int b = x >> 8;
    int o0 = offs[b];
    int len = offs[b + 1] - o0;
    int tid = threadIdx.x;
    size_t bh = (size_t)(b * H + h);
    if (nt * BS >= len) {
        if (tid < 128) {
            kc0[(bh * NB + nt) * 128 + tid] = 0;
            kc1[(bh * NB + nt) * 128 + tid] = 0;
            kc2[(bh * NB + nt) * 128 + tid] = 0;
            vt_cmp[(bh * 128 + tid) * NB + nt] = 0;
        }
        return;
    }

    __shared__ __align__(16) unsigned short tile[128 * 40];
    __shared__ float redK[4][128];
    __shared__ float redV[4][128];
    int j = tid >> 3, dc = tid & 7;
    int w = tid >> 6, lane = tid & 63;
    size_t base = (size_t)(o0 + nt * BS + j) * HD + h * D + dc * 16;

    // K -> kb16 (bf16, same layout) + block-mean partial
    {
        float xv[16];
        *(float4*)(xv + 0)  = *(const float4*)(k + base);
        *(float4*)(xv + 4)  = *(const float4*)(k + base + 4);
        *(float4*)(xv + 8)  = *(const float4*)(k + base + 8);
        *(float4*)(xv + 12) = *(const float4*)(k + base + 12);
        short8 lo, hi;
#pragma unroll
        for (int i = 0; i < 8; i++) { lo[i] = (short)f2bf(xv[i]); hi[i] = (short)f2bf(xv[8 + i]); }
        *(short8*)(kb16 + base) = lo;
        *(short8*)(kb16 + base + 8) = hi;
        // butterfly over the wave's 8 j-lanes (lane bits 3,4,5)
#pragma unroll
        for (int i = 0; i < 16; i++) {
            float s = xv[i];
            s += __shfl_xor(s, 8); s += __shfl_xor(s, 16); s += __shfl_xor(s, 32);
            if (lane < 8) redK[w][lane * 16 + i] = s;
        }
    }
    // V -> LDS transpose tile[d][j] + block-mean partial
    {
        float xv[16];
        *(float4*)(xv + 0)  = *(const float4*)(v + base);
        *(float4*)(xv + 4)  = *(const float4*)(v + base + 4);
        *(float4*)(xv + 8)  = *(const float4*)(v + base + 8);
        *(float4*)(xv + 12) = *(const float4*)(v + base + 12);
#pragma unroll
        for (int i = 0; i < 16; i++) tile[(dc * 16 + i) * 40 + j] = f2bf(xv[i]);
#pragma unroll
        for (int i = 0; i < 16; i++) {
            float s = xv[i];
            s += __shfl_xor(s, 8); s += __shfl_xor(s, 16); s += __shfl_xor(s, 32);
            if (lane < 8) redV[w][lane * 16 + i] = s;
        }
    }
    // gates (dot over this thread's 16 dims, reduce across 8 dc-lanes)
    {
        float xv[16];
        *(float4*)(xv + 0)  = *(const float4*)(q + base);
        *(float4*)(xv + 4)  = *(const float4*)(q + base + 4);
        *(float4*)(xv + 8)  = *(const float4*)(q + base + 8);
        *(float4*)(xv + 12) = *(const float4*)(q + base + 12);
        float p0 = 0.f, p1 = 0.f;
#pragma unroll
        for (int i = 0; i < 16; i++) {
            int wb = (h * D + dc * 16 + i) * 3;
            p0 += xv[i] * Wg[wb + 0];
            p1 += xv[i] * Wg[wb + 1];
        }
#pragma unroll
        for (int off = 4; off > 0; off >>= 1) {
            p0 += __shfl_xor(p0, off);
            p1 += __shfl_xor(p1, off);
        }
        if (dc == 0) {
            float g0 = 1.f / (1.f + expf(-(p0 + bg[h * 3 + 0])));
            float g1 = 1.f / (1.f + expf(-(p1 + bg[h * 3 + 1])));
            float* gp = g + (size_t)((b * NMAX + nt * BS + j) * H + h) * 2;
            gp[0] = g0; gp[1] = g1;
        }
    }
    __syncthreads();
    // tile -> vt_blk (contiguous 8KB per (bh,nt))
    {
        int d = tid >> 1, hf = tid & 1;
        short8 a = *(const short8*)(tile + d * 40 + hf * 16);
        short8 c = *(const short8*)(tile + d * 40 + hf * 16 + 8);
        size_t ob = ((bh * NB + nt) * 128 + (size_t)d) * 32 + hf * 16;
        *(short8*)(vt_blk + ob) = a;
        *(short8*)(vt_blk + ob + 8) = c;
    }
    // means -> kc planes / vt_cmp
    if (tid < 128) {
        int d = tid;
        const float inv = 1.f / 32.f;
        float km = (redK[0][d] + redK[1][d] + redK[2][d] + redK[3][d]) * inv;
        float vm = (redV[0][d] + redV[1][d] + redV[2][d] + redV[3][d]) * inv;
        unsigned short e0, e1, e2;
        split3(km, e0, e1, e2);
        kc0[(bh * NB + nt) * 128 + d] = e0;
        kc1[(bh * NB + nt) * 128 + d] = e1;
        kc2[(bh * NB + nt) * 128 + d] = e2;
        vt_cmp[(bh * 128 + d) * NB + nt] = f2bf(vm);
    }
}

// ---------------------------------------------------------------------------
// K3a: compressed attention + top-8 selection, ONE 32-row q-block per WG.
// Staging is pure copies of precomputed bf16 planes (split3 done once in
// prep; non-causal rows skipped — masked out downstream). Selection is
// RANK-BASED: rank_i = #{j: (vj,-j) > (vi,-i)}; top-8 <=> rank<8 — same set
// as iterative max-pick with idx tiebreak, but 31 independent shuffles
// instead of a serial 8x5-step reduce chain.
// MFMA layouts (m89/m120): A[m=lane&15][k=quad*8+j]; C/D col=lane&15,
// row=quad*4+reg.
// ---------------------------------------------------------------------------
__global__ __launch_bounds__(256) void cmp_attn(
    const float* __restrict__ q, const unsigned short* __restrict__ kc0,
    const unsigned short* __restrict__ kc1, const unsigned short* __restrict__ kc2,
    const unsigned short* __restrict__ vt_cmp, const float* __restrict__ g,
    const int* __restrict__ offs, unsigned* __restrict__ ms_g,
    float* __restrict__ o_cmp_j) {
    int x = blockIdx.x;                 // (b*H + h)*NB + qblk
    int qblk = x & (NB - 1);
    int h = (x >> 5) & 7;
    int b = x >> 8;
    int o0 = offs[b];
    int len = offs[b + 1] - o0;
    if (qblk * BS >= len) return;
    size_t bh = (size_t)(b * H + h);

    // pool: R0/R1/R2 k_cmp planes (32x136), R3 v_cmp^T (128x40), Ps (32x40)
    __shared__ __align__(16) unsigned short pool[19456];
    __shared__ float Ss[32 * 33];
    unsigned short* R0 = pool;           // 4352
    unsigned short* R1 = pool + 4352;    // 4352
    unsigned short* R2 = pool + 8704;    // 4352
    unsigned short* R3 = pool + 13056;   // 5120
    unsigned short* Ps = pool + 18176;   // 1280 (32x40)

    int tid = threadIdx.x;
    int w = tid >> 6, lane = tid & 63;
    int r = lane & 15, quad = lane >> 4;
    int mt = w >> 1, jt = w & 1;        // row-half / col-half quadrant
    int stg_j = tid >> 3, stg_dc = tid & 7;

    // ---- stage kc planes (causal rows only) + vt_cmp ----
    if (stg_j <= qblk) {
        size_t src = (bh * NB + stg_j) * 128 + stg_dc * 16;
        int ofs = stg_j * 136 + stg_dc * 16;
        short8 a0 = *(const short8*)(kc0 + src);
        short8 b0 = *(const short8*)(kc0 + src + 8);
        short8 a1 = *(const short8*)(kc1 + src);
        short8 b1 = *(const short8*)(kc1 + src + 8);
        short8 a2 = *(const short8*)(kc2 + src);
        short8 b2 = *(const short8*)(kc2 + src + 8);
        *(short8*)(R0 + ofs) = a0; *(short8*)(R0 + ofs + 8) = b0;
        *(short8*)(R1 + ofs) = a1; *(short8*)(R1 + ofs + 8) = b1;
        *(short8*)(R2 + ofs) = a2; *(short8*)(R2 + ofs + 8) = b2;
    }
    {
        int d = tid >> 1, hf = tid & 1;
        short8 vv = *(const short8*)(vt_cmp + (bh * 128 + d) * NB + hf * 16);
        short8 vw = *(const short8*)(vt_cmp + (bh * 128 + d) * NB + hf * 16 + 8);
        *(short8*)(R3 + d * 40 + hf * 16) = vv;
        *(short8*)(R3 + d * 40 + hf * 16 + 8) = vw;
    }
    __syncthreads();

    // ---- Q fragments (3 planes), QK ----
    short8 qf0[4], qf1[4], qf2[4];
    {
        const float* qrow = q + (size_t)(o0 + qblk * BS + mt * 16 + r) * HD + h * D;
#pragma unroll
        for (int s = 0; s < 4; s++) {
            const float* p0 = qrow + s * 32 + quad * 8;
            float xv[8];
            *(float4*)(xv) = *(const float4*)p0;
            *(float4*)(xv + 4) = *(const float4*)(p0 + 4);
            short8 f0, f1, f2;
#pragma unroll
            for (int i = 0; i < 8; i++) {
                unsigned short e0, e1, e2;
                split3(xv[i], e0, e1, e2);
                f0[i] = (short)e0; f1[i] = (short)e1; f2[i] = (short)e2;
            }
            qf0[s] = f0; qf1[s] = f1; qf2[s] = f2;
        }
    }
    // QK: 6 product rounds, small terms first
    f32x4 sv = (f32x4){0.f, 0.f, 0.f, 0.f};
#pragma unroll
    for (int s = 0; s < 4; s++) {
        int ofs = (jt * 16 + r) * 136 + s * 32 + quad * 8;
        short8 k0 = *(const short8*)(R0 + ofs);
        short8 k1 = *(const short8*)(R1 + ofs);
        short8 k2 = *(const short8*)(R2 + ofs);
        sv = MFMA16(qf1[s], k1, sv);
        sv = MFMA16(qf0[s], k2, sv);
        sv = MFMA16(qf2[s], k0, sv);
        sv = MFMA16(qf0[s], k1, sv);
        sv = MFMA16(qf1[s], k0, sv);
        sv = MFMA16(qf0[s], k0, sv);
    }
    int colj = jt * 16 + r;
    bool causal = (colj <= qblk);
#pragma unroll
    for (int i = 0; i < 4; i++) {
        int mrow = mt * 16 + quad * 4 + i;      // 0..31
        float sc = sv[i] * SCALE;
        Ss[mrow * 33 + colj] = causal ? sc : SENT;
        Ps[mrow * 40 + colj] = f2bf(causal ? silu(sc) : 0.f);
    }
    __syncthreads();

    // ---- PV -> o_cmp ----
    f32x4 accC[2][2];
#pragma unroll
    for (int a = 0; a < 2; a++)
#pragma unroll
        for (int c = 0; c < 2; c++) accC[a][c] = (f32x4){0.f, 0.f, 0.f, 0.f};
    {
        short8 pf0 = *(const short8*)(Ps + r * 40 + quad * 8);
        short8 pf1 = *(const short8*)(Ps + (16 + r) * 40 + quad * 8);
        short8 vf0 = *(const short8*)(R3 + ((2 * w + 0) * 16 + r) * 40 + quad * 8);
        short8 vf1 = *(const short8*)(R3 + ((2 * w + 1) * 16 + r) * 40 + quad * 8);
        accC[0][0] = MFMA16(pf0, vf0, accC[0][0]);
        accC[0][1] = MFMA16(pf0, vf1, accC[0][1]);
        accC[1][0] = MFMA16(pf1, vf0, accC[1][0]);
        accC[1][1] = MFMA16(pf1, vf1, accC[1][1]);
    }
    // ---- selection -> ms_g (rank + ballot) ----
    size_t msbase = (bh << 10) + (size_t)qblk * BS;
    if (qblk < S_SEL) {
        if (tid < BS) ms_g[msbase + tid] = (1u << (qblk + 1)) - 1u;
    } else {
        int h2 = lane >> 5, l32 = lane & 31;
#pragma unroll
        for (int pass = 0; pass < 4; pass++) {
            int row = w * 8 + pass * 2 + h2;
            float val = Ss[row * 33 + l32];
            int cnt = 0;
#pragma unroll
            for (int kk = 1; kk < 32; kk++) {
                int jj = (l32 + kk) & 31;
                float ov = __shfl(val, h2 * 32 + jj);
                if ((ov > val) || (ov == val && jj < l32)) cnt++;
            }
            bool sel = (cnt < S_SEL) && (val > -2.9e38f);
            unsigned long long bal = __ballot(sel);
            unsigned mask = (unsigned)(h2 ? (bal >> 32) : (bal & 0xffffffffULL));
            if (l32 == 0) ms_g[msbase + row] = mask;
        }
    }
    // ---- epilogue o_cmp ----
#pragma unroll
    for (int mtl = 0; mtl < 2; mtl++) {
#pragma unroll
        for (int i = 0; i < 4; i++) {
            int mrow = mtl * 16 + quad * 4 + i;
            int gm = qblk * BS + mrow;
            float gc = g[(size_t)((b * NMAX + gm) * H + h) * 2];
            float* dst = o_cmp_j + (size_t)(o0 + gm) * HD + h * D;
            dst[(2 * w + 0) * 16 + r] = accC[mtl][0][i] * gc;
            dst[(2 * w + 1) * 16 + r] = accC[mtl][1][i] * gc;
        }
    }
}

// ---------------------------------------------------------------------------
// K3b: selected attention — hybrid of the two measured-best structures:
// r2's staging (K+V double-buffered LDS, register prefetch one FULL
// iteration ahead, KP=136 aligned pitch, CHUNK=8 -> 864 blocks / 27.6MB
// epilogue) + r3's verified wave-local PV (A = own 16-row P slice, B = 8
// V^T d-frags) which removes the cross-wave Ps dependency -> the
// mid-iteration barrier is GONE. Race-freedom with ONE barrier/iter:
// commit(i) targets buf[(i+1)%2], whose last readers (QK+PV of iter i-1)
// finished before BAR(i-1), and whose next readers (iter i+1) start after
// BAR(i). Ps write->read is same-wave (compiler lgkmcnt).
// fp32 partials -> atomicAdd into pre-zeroed o_slc_j (plain store when the
// whole mtile fits one chunk).
// ---------------------------------------------------------------------------
__global__ __launch_bounds__(256) void slc_attn(
    const float* __restrict__ q, const unsigned short* __restrict__ kb16,
    const unsigned short* __restrict__ vt_blk, const float* __restrict__ g,
    const int* __restrict__ offs, const unsigned* __restrict__ ms_g,
    float* __restrict__ o_slc_j) {
    int x = blockIdx.x;                 // (((b*H + h)*16 + mtile)*MC + chunk)
    int chunk = x & (MC - 1);
    int mtile = (x >> 2) & 15;
    int h = (x >> 6) & 7;
    int b = x >> 9;
    int o0 = offs[b];
    int len = offs[b + 1] - o0;
    if (mtile * 64 >= len) return;      // uniform exit (lens are multiples of 64)
    int qmax = 2 * mtile + 1;
    int kb0 = chunk * CHUNK;
    if (kb0 > qmax) return;
    int kend = min(qmax, kb0 + CHUNK - 1);

    // single pool: Kbuf0|Kbuf1 (32xKP) | VTbuf0|VTbuf1 (128x40) | Ps (64x40)
    __shared__ __align__(16) unsigned short pool[2 * 32 * KP + 2 * 5120 + 2560];
    __shared__ unsigned Ms[64];
    unsigned short* Kst0 = pool;                      // 4352
    unsigned short* Kst1 = pool + 32 * KP;            // 4352
    unsigned short* Vst0 = pool + 2 * 32 * KP;        // 5120
    unsigned short* Vst1 = pool + 2 * 32 * KP + 5120; // 5120
    unsigned short* Ps   = pool + 2 * 32 * KP + 10240;// 2560

    int tid = threadIdx.x;
    int w = tid >> 6, lane = tid & 63;
    int r = lane & 15, quad = lane >> 4;
    int stg_j = tid >> 3, stg_dc = tid & 7;

    if (tid < 64)
        Ms[tid] = ms_g[((size_t)(b * H + h) << 10) + mtile * 64 + tid];

    // Q fragments (plane 0): wave w -> rows 16w + r
    short8 qs[4];
    {
        const float* qrow = q + (size_t)(o0 + mtile * 64 + w * 16 + r) * HD + h * D;
#pragma unroll
        for (int s = 0; s < 4; s++) {
            const float* p0 = qrow + s * 32 + quad * 8;
            float xv[8];
            *(float4*)(xv) = *(const float4*)p0;
            *(float4*)(xv + 4) = *(const float4*)(p0 + 4);
            short8 f;
#pragma unroll
            for (int i = 0; i < 8; i++) f[i] = (short)f2bf(xv[i]);
            qs[s] = f;
        }
    }
    f32x4 acc[8];                       // wave-local: rows [16w,16w+16), all 128 d
#pragma unroll
    for (int a = 0; a < 8; a++) acc[a] = (f32x4){0.f, 0.f, 0.f, 0.f};

    size_t vtbase = (size_t)((b * H + h) * NB) * 4096;
    int vd = tid >> 1, vhf = tid & 1;

    // prestage kb0 into Kst0 / Vst0
    {
        const unsigned short* ks = kb16 + (size_t)(o0 + kb0 * BS + stg_j) * HD + h * D + stg_dc * 16;
        short8 k0 = *(const short8*)ks;
        short8 k1 = *(const short8*)(ks + 8);
        *(short8*)(Kst0 + stg_j * KP + stg_dc * 16) = k0;
        *(short8*)(Kst0 + stg_j * KP + stg_dc * 16 + 8) = k1;
        const unsigned short* vs = vt_blk + vtbase + (size_t)kb0 * 4096 + tid * 16;
        short8 v0 = *(const short8*)vs;
        short8 v1 = *(const short8*)(vs + 8);
        *(short8*)(Vst0 + vd * 40 + vhf * 16) = v0;
        *(short8*)(Vst0 + vd * 40 + vhf * 16 + 8) = v1;
    }
    __syncthreads();

    int c = 0;
    for (int kb = kb0; kb <= kend; kb++) {
        short8 pk0, pk1, pv0, pv1;
        bool pf = (kb < kend);
        if (pf) {                       // prefetch kb+1 into registers
            const unsigned short* ks = kb16 + (size_t)(o0 + (kb + 1) * BS + stg_j) * HD + h * D + stg_dc * 16;
            pk0 = *(const short8*)ks;
            pk1 = *(const short8*)(ks + 8);
            const unsigned short* vs = vt_blk + vtbase + (size_t)(kb + 1) * 4096 + tid * 16;
            pv0 = *(const short8*)vs;
            pv1 = *(const short8*)(vs + 8);
        }
        // QK: wave w -> rows [16w,16w+16), both j-frags
        unsigned short* K = c ? Kst1 : Kst0;
        unsigned short* V = c ? Vst1 : Vst0;
        f32x4 s0 = (f32x4){0.f, 0.f, 0.f, 0.f};
        f32x4 s1 = (f32x4){0.f, 0.f, 0.f, 0.f};
#pragma unroll
        for (int s = 0; s < 4; s++) {
            short8 kf0 = *(const short8*)(K + r * KP + s * 32 + quad * 8);
            short8 kf1 = *(const short8*)(K + (16 + r) * KP + s * 32 + quad * 8);
            s0 = MFMA16(qs[s], kf0, s0);
            s1 = MFMA16(qs[s], kf1, s1);
        }
        // mask + silu -> OWN Ps slice (rows 16w..16w+15; wave-local)
#pragma unroll
        for (int jf = 0; jf < 2; jf++) {
            f32x4 svv = jf ? s1 : s0;
            int colj = jf * 16 + r;
            int kpos = kb * BS + colj;
#pragma unroll
            for (int i = 0; i < 4; i++) {
                int mrow = w * 16 + quad * 4 + i;
                int mpos = mtile * 64 + mrow;
                float p = (((Ms[mrow] >> kb) & 1u) && (kpos <= mpos))
                          ? silu(svv[i] * SCALE) : 0.f;
                Ps[mrow * 40 + colj] = f2bf(p);
            }
        }
        // PV: A = own P slice (same-wave LDS turnaround), B = 8 V^T d-frags
        {
            short8 pf8 = *(const short8*)(Ps + (w * 16 + r) * 40 + quad * 8);
#pragma unroll
            for (int nf = 0; nf < 8; nf++) {
                short8 vf = *(const short8*)(V + (nf * 16 + r) * 40 + quad * 8);
                acc[nf] = MFMA16(pf8, vf, acc[nf]);
            }
        }
        if (pf) {                       // commit prefetch into the other buffer
            unsigned short* Kn = c ? Kst0 : Kst1;
            unsigned short* Vn = c ? Vst0 : Vst1;
            *(short8*)(Kn + stg_j * KP + stg_dc * 16) = pk0;
            *(short8*)(Kn + stg_j * KP + stg_dc * 16 + 8) = pk1;
            *(short8*)(Vn + vd * 40 + vhf * 16) = pv0;
            *(short8*)(Vn + vd * 40 + vhf * 16 + 8) = pv1;
        }
        __syncthreads();                // single barrier per iteration
        c ^= 1;
    }

    // epilogue: wave w writes its rows [16w,16w+16), all 128 d
    bool single = (qmax < CHUNK);
#pragma unroll
    for (int i = 0; i < 4; i++) {
        int mrow = w * 16 + quad * 4 + i;
        int gm = mtile * 64 + mrow;
        float gs = g[(size_t)((b * NMAX + gm) * H + h) * 2 + 1];
        float* dst = o_slc_j + (size_t)(o0 + gm) * HD + h * D;
#pragma unroll
        for (int nf = 0; nf < 8; nf++) {
            float v0 = acc[nf][i] * gs;
            if (single) dst[nf * 16 + r] = v0;
            else        atomicAdd(dst + nf * 16 + r, v0);
        }
    }
}

// ---------------------------------------------------------------------------
// K4: padded qp, kp (outputs 1,2) — runs AFTER attention (kp region may have
// been used as scratch for kb16/vt_blk when ws is small)
// ---------------------------------------------------------------------------
__global__ __launch_bounds__(256) void pad_qk_kernel(
    const float* __restrict__ q, const float* __restrict__ k,
    const int* __restrict__ offs,
    float* __restrict__ qp, float* __restrict__ kp) {
    int idx = blockIdx.x * 256 + threadIdx.x;       // float4 index over [B,n,H,D/4]
    int d4 = idx & 31;
    int h  = (idx >> 5) & 7;
    int m  = (idx >> 8) & (NMAX - 1);
    int b  = idx >> 18;
    int o0 = offs[b];
    int len = offs[b + 1] - o0;
    float4 qv = make_float4(0.f, 0.f, 0.f, 0.f);
    float4 kv = qv;
    if (m < len) {
        size_t src = (size_t)(o0 + m) * HD + h * D + d4 * 4;
        qv = *(const float4*)(q + src);
        kv = *(const float4*)(k + src);
    }
    *(float4*)(qp + (size_t)idx * 4) = qv;
    *(float4*)(kp + (size_t)idx * 4) = kv;
}

// ---------------------------------------------------------------------------
// K5: LayerNorm(1024) per stream, gate by u, sum -> out (oc may alias out)
// ---------------------------------------------------------------------------
__global__ __launch_bounds__(256) void ln_combine_kernel(
    const float* __restrict__ oc, const float* __restrict__ os,
    const float* __restrict__ u, float* __restrict__ out) {
    int t = blockIdx.x, tid = threadIdx.x;
    size_t base = (size_t)t * HD;
    float4 xc = *(const float4*)(oc + base + tid * 4);
    float4 xs = *(const float4*)(os + base + tid * 4);
    float4 uu = *(const float4*)(u + base + tid * 4);
    float s_c = xc.x + xc.y + xc.z + xc.w;
    float q_c = xc.x * xc.x + xc.y * xc.y + xc.z * xc.z + xc.w * xc.w;
    float s_s = xs.x + xs.y + xs.z + xs.w;
    float q_s = xs.x * xs.x + xs.y * xs.y + xs.z * xs.z + xs.w * xs.w;
#pragma unroll
    for (int off = 32; off > 0; off >>= 1) {
        s_c += __shfl_xor(s_c, off); q_c += __shfl_xor(q_c, off);
        s_s += __shfl_xor(s_s, off); q_s += __shfl_xor(q_s, off);
    }
    __shared__ float red[4][4];
    int w = tid >> 6, lane = tid & 63;
    if (lane == 0) {
        red[w][0] = s_c; red[w][1] = q_c; red[w][2] = s_s; red[w][3] = q_s;
    }
    __syncthreads();
    float tsc = red[0][0] + red[1][0] + red[2][0] + red[3][0];
    float tqc = red[0][1] + red[1][1] + red[2][1] + red[3][1];
    float tss = red[0][2] + red[1][2] + red[2][2] + red[3][2];
    float tqs = red[0][3] + red[1][3] + red[2][3] + red[3][3];
    const float inv = 1.f / 1024.f;
    float mc = tsc * inv, vc = tqc * inv - mc * mc;
    float ms = tss * inv, vs = tqs * inv - ms * ms;
    float rc = rsqrtf(vc + 1e-5f), rs = rsqrtf(vs + 1e-5f);
    float4 o;
    o.x = ((xc.x - mc) * rc + (xs.x - ms) * rs) * uu.x;
    o.y = ((xc.y - mc) * rc + (xs.y - ms) * rs) * uu.y;
    o.z = ((xc.z - mc) * rc + (xs.z - ms) * rs) * uu.z;
    o.w = ((xc.w - mc) * rc + (xs.w - ms) * rs) * uu.w;
    *(float4*)(out + base + tid * 4) = o;
}

// ---------------------------------------------------------------------------
extern "C" void kernel_launch(void* const* d_in, const int* in_sizes, int n_in,
                              void* d_out, int out_size, void* d_ws, size_t ws_size,
                              hipStream_t stream) {
    const float* q  = (const float*)d_in[0];
    const float* k  = (const float*)d_in[1];
    const float* v  = (const float*)d_in[2];
    const float* u  = (const float*)d_in[3];
    const float* Wg = (const float*)d_in[4];
    const float* bg = (const float*)d_in[5];
    const int* offs = (const int*)d_in[6];   // int32 (jnp default, x64 off)

    int B = in_sizes[6] - 1;
    int T = in_sizes[0] / HD;

    float* out = (float*)d_out;
    float* qp  = out + (size_t)T * HD;
    float* kp  = qp + (size_t)B * NMAX * HD;

    float* o_cmp_j = out;   // aliases final out (safe: see ln_combine)

    size_t plane = (size_t)B * H * NB * 128;        // elems per kc plane
    char* w = (char*)d_ws;
    unsigned short* kc0 = (unsigned short*)w;  w += plane * 2;
    unsigned short* kc1 = (unsigned short*)w;  w += plane * 2;
    unsigned short* kc2 = (unsigned short*)w;  w += plane * 2;
    unsigned short* vt_cmp = (unsigned short*)w; w += plane * 2;
    float* g     = (float*)w;            w += (size_t)B * NMAX * H * 2 * 4;
    unsigned* ms_g = (unsigned*)w;       w += (size_t)B * H * NMAX * 4;
    float* o_slc_j = (float*)w;          w += (size_t)T * HD * 4;

    // bf16 scratch: prefer ws tail; else use kp output region (rewritten after)
    size_t kb16_bytes = (size_t)T * HD * 2;
    size_t vt_bytes   = (size_t)B * H * NB * 128 * 32 * 2;
    size_t used = (size_t)(w - (char*)d_ws);
    char* scr = (used + kb16_bytes + vt_bytes <= ws_size) ? w : (char*)kp;
    unsigned short* kb16  = (unsigned short*)scr;
    unsigned short* vt_blk = (unsigned short*)(scr + kb16_bytes);

    int prepBlocks = B * H * NB;
    int cmpAttnBlocks = B * H * NB;
    int slcBlocks  = B * H * 16 * MC;
    int padBlocks  = (B * NMAX * HD / 4) / 256;

    (void)hipMemsetAsync(o_slc_j, 0, (size_t)T * HD * sizeof(float), stream);
    prep_kernel<<<prepBlocks, 256, 0, stream>>>(q, k, v, Wg, bg, offs, kb16, vt_blk,
                                                g, kc0, kc1, kc2, vt_cmp);
    cmp_attn<<<cmpAttnBlocks, 256, 0, stream>>>(q, kc0, kc1, kc2, vt_cmp, g,
                                                offs, ms_g, o_cmp_j);
    slc_attn<<<slcBlocks, 256, 0, stream>>>(q, kb16, vt_blk, g, offs, ms_g, o_slc_j);
    pad_qk_kernel<<<padBlocks, 256, 0, stream>>>(q, k, offs, qp, kp);
    ln_combine_kernel<<<T, 256, 0, stream>>>(o_cmp_j, o_slc_j, u, out);
}

// Round 7
// 205.359 us; speedup vs baseline: 1.2987x; 1.0387x over previous
//
#include <hip/hip_runtime.h>
#include <hip/hip_bf16.h>
#include <cmath>

#define H 8
#define D 128
#define HD 1024            // H*D
#define NMAX 1024
#define BS 32
#define NB 32
#define S_SEL 8
#define CHUNK 8            // kb blocks per slc_attn workgroup
#define MC 4               // chunks per mtile (NB/CHUNK)
#define KP 136             // K LDS pitch (shorts). MUST be mult of 8 (16B align for b128!)
#define SCALE 0.08838834764831845f   // 1/sqrt(128)
#define SENT -3.0e38f

typedef __attribute__((ext_vector_type(8))) short short8;   // 8 bf16 = 4 VGPRs
typedef __attribute__((ext_vector_type(4))) float f32x4;    // MFMA acc

#define MFMA16(a, b, c) __builtin_amdgcn_mfma_f32_16x16x32_bf16(a, b, c, 0, 0, 0)

// fast silu: v_exp_f32 + v_rcp_f32 (~5 inst vs ~25 for libm expf + div).
// Feeds bf16 P values — bf16 rounding (2^-8) dominates native-exp err (2^-20).
__device__ __forceinline__ float silu(float x) {
    return x * __builtin_amdgcn_rcpf(1.f + __expf(-x));
}
__device__ __forceinline__ float sigmoid_fast(float x) {
    return __builtin_amdgcn_rcpf(1.f + __expf(-x));
}
__device__ __forceinline__ unsigned short f2bf(float x) {
    return __builtin_bit_cast(unsigned short, __float2bfloat16(x));
}
__device__ __forceinline__ float bfup(unsigned short b) {
    unsigned u = (unsigned)b << 16;
    return __builtin_bit_cast(float, u);
}
// 3-term bf16 split: x ~= b0 + b1 + b2 with |err| ~ 2^-27 |x|
__device__ __forceinline__ void split3(float x, unsigned short& b0,
                                       unsigned short& b1, unsigned short& b2) {
    b0 = f2bf(x);
    float r1 = x - bfup(b0);
    b1 = f2bf(r1);
    float r2 = r1 - bfup(b1);
    b2 = f2bf(r2);
}

// ---------------------------------------------------------------------------
// K1 prep: per (b,h,nt) 32-token block:
//   - kb16[tok][h][d]   : bf16 copy of K (straight convert, coalesced)
//   - vt_blk[bh][nt][d][j]: bf16 V^T in 8KB contiguous blocks (LDS transpose)
//   - g[b,m,h,{0,1}]    : gates (8-lane reduction, lanes share (tok,h))
//   - kc0/1/2[bh][nt][d]: split3 bf16 planes of the K block-mean (fused-in
//     compress; bit-identical to fp32 mean + split3)
//   - vt_cmp[bh][d][nt] : bf16 V block-mean, transposed
// Invalid blocks (nt*BS >= len) zero their kc/vt_cmp slots (NaN safety).
// ---------------------------------------------------------------------------
__global__ __launch_bounds__(256) void prep_kernel(
    const float* __restrict__ q, const float* __restrict__ k,
    const float* __restrict__ v, const float* __restrict__ Wg,
    const float* __restrict__ bg, const int* __restrict__ offs,
    unsigned short* __restrict__ kb16, unsigned short* __restrict__ vt_blk,
    float* __restrict__ g, unsigned short* __restrict__ kc0,
    unsigned short* __restrict__ kc1, unsigned short* __restrict__ kc2,
    unsigned short* __restrict__ vt_cmp) {
    int x = blockIdx.x;
    int nt = x & (NB - 1);
    int h = (x >> 5) & 7;
    int b = x >> 8;
    int o0 = offs[b];
    int len = offs[b + 1] - o0;
    int tid = threadIdx.x;
    size_t bh = (size_t)(b * H + h);
    if (nt * BS >= len) {
        if (tid < 128) {
            kc0[(bh * NB + nt) * 128 + tid] = 0;
            kc1[(bh * NB + nt) * 128 + tid] = 0;
            kc2[(bh * NB + nt) * 128 + tid] = 0;
            vt_cmp[(bh * 128 + tid) * NB + nt] = 0;
        }
        return;
    }

    __shared__ __align__(16) unsigned short tile[128 * 40];
    __shared__ float redK[4][128];
    __shared__ float redV[4][128];
    int j = tid >> 3, dc = tid & 7;
    int w = tid >> 6, lane = tid & 63;
    size_t base = (size_t)(o0 + nt * BS + j) * HD + h * D + dc * 16;

    // K -> kb16 (bf16, same layout) + block-mean partial
    {
        float xv[16];
        *(float4*)(xv + 0)  = *(const float4*)(k + base);
        *(float4*)(xv + 4)  = *(const float4*)(k + base + 4);
        *(float4*)(xv + 8)  = *(const float4*)(k + base + 8);
        *(float4*)(xv + 12) = *(const float4*)(k + base + 12);
        short8 lo, hi;
#pragma unroll
        for (int i = 0; i < 8; i++) { lo[i] = (short)f2bf(xv[i]); hi[i] = (short)f2bf(xv[8 + i]); }
        *(short8*)(kb16 + base) = lo;
        *(short8*)(kb16 + base + 8) = hi;
        // butterfly over the wave's 8 j-lanes (lane bits 3,4,5)
#pragma unroll
        for (int i = 0; i < 16; i++) {
            float s = xv[i];
            s += __shfl_xor(s, 8); s += __shfl_xor(s, 16); s += __shfl_xor(s, 32);
            if (lane < 8) redK[w][lane * 16 + i] = s;
        }
    }
    // V -> LDS transpose tile[d][j] + block-mean partial
    {
        float xv[16];
        *(float4*)(xv + 0)  = *(const float4*)(v + base);
        *(float4*)(xv + 4)  = *(const float4*)(v + base + 4);
        *(float4*)(xv + 8)  = *(const float4*)(v + base + 8);
        *(float4*)(xv + 12) = *(const float4*)(v + base + 12);
#pragma unroll
        for (int i = 0; i < 16; i++) tile[(dc * 16 + i) * 40 + j] = f2bf(xv[i]);
#pragma unroll
        for (int i = 0; i < 16; i++) {
            float s = xv[i];
            s += __shfl_xor(s, 8); s += __shfl_xor(s, 16); s += __shfl_xor(s, 32);
            if (lane < 8) redV[w][lane * 16 + i] = s;
        }
    }
    // gates (dot over this thread's 16 dims, reduce across 8 dc-lanes)
    {
        float xv[16];
        *(float4*)(xv + 0)  = *(const float4*)(q + base);
        *(float4*)(xv + 4)  = *(const float4*)(q + base + 4);
        *(float4*)(xv + 8)  = *(const float4*)(q + base + 8);
        *(float4*)(xv + 12) = *(const float4*)(q + base + 12);
        float p0 = 0.f, p1 = 0.f;
#pragma unroll
        for (int i = 0; i < 16; i++) {
            int wb = (h * D + dc * 16 + i) * 3;
            p0 += xv[i] * Wg[wb + 0];
            p1 += xv[i] * Wg[wb + 1];
        }
#pragma unroll
        for (int off = 4; off > 0; off >>= 1) {
            p0 += __shfl_xor(p0, off);
            p1 += __shfl_xor(p1, off);
        }
        if (dc == 0) {
            float g0 = sigmoid_fast(p0 + bg[h * 3 + 0]);
            float g1 = sigmoid_fast(p1 + bg[h * 3 + 1]);
            float* gp = g + (size_t)((b * NMAX + nt * BS + j) * H + h) * 2;
            gp[0] = g0; gp[1] = g1;
        }
    }
    __syncthreads();
    // tile -> vt_blk (contiguous 8KB per (bh,nt))
    {
        int d = tid >> 1, hf = tid & 1;
        short8 a = *(const short8*)(tile + d * 40 + hf * 16);
        short8 c = *(const short8*)(tile + d * 40 + hf * 16 + 8);
        size_t ob = ((bh * NB + nt) * 128 + (size_t)d) * 32 + hf * 16;
        *(short8*)(vt_blk + ob) = a;
        *(short8*)(vt_blk + ob + 8) = c;
    }
    // means -> kc planes / vt_cmp
    if (tid < 128) {
        int d = tid;
        const float inv = 1.f / 32.f;
        float km = (redK[0][d] + redK[1][d] + redK[2][d] + redK[3][d]) * inv;
        float vm = (redV[0][d] + redV[1][d] + redV[2][d] + redV[3][d]) * inv;
        unsigned short e0, e1, e2;
        split3(km, e0, e1, e2);
        kc0[(bh * NB + nt) * 128 + d] = e0;
        kc1[(bh * NB + nt) * 128 + d] = e1;
        kc2[(bh * NB + nt) * 128 + d] = e2;
        vt_cmp[(bh * 128 + d) * NB + nt] = f2bf(vm);
    }
}

// ---------------------------------------------------------------------------
// K3a: compressed attention + top-8 selection, ONE 32-row q-block per WG.
// qblk dispatch REVERSED (heavy blocks first — LPT). For qblk<16 the jt=1
// waves' QK output (cols 16-31) is entirely non-causal -> skip their Q
// split3 + 24 MFMAs (sv stays 0; the write loop emits SENT/0 regardless).
// Selection is RANK-BASED: rank_i = #{j: (vj,-j) > (vi,-i)}; top-8 <=>
// rank<8 — same set as iterative max-pick with idx tiebreak.
// MFMA layouts (m89/m120): A[m=lane&15][k=quad*8+j]; C/D col=lane&15,
// row=quad*4+reg.
// ---------------------------------------------------------------------------
__global__ __launch_bounds__(256) void cmp_attn(
    const float* __restrict__ q, const unsigned short* __restrict__ kc0,
    const unsigned short* __restrict__ kc1, const unsigned short* __restrict__ kc2,
    const unsigned short* __restrict__ vt_cmp, const float* __restrict__ g,
    const int* __restrict__ offs, unsigned* __restrict__ ms_g,
    float* __restrict__ o_cmp_j) {
    int x = blockIdx.x;                 // (b*H + h)*NB + qblk_idx
    int qblk = (NB - 1) - (x & (NB - 1));   // reversed: long blocks dispatch first
    int h = (x >> 5) & 7;
    int b = x >> 8;
    int o0 = offs[b];
    int len = offs[b + 1] - o0;
    if (qblk * BS >= len) return;
    size_t bh = (size_t)(b * H + h);

    // pool: R0/R1/R2 k_cmp planes (32x136), R3 v_cmp^T (128x40), Ps (32x40)
    __shared__ __align__(16) unsigned short pool[19456];
    __shared__ float Ss[32 * 33];
    unsigned short* R0 = pool;           // 4352
    unsigned short* R1 = pool + 4352;    // 4352
    unsigned short* R2 = pool + 8704;    // 4352
    unsigned short* R3 = pool + 13056;   // 5120
    unsigned short* Ps = pool + 18176;   // 1280 (32x40)

    int tid = threadIdx.x;
    int w = tid >> 6, lane = tid & 63;
    int r = lane & 15, quad = lane >> 4;
    int mt = w >> 1, jt = w & 1;        // row-half / col-half quadrant
    int stg_j = tid >> 3, stg_dc = tid & 7;

    // ---- stage kc planes (causal rows only) + vt_cmp ----
    if (stg_j <= qblk) {
        size_t src = (bh * NB + stg_j) * 128 + stg_dc * 16;
        int ofs = stg_j * 136 + stg_dc * 16;
        short8 a0 = *(const short8*)(kc0 + src);
        short8 b0 = *(const short8*)(kc0 + src + 8);
        short8 a1 = *(const short8*)(kc1 + src);
        short8 b1 = *(const short8*)(kc1 + src + 8);
        short8 a2 = *(const short8*)(kc2 + src);
        short8 b2 = *(const short8*)(kc2 + src + 8);
        *(short8*)(R0 + ofs) = a0; *(short8*)(R0 + ofs + 8) = b0;
        *(short8*)(R1 + ofs) = a1; *(short8*)(R1 + ofs + 8) = b1;
        *(short8*)(R2 + ofs) = a2; *(short8*)(R2 + ofs + 8) = b2;
    }
    {
        int d = tid >> 1, hf = tid & 1;
        short8 vv = *(const short8*)(vt_cmp + (bh * 128 + d) * NB + hf * 16);
        short8 vw = *(const short8*)(vt_cmp + (bh * 128 + d) * NB + hf * 16 + 8);
        *(short8*)(R3 + d * 40 + hf * 16) = vv;
        *(short8*)(R3 + d * 40 + hf * 16 + 8) = vw;
    }
    __syncthreads();

    // ---- Q fragments (3 planes) + QK — skipped when this wave's columns
    // (jt=1 -> 16..31) are entirely non-causal (qblk < 16): its sv would be
    // fully masked to SENT/0 below anyway.
    f32x4 sv = (f32x4){0.f, 0.f, 0.f, 0.f};
    if (jt == 0 || qblk >= 16) {
        short8 qf0[4], qf1[4], qf2[4];
        const float* qrow = q + (size_t)(o0 + qblk * BS + mt * 16 + r) * HD + h * D;
#pragma unroll
        for (int s = 0; s < 4; s++) {
            const float* p0 = qrow + s * 32 + quad * 8;
            float xv[8];
            *(float4*)(xv) = *(const float4*)p0;
            *(float4*)(xv + 4) = *(const float4*)(p0 + 4);
            short8 f0, f1, f2;
#pragma unroll
            for (int i = 0; i < 8; i++) {
                unsigned short e0, e1, e2;
                split3(xv[i], e0, e1, e2);
                f0[i] = (short)e0; f1[i] = (short)e1; f2[i] = (short)e2;
            }
            qf0[s] = f0; qf1[s] = f1; qf2[s] = f2;
        }
        // QK: 6 product rounds, small terms first
#pragma unroll
        for (int s = 0; s < 4; s++) {
            int ofs = (jt * 16 + r) * 136 + s * 32 + quad * 8;
            short8 k0 = *(const short8*)(R0 + ofs);
            short8 k1 = *(const short8*)(R1 + ofs);
            short8 k2 = *(const short8*)(R2 + ofs);
            sv = MFMA16(qf1[s], k1, sv);
            sv = MFMA16(qf0[s], k2, sv);
            sv = MFMA16(qf2[s], k0, sv);
            sv = MFMA16(qf0[s], k1, sv);
            sv = MFMA16(qf1[s], k0, sv);
            sv = MFMA16(qf0[s], k0, sv);
        }
    }
    int colj = jt * 16 + r;
    bool causal = (colj <= qblk);
#pragma unroll
    for (int i = 0; i < 4; i++) {
        int mrow = mt * 16 + quad * 4 + i;      // 0..31
        float sc = sv[i] * SCALE;
        Ss[mrow * 33 + colj] = causal ? sc : SENT;
        Ps[mrow * 40 + colj] = f2bf(causal ? silu(sc) : 0.f);
    }
    __syncthreads();

    // ---- PV -> o_cmp ----
    f32x4 accC[2][2];
#pragma unroll
    for (int a = 0; a < 2; a++)
#pragma unroll
        for (int c = 0; c < 2; c++) accC[a][c] = (f32x4){0.f, 0.f, 0.f, 0.f};
    {
        short8 pf0 = *(const short8*)(Ps + r * 40 + quad * 8);
        short8 pf1 = *(const short8*)(Ps + (16 + r) * 40 + quad * 8);
        short8 vf0 = *(const short8*)(R3 + ((2 * w + 0) * 16 + r) * 40 + quad * 8);
        short8 vf1 = *(const short8*)(R3 + ((2 * w + 1) * 16 + r) * 40 + quad * 8);
        accC[0][0] = MFMA16(pf0, vf0, accC[0][0]);
        accC[0][1] = MFMA16(pf0, vf1, accC[0][1]);
        accC[1][0] = MFMA16(pf1, vf0, accC[1][0]);
        accC[1][1] = MFMA16(pf1, vf1, accC[1][1]);
    }
    // ---- selection -> ms_g (rank + ballot) ----
    size_t msbase = (bh << 10) + (size_t)qblk * BS;
    if (qblk < S_SEL) {
        if (tid < BS) ms_g[msbase + tid] = (1u << (qblk + 1)) - 1u;
    } else {
        int h2 = lane >> 5, l32 = lane & 31;
#pragma unroll
        for (int pass = 0; pass < 4; pass++) {
            int row = w * 8 + pass * 2 + h2;
            float val = Ss[row * 33 + l32];
            int cnt = 0;
#pragma unroll
            for (int kk = 1; kk < 32; kk++) {
                int jj = (l32 + kk) & 31;
                float ov = __shfl(val, h2 * 32 + jj);
                if ((ov > val) || (ov == val && jj < l32)) cnt++;
            }
            bool sel = (cnt < S_SEL) && (val > -2.9e38f);
            unsigned long long bal = __ballot(sel);
            unsigned mask = (unsigned)(h2 ? (bal >> 32) : (bal & 0xffffffffULL));
            if (l32 == 0) ms_g[msbase + row] = mask;
        }
    }
    // ---- epilogue o_cmp ----
#pragma unroll
    for (int mtl = 0; mtl < 2; mtl++) {
#pragma unroll
        for (int i = 0; i < 4; i++) {
            int mrow = mtl * 16 + quad * 4 + i;
            int gm = qblk * BS + mrow;
            float gc = g[(size_t)((b * NMAX + gm) * H + h) * 2];
            float* dst = o_cmp_j + (size_t)(o0 + gm) * HD + h * D;
            dst[(2 * w + 0) * 16 + r] = accC[mtl][0][i] * gc;
            dst[(2 * w + 1) * 16 + r] = accC[mtl][1][i] * gc;
        }
    }
}

// ---------------------------------------------------------------------------
// K3b: selected attention — r6 structure (single barrier/iter, wave-local
// PV, K+V double-buffered LDS, register prefetch one FULL iteration ahead,
// KP=136 aligned). New: mtile dispatch REVERSED (LPT — the 8-iteration
// blocks launch first, short blocks fill the scheduling tail).
// Race-freedom with ONE barrier/iter: commit(i) targets buf[(i+1)%2], whose
// last readers (QK+PV of iter i-1) finished before BAR(i-1), and whose next
// readers (iter i+1) start after BAR(i). Ps write->read is same-wave
// (compiler lgkmcnt). fp32 partials -> atomicAdd into pre-zeroed o_slc_j
// (plain store when the whole mtile fits one chunk).
// ---------------------------------------------------------------------------
__global__ __launch_bounds__(256) void slc_attn(
    const float* __restrict__ q, const unsigned short* __restrict__ kb16,
    const unsigned short* __restrict__ vt_blk, const float* __restrict__ g,
    const int* __restrict__ offs, const unsigned* __restrict__ ms_g,
    float* __restrict__ o_slc_j) {
    int x = blockIdx.x;                 // (((b*H + h)*16 + mtile_idx)*MC + chunk)
    int chunk = x & (MC - 1);
    int mtile = 15 - ((x >> 2) & 15);   // reversed: longest blocks dispatch first
    int h = (x >> 6) & 7;
    int b = x >> 9;
    int o0 = offs[b];
    int len = offs[b + 1] - o0;
    if (mtile * 64 >= len) return;      // uniform exit (lens are multiples of 64)
    int qmax = 2 * mtile + 1;
    int kb0 = chunk * CHUNK;
    if (kb0 > qmax) return;
    int kend = min(qmax, kb0 + CHUNK - 1);

    // single pool: Kbuf0|Kbuf1 (32xKP) | VTbuf0|VTbuf1 (128x40) | Ps (64x40)
    __shared__ __align__(16) unsigned short pool[2 * 32 * KP + 2 * 5120 + 2560];
    __shared__ unsigned Ms[64];
    unsigned short* Kst0 = pool;                      // 4352
    unsigned short* Kst1 = pool + 32 * KP;            // 4352
    unsigned short* Vst0 = pool + 2 * 32 * KP;        // 5120
    unsigned short* Vst1 = pool + 2 * 32 * KP + 5120; // 5120
    unsigned short* Ps   = pool + 2 * 32 * KP + 10240;// 2560

    int tid = threadIdx.x;
    int w = tid >> 6, lane = tid & 63;
    int r = lane & 15, quad = lane >> 4;
    int stg_j = tid >> 3, stg_dc = tid & 7;

    if (tid < 64)
        Ms[tid] = ms_g[((size_t)(b * H + h) << 10) + mtile * 64 + tid];

    // Q fragments (plane 0): wave w -> rows 16w + r
    short8 qs[4];
    {
        const float* qrow = q + (size_t)(o0 + mtile * 64 + w * 16 + r) * HD + h * D;
#pragma unroll
        for (int s = 0; s < 4; s++) {
            const float* p0 = qrow + s * 32 + quad * 8;
            float xv[8];
            *(float4*)(xv) = *(const float4*)p0;
            *(float4*)(xv + 4) = *(const float4*)(p0 + 4);
            short8 f;
#pragma unroll
            for (int i = 0; i < 8; i++) f[i] = (short)f2bf(xv[i]);
            qs[s] = f;
        }
    }
    f32x4 acc[8];                       // wave-local: rows [16w,16w+16), all 128 d
#pragma unroll
    for (int a = 0; a < 8; a++) acc[a] = (f32x4){0.f, 0.f, 0.f, 0.f};

    size_t vtbase = (size_t)((b * H + h) * NB) * 4096;
    int vd = tid >> 1, vhf = tid & 1;

    // prestage kb0 into Kst0 / Vst0
    {
        const unsigned short* ks = kb16 + (size_t)(o0 + kb0 * BS + stg_j) * HD + h * D + stg_dc * 16;
        short8 k0 = *(const short8*)ks;
        short8 k1 = *(const short8*)(ks + 8);
        *(short8*)(Kst0 + stg_j * KP + stg_dc * 16) = k0;
        *(short8*)(Kst0 + stg_j * KP + stg_dc * 16 + 8) = k1;
        const unsigned short* vs = vt_blk + vtbase + (size_t)kb0 * 4096 + tid * 16;
        short8 v0 = *(const short8*)vs;
        short8 v1 = *(const short8*)(vs + 8);
        *(short8*)(Vst0 + vd * 40 + vhf * 16) = v0;
        *(short8*)(Vst0 + vd * 40 + vhf * 16 + 8) = v1;
    }
    __syncthreads();

    int c = 0;
    for (int kb = kb0; kb <= kend; kb++) {
        short8 pk0, pk1, pv0, pv1;
        bool pf = (kb < kend);
        if (pf) {                       // prefetch kb+1 into registers
            const unsigned short* ks = kb16 + (size_t)(o0 + (kb + 1) * BS + stg_j) * HD + h * D + stg_dc * 16;
            pk0 = *(const short8*)ks;
            pk1 = *(const short8*)(ks + 8);
            const unsigned short* vs = vt_blk + vtbase + (size_t)(kb + 1) * 4096 + tid * 16;
            pv0 = *(const short8*)vs;
            pv1 = *(const short8*)(vs + 8);
        }
        // QK: wave w -> rows [16w,16w+16), both j-frags
        unsigned short* K = c ? Kst1 : Kst0;
        unsigned short* V = c ? Vst1 : Vst0;
        f32x4 s0 = (f32x4){0.f, 0.f, 0.f, 0.f};
        f32x4 s1 = (f32x4){0.f, 0.f, 0.f, 0.f};
#pragma unroll
        for (int s = 0; s < 4; s++) {
            short8 kf0 = *(const short8*)(K + r * KP + s * 32 + quad * 8);
            short8 kf1 = *(const short8*)(K + (16 + r) * KP + s * 32 + quad * 8);
            s0 = MFMA16(qs[s], kf0, s0);
            s1 = MFMA16(qs[s], kf1, s1);
        }
        // mask + silu -> OWN Ps slice (rows 16w..16w+15; wave-local)
#pragma unroll
        for (int jf = 0; jf < 2; jf++) {
            f32x4 svv = jf ? s1 : s0;
            int colj = jf * 16 + r;
            int kpos = kb * BS + colj;
#pragma unroll
            for (int i = 0; i < 4; i++) {
                int mrow = w * 16 + quad * 4 + i;
                int mpos = mtile * 64 + mrow;
                float p = (((Ms[mrow] >> kb) & 1u) && (kpos <= mpos))
                          ? silu(svv[i] * SCALE) : 0.f;
                Ps[mrow * 40 + colj] = f2bf(p);
            }
        }
        // PV: A = own P slice (same-wave LDS turnaround), B = 8 V^T d-frags
        {
            short8 pf8 = *(const short8*)(Ps + (w * 16 + r) * 40 + quad * 8);
#pragma unroll
            for (int nf = 0; nf < 8; nf++) {
                short8 vf = *(const short8*)(V + (nf * 16 + r) * 40 + quad * 8);
                acc[nf] = MFMA16(pf8, vf, acc[nf]);
            }
        }
        if (pf) {                       // commit prefetch into the other buffer
            unsigned short* Kn = c ? Kst0 : Kst1;
            unsigned short* Vn = c ? Vst0 : Vst1;
            *(short8*)(Kn + stg_j * KP + stg_dc * 16) = pk0;
            *(short8*)(Kn + stg_j * KP + stg_dc * 16 + 8) = pk1;
            *(short8*)(Vn + vd * 40 + vhf * 16) = pv0;
            *(short8*)(Vn + vd * 40 + vhf * 16 + 8) = pv1;
        }
        __syncthreads();                // single barrier per iteration
        c ^= 1;
    }

    // epilogue: wave w writes its rows [16w,16w+16), all 128 d
    bool single = (qmax < CHUNK);
#pragma unroll
    for (int i = 0; i < 4; i++) {
        int mrow = w * 16 + quad * 4 + i;
        int gm = mtile * 64 + mrow;
        float gs = g[(size_t)((b * NMAX + gm) * H + h) * 2 + 1];
        float* dst = o_slc_j + (size_t)(o0 + gm) * HD + h * D;
#pragma unroll
        for (int nf = 0; nf < 8; nf++) {
            float v0 = acc[nf][i] * gs;
            if (single) dst[nf * 16 + r] = v0;
            else        atomicAdd(dst + nf * 16 + r, v0);
        }
    }
}

// ---------------------------------------------------------------------------
// K4: padded qp, kp (outputs 1,2) — runs AFTER attention (kp region may have
// been used as scratch for kb16/vt_blk when ws is small)
// ---------------------------------------------------------------------------
__global__ __launch_bounds__(256) void pad_qk_kernel(
    const float* __restrict__ q, const float* __restrict__ k,
    const int* __restrict__ offs,
    float* __restrict__ qp, float* __restrict__ kp) {
    int idx = blockIdx.x * 256 + threadIdx.x;       // float4 index over [B,n,H,D/4]
    int d4 = idx & 31;
    int h  = (idx >> 5) & 7;
    int m  = (idx >> 8) & (NMAX - 1);
    int b  = idx >> 18;
    int o0 = offs[b];
    int len = offs[b + 1] - o0;
    float4 qv = make_float4(0.f, 0.f, 0.f, 0.f);
    float4 kv = qv;
    if (m < len) {
        size_t src = (size_t)(o0 + m) * HD + h * D + d4 * 4;
        qv = *(const float4*)(q + src);
        kv = *(const float4*)(k + src);
    }
    *(float4*)(qp + (size_t)idx * 4) = qv;
    *(float4*)(kp + (size_t)idx * 4) = kv;
}

// ---------------------------------------------------------------------------
// K5: LayerNorm(1024) per stream, gate by u, sum -> out (oc may alias out)
// ---------------------------------------------------------------------------
__global__ __launch_bounds__(256) void ln_combine_kernel(
    const float* __restrict__ oc, const float* __restrict__ os,
    const float* __restrict__ u, float* __restrict__ out) {
    int t = blockIdx.x, tid = threadIdx.x;
    size_t base = (size_t)t * HD;
    float4 xc = *(const float4*)(oc + base + tid * 4);
    float4 xs = *(const float4*)(os + base + tid * 4);
    float4 uu = *(const float4*)(u + base + tid * 4);
    float s_c = xc.x + xc.y + xc.z + xc.w;
    float q_c = xc.x * xc.x + xc.y * xc.y + xc.z * xc.z + xc.w * xc.w;
    float s_s = xs.x + xs.y + xs.z + xs.w;
    float q_s = xs.x * xs.x + xs.y * xs.y + xs.z * xs.z + xs.w * xs.w;
#pragma unroll
    for (int off = 32; off > 0; off >>= 1) {
        s_c += __shfl_xor(s_c, off); q_c += __shfl_xor(q_c, off);
        s_s += __shfl_xor(s_s, off); q_s += __shfl_xor(q_s, off);
    }
    __shared__ float red[4][4];
    int w = tid >> 6, lane = tid & 63;
    if (lane == 0) {
        red[w][0] = s_c; red[w][1] = q_c; red[w][2] = s_s; red[w][3] = q_s;
    }
    __syncthreads();
    float tsc = red[0][0] + red[1][0] + red[2][0] + red[3][0];
    float tqc = red[0][1] + red[1][1] + red[2][1] + red[3][1];
    float tss = red[0][2] + red[1][2] + red[2][2] + red[3][2];
    float tqs = red[0][3] + red[1][3] + red[2][3] + red[3][3];
    const float inv = 1.f / 1024.f;
    float mc = tsc * inv, vc = tqc * inv - mc * mc;
    float ms = tss * inv, vs = tqs * inv - ms * ms;
    float rc = rsqrtf(vc + 1e-5f), rs = rsqrtf(vs + 1e-5f);
    float4 o;
    o.x = ((xc.x - mc) * rc + (xs.x - ms) * rs) * uu.x;
    o.y = ((xc.y - mc) * rc + (xs.y - ms) * rs) * uu.y;
    o.z = ((xc.z - mc) * rc + (xs.z - ms) * rs) * uu.z;
    o.w = ((xc.w - mc) * rc + (xs.w - ms) * rs) * uu.w;
    *(float4*)(out + base + tid * 4) = o;
}

// ---------------------------------------------------------------------------
extern "C" void kernel_launch(void* const* d_in, const int* in_sizes, int n_in,
                              void* d_out, int out_size, void* d_ws, size_t ws_size,
                              hipStream_t stream) {
    const float* q  = (const float*)d_in[0];
    const float* k  = (const float*)d_in[1];
    const float* v  = (const float*)d_in[2];
    const float* u  = (const float*)d_in[3];
    const float* Wg = (const float*)d_in[4];
    const float* bg = (const float*)d_in[5];
    const int* offs = (const int*)d_in[6];   // int32 (jnp default, x64 off)

    int B = in_sizes[6] - 1;
    int T = in_sizes[0] / HD;

    float* out = (float*)d_out;
    float* qp  = out + (size_t)T * HD;
    float* kp  = qp + (size_t)B * NMAX * HD;

    float* o_cmp_j = out;   // aliases final out (safe: see ln_combine)

    size_t plane = (size_t)B * H * NB * 128;        // elems per kc plane
    char* w = (char*)d_ws;
    unsigned short* kc0 = (unsigned short*)w;  w += plane * 2;
    unsigned short* kc1 = (unsigned short*)w;  w += plane * 2;
    unsigned short* kc2 = (unsigned short*)w;  w += plane * 2;
    unsigned short* vt_cmp = (unsigned short*)w; w += plane * 2;
    float* g     = (float*)w;            w += (size_t)B * NMAX * H * 2 * 4;
    unsigned* ms_g = (unsigned*)w;       w += (size_t)B * H * NMAX * 4;
    float* o_slc_j = (float*)w;          w += (size_t)T * HD * 4;

    // bf16 scratch: prefer ws tail; else use kp output region (rewritten after)
    size_t kb16_bytes = (size_t)T * HD * 2;
    size_t vt_bytes   = (size_t)B * H * NB * 128 * 32 * 2;
    size_t used = (size_t)(w - (char*)d_ws);
    char* scr = (used + kb16_bytes + vt_bytes <= ws_size) ? w : (char*)kp;
    unsigned short* kb16  = (unsigned short*)scr;
    unsigned short* vt_blk = (unsigned short*)(scr + kb16_bytes);

    int prepBlocks = B * H * NB;
    int cmpAttnBlocks = B * H * NB;
    int slcBlocks  = B * H * 16 * MC;
    int padBlocks  = (B * NMAX * HD / 4) / 256;

    (void)hipMemsetAsync(o_slc_j, 0, (size_t)T * HD * sizeof(float), stream);
    prep_kernel<<<prepBlocks, 256, 0, stream>>>(q, k, v, Wg, bg, offs, kb16, vt_blk,
                                                g, kc0, kc1, kc2, vt_cmp);
    cmp_attn<<<cmpAttnBlocks, 256, 0, stream>>>(q, kc0, kc1, kc2, vt_cmp, g,
                                                offs, ms_g, o_cmp_j);
    slc_attn<<<slcBlocks, 256, 0, stream>>>(q, kb16, vt_blk, g, offs, ms_g, o_slc_j);
    pad_qk_kernel<<<padBlocks, 256, 0, stream>>>(q, k, offs, qp, kp);
    ln_combine_kernel<<<T, 256, 0, stream>>>(o_cmp_j, o_slc_j, u, out);
}

// Round 8
// 199.190 us; speedup vs baseline: 1.3389x; 1.0310x over previous
//
#include <hip/hip_runtime.h>
#include <hip/hip_bf16.h>
#include <cmath>

#define H 8
#define D 128
#define HD 1024            // H*D
#define NMAX 1024
#define BS 32
#define NB 32
#define S_SEL 8
#define CHUNK 8            // kb blocks per slc_attn workgroup
#define MC 4               // chunks per mtile (NB/CHUNK)
#define KP 136             // K LDS pitch (shorts). MUST be mult of 8 (16B align for b128!)
#define NXCD 8
#define SCALE 0.08838834764831845f   // 1/sqrt(128)
#define SENT -3.0e38f

typedef __attribute__((ext_vector_type(8))) short short8;   // 8 bf16 = 4 VGPRs
typedef __attribute__((ext_vector_type(4))) float f32x4;    // MFMA acc

#define MFMA16(a, b, c) __builtin_amdgcn_mfma_f32_16x16x32_bf16(a, b, c, 0, 0, 0)

// fast silu: v_exp_f32 + v_rcp_f32 (~5 inst vs ~25 for libm expf + div).
// Feeds bf16 P values — bf16 rounding (2^-8) dominates native-exp err (2^-20).
__device__ __forceinline__ float silu(float x) {
    return x * __builtin_amdgcn_rcpf(1.f + __expf(-x));
}
__device__ __forceinline__ float sigmoid_fast(float x) {
    return __builtin_amdgcn_rcpf(1.f + __expf(-x));
}
__device__ __forceinline__ unsigned short f2bf(float x) {
    return __builtin_bit_cast(unsigned short, __float2bfloat16(x));
}
__device__ __forceinline__ float bfup(unsigned short b) {
    unsigned u = (unsigned)b << 16;
    return __builtin_bit_cast(float, u);
}
// 3-term bf16 split: x ~= b0 + b1 + b2 with |err| ~ 2^-27 |x|
__device__ __forceinline__ void split3(float x, unsigned short& b0,
                                       unsigned short& b1, unsigned short& b2) {
    b0 = f2bf(x);
    float r1 = x - bfup(b0);
    b1 = f2bf(r1);
    float r2 = r1 - bfup(b1);
    b2 = f2bf(r2);
}

// ---------------------------------------------------------------------------
// K1 prep: per (b,h,nt) 32-token block:
//   - kb16[tok][h][d]   : bf16 copy of K (straight convert, coalesced)
//   - vt_blk[bh][nt][d][j]: bf16 V^T in 8KB contiguous blocks (LDS transpose)
//   - g[b,m,h,{0,1}]    : gates (8-lane reduction, lanes share (tok,h))
//   - kc0/1/2[bh][nt][d]: split3 bf16 planes of the K block-mean
//   - vt_cmp[bh][d][nt] : bf16 V block-mean, transposed
//   - FUSED: qp/kp padded outputs (same q,k data already in registers;
//     qp/kp may be null -> fallback pad_qk kernel runs later)
//   - FUSED: zeroes its o_slc_j slice (replaces the memset dispatch; the
//     union of valid blocks covers exactly the jagged [T,HD] buffer)
// Invalid blocks (nt*BS >= len) zero kc/vt_cmp slots and their qp/kp slices.
// All lengths are multiples of 32, so valid blocks are fully valid.
// ---------------------------------------------------------------------------
__global__ __launch_bounds__(256) void prep_kernel(
    const float* __restrict__ q, const float* __restrict__ k,
    const float* __restrict__ v, const float* __restrict__ Wg,
    const float* __restrict__ bg, const int* __restrict__ offs,
    unsigned short* __restrict__ kb16, unsigned short* __restrict__ vt_blk,
    float* __restrict__ g, unsigned short* __restrict__ kc0,
    unsigned short* __restrict__ kc1, unsigned short* __restrict__ kc2,
    unsigned short* __restrict__ vt_cmp, float* __restrict__ o_slc,
    float* __restrict__ qp, float* __restrict__ kp) {
    int x = blockIdx.x;
    int nt = x & (NB - 1);
    int h = (x >> 5) & 7;
    int b = x >> 8;
    int o0 = offs[b];
    int len = offs[b + 1] - o0;
    int tid = threadIdx.x;
    size_t bh = (size_t)(b * H + h);
    int j = tid >> 3, dc = tid & 7;
    size_t pbase = (size_t)((b * NMAX + nt * BS + j)) * HD + h * D + dc * 16;
    if (nt * BS >= len) {
        if (tid < 128) {
            kc0[(bh * NB + nt) * 128 + tid] = 0;
            kc1[(bh * NB + nt) * 128 + tid] = 0;
            kc2[(bh * NB + nt) * 128 + tid] = 0;
            vt_cmp[(bh * 128 + tid) * NB + nt] = 0;
        }
        if (qp) {                       // zero padding region of qp/kp
            float4 z = make_float4(0.f, 0.f, 0.f, 0.f);
#pragma unroll
            for (int i = 0; i < 4; i++) {
                *(float4*)(qp + pbase + i * 4) = z;
                *(float4*)(kp + pbase + i * 4) = z;
            }
        }
        return;
    }

    __shared__ __align__(16) unsigned short tile[128 * 40];
    __shared__ float redK[4][128];
    __shared__ float redV[4][128];
    int w = tid >> 6, lane = tid & 63;
    size_t base = (size_t)(o0 + nt * BS + j) * HD + h * D + dc * 16;

    // zero this token/head slice of o_slc (replaces memset dispatch)
    {
        float4 z = make_float4(0.f, 0.f, 0.f, 0.f);
#pragma unroll
        for (int i = 0; i < 4; i++) *(float4*)(o_slc + base + i * 4) = z;
    }

    // K -> kb16 (bf16) + kp (fused pad) + block-mean partial
    {
        float xv[16];
        *(float4*)(xv + 0)  = *(const float4*)(k + base);
        *(float4*)(xv + 4)  = *(const float4*)(k + base + 4);
        *(float4*)(xv + 8)  = *(const float4*)(k + base + 8);
        *(float4*)(xv + 12) = *(const float4*)(k + base + 12);
        short8 lo, hi;
#pragma unroll
        for (int i = 0; i < 8; i++) { lo[i] = (short)f2bf(xv[i]); hi[i] = (short)f2bf(xv[8 + i]); }
        *(short8*)(kb16 + base) = lo;
        *(short8*)(kb16 + base + 8) = hi;
        if (kp) {
#pragma unroll
            for (int i = 0; i < 4; i++) *(float4*)(kp + pbase + i * 4) = *(float4*)(xv + i * 4);
        }
        // butterfly over the wave's 8 j-lanes (lane bits 3,4,5)
#pragma unroll
        for (int i = 0; i < 16; i++) {
            float s = xv[i];
            s += __shfl_xor(s, 8); s += __shfl_xor(s, 16); s += __shfl_xor(s, 32);
            if (lane < 8) redK[w][lane * 16 + i] = s;
        }
    }
    // V -> LDS transpose tile[d][j] + block-mean partial
    {
        float xv[16];
        *(float4*)(xv + 0)  = *(const float4*)(v + base);
        *(float4*)(xv + 4)  = *(const float4*)(v + base + 4);
        *(float4*)(xv + 8)  = *(const float4*)(v + base + 8);
        *(float4*)(xv + 12) = *(const float4*)(v + base + 12);
#pragma unroll
        for (int i = 0; i < 16; i++) tile[(dc * 16 + i) * 40 + j] = f2bf(xv[i]);
#pragma unroll
        for (int i = 0; i < 16; i++) {
            float s = xv[i];
            s += __shfl_xor(s, 8); s += __shfl_xor(s, 16); s += __shfl_xor(s, 32);
            if (lane < 8) redV[w][lane * 16 + i] = s;
        }
    }
    // gates (dot over this thread's 16 dims) + qp (fused pad)
    {
        float xv[16];
        *(float4*)(xv + 0)  = *(const float4*)(q + base);
        *(float4*)(xv + 4)  = *(const float4*)(q + base + 4);
        *(float4*)(xv + 8)  = *(const float4*)(q + base + 8);
        *(float4*)(xv + 12) = *(const float4*)(q + base + 12);
        if (qp) {
#pragma unroll
            for (int i = 0; i < 4; i++) *(float4*)(qp + pbase + i * 4) = *(float4*)(xv + i * 4);
        }
        float p0 = 0.f, p1 = 0.f;
#pragma unroll
        for (int i = 0; i < 16; i++) {
            int wb = (h * D + dc * 16 + i) * 3;
            p0 += xv[i] * Wg[wb + 0];
            p1 += xv[i] * Wg[wb + 1];
        }
#pragma unroll
        for (int off = 4; off > 0; off >>= 1) {
            p0 += __shfl_xor(p0, off);
            p1 += __shfl_xor(p1, off);
        }
        if (dc == 0) {
            float g0 = sigmoid_fast(p0 + bg[h * 3 + 0]);
            float g1 = sigmoid_fast(p1 + bg[h * 3 + 1]);
            float* gp = g + (size_t)((b * NMAX + nt * BS + j) * H + h) * 2;
            gp[0] = g0; gp[1] = g1;
        }
    }
    __syncthreads();
    // tile -> vt_blk (contiguous 8KB per (bh,nt))
    {
        int d = tid >> 1, hf = tid & 1;
        short8 a = *(const short8*)(tile + d * 40 + hf * 16);
        short8 c = *(const short8*)(tile + d * 40 + hf * 16 + 8);
        size_t ob = ((bh * NB + nt) * 128 + (size_t)d) * 32 + hf * 16;
        *(short8*)(vt_blk + ob) = a;
        *(short8*)(vt_blk + ob + 8) = c;
    }
    // means -> kc planes / vt_cmp
    if (tid < 128) {
        int d = tid;
        const float inv = 1.f / 32.f;
        float km = (redK[0][d] + redK[1][d] + redK[2][d] + redK[3][d]) * inv;
        float vm = (redV[0][d] + redV[1][d] + redV[2][d] + redV[3][d]) * inv;
        unsigned short e0, e1, e2;
        split3(km, e0, e1, e2);
        kc0[(bh * NB + nt) * 128 + d] = e0;
        kc1[(bh * NB + nt) * 128 + d] = e1;
        kc2[(bh * NB + nt) * 128 + d] = e2;
        vt_cmp[(bh * 128 + d) * NB + nt] = f2bf(vm);
    }
}

// ---------------------------------------------------------------------------
// K3a: compressed attention + top-8 selection, ONE 32-row q-block per WG.
// qblk dispatch REVERSED (heavy blocks first — LPT). For qblk<16 the jt=1
// waves skip Q split3 + QK (fully non-causal). Selection is RANK-BASED.
// MFMA layouts (m89/m120): A[m=lane&15][k=quad*8+j]; C/D col=lane&15,
// row=quad*4+reg.
// ---------------------------------------------------------------------------
__global__ __launch_bounds__(256) void cmp_attn(
    const float* __restrict__ q, const unsigned short* __restrict__ kc0,
    const unsigned short* __restrict__ kc1, const unsigned short* __restrict__ kc2,
    const unsigned short* __restrict__ vt_cmp, const float* __restrict__ g,
    const int* __restrict__ offs, unsigned* __restrict__ ms_g,
    float* __restrict__ o_cmp_j) {
    int x = blockIdx.x;                 // (b*H + h)*NB + qblk_idx
    int qblk = (NB - 1) - (x & (NB - 1));   // reversed: long blocks dispatch first
    int h = (x >> 5) & 7;
    int b = x >> 8;
    int o0 = offs[b];
    int len = offs[b + 1] - o0;
    if (qblk * BS >= len) return;
    size_t bh = (size_t)(b * H + h);

    // pool: R0/R1/R2 k_cmp planes (32x136), R3 v_cmp^T (128x40), Ps (32x40)
    __shared__ __align__(16) unsigned short pool[19456];
    __shared__ float Ss[32 * 33];
    unsigned short* R0 = pool;           // 4352
    unsigned short* R1 = pool + 4352;    // 4352
    unsigned short* R2 = pool + 8704;    // 4352
    unsigned short* R3 = pool + 13056;   // 5120
    unsigned short* Ps = pool + 18176;   // 1280 (32x40)

    int tid = threadIdx.x;
    int w = tid >> 6, lane = tid & 63;
    int r = lane & 15, quad = lane >> 4;
    int mt = w >> 1, jt = w & 1;        // row-half / col-half quadrant
    int stg_j = tid >> 3, stg_dc = tid & 7;

    // ---- stage kc planes (causal rows only) + vt_cmp ----
    if (stg_j <= qblk) {
        size_t src = (bh * NB + stg_j) * 128 + stg_dc * 16;
        int ofs = stg_j * 136 + stg_dc * 16;
        short8 a0 = *(const short8*)(kc0 + src);
        short8 b0 = *(const short8*)(kc0 + src + 8);
        short8 a1 = *(const short8*)(kc1 + src);
        short8 b1 = *(const short8*)(kc1 + src + 8);
        short8 a2 = *(const short8*)(kc2 + src);
        short8 b2 = *(const short8*)(kc2 + src + 8);
        *(short8*)(R0 + ofs) = a0; *(short8*)(R0 + ofs + 8) = b0;
        *(short8*)(R1 + ofs) = a1; *(short8*)(R1 + ofs + 8) = b1;
        *(short8*)(R2 + ofs) = a2; *(short8*)(R2 + ofs + 8) = b2;
    }
    {
        int d = tid >> 1, hf = tid & 1;
        short8 vv = *(const short8*)(vt_cmp + (bh * 128 + d) * NB + hf * 16);
        short8 vw = *(const short8*)(vt_cmp + (bh * 128 + d) * NB + hf * 16 + 8);
        *(short8*)(R3 + d * 40 + hf * 16) = vv;
        *(short8*)(R3 + d * 40 + hf * 16 + 8) = vw;
    }
    __syncthreads();

    // ---- Q fragments (3 planes) + QK — skipped when this wave's columns
    // (jt=1 -> 16..31) are entirely non-causal (qblk < 16)
    f32x4 sv = (f32x4){0.f, 0.f, 0.f, 0.f};
    if (jt == 0 || qblk >= 16) {
        short8 qf0[4], qf1[4], qf2[4];
        const float* qrow = q + (size_t)(o0 + qblk * BS + mt * 16 + r) * HD + h * D;
#pragma unroll
        for (int s = 0; s < 4; s++) {
            const float* p0 = qrow + s * 32 + quad * 8;
            float xv[8];
            *(float4*)(xv) = *(const float4*)p0;
            *(float4*)(xv + 4) = *(const float4*)(p0 + 4);
            short8 f0, f1, f2;
#pragma unroll
            for (int i = 0; i < 8; i++) {
                unsigned short e0, e1, e2;
                split3(xv[i], e0, e1, e2);
                f0[i] = (short)e0; f1[i] = (short)e1; f2[i] = (short)e2;
            }
            qf0[s] = f0; qf1[s] = f1; qf2[s] = f2;
        }
        // QK: 6 product rounds, small terms first
#pragma unroll
        for (int s = 0; s < 4; s++) {
            int ofs = (jt * 16 + r) * 136 + s * 32 + quad * 8;
            short8 k0 = *(const short8*)(R0 + ofs);
            short8 k1 = *(const short8*)(R1 + ofs);
            short8 k2 = *(const short8*)(R2 + ofs);
            sv = MFMA16(qf1[s], k1, sv);
            sv = MFMA16(qf0[s], k2, sv);
            sv = MFMA16(qf2[s], k0, sv);
            sv = MFMA16(qf0[s], k1, sv);
            sv = MFMA16(qf1[s], k0, sv);
            sv = MFMA16(qf0[s], k0, sv);
        }
    }
    int colj = jt * 16 + r;
    bool causal = (colj <= qblk);
#pragma unroll
    for (int i = 0; i < 4; i++) {
        int mrow = mt * 16 + quad * 4 + i;      // 0..31
        float sc = sv[i] * SCALE;
        Ss[mrow * 33 + colj] = causal ? sc : SENT;
        Ps[mrow * 40 + colj] = f2bf(causal ? silu(sc) : 0.f);
    }
    __syncthreads();

    // ---- PV -> o_cmp ----
    f32x4 accC[2][2];
#pragma unroll
    for (int a = 0; a < 2; a++)
#pragma unroll
        for (int c = 0; c < 2; c++) accC[a][c] = (f32x4){0.f, 0.f, 0.f, 0.f};
    {
        short8 pf0 = *(const short8*)(Ps + r * 40 + quad * 8);
        short8 pf1 = *(const short8*)(Ps + (16 + r) * 40 + quad * 8);
        short8 vf0 = *(const short8*)(R3 + ((2 * w + 0) * 16 + r) * 40 + quad * 8);
        short8 vf1 = *(const short8*)(R3 + ((2 * w + 1) * 16 + r) * 40 + quad * 8);
        accC[0][0] = MFMA16(pf0, vf0, accC[0][0]);
        accC[0][1] = MFMA16(pf0, vf1, accC[0][1]);
        accC[1][0] = MFMA16(pf1, vf0, accC[1][0]);
        accC[1][1] = MFMA16(pf1, vf1, accC[1][1]);
    }
    // ---- selection -> ms_g (rank + ballot) ----
    size_t msbase = (bh << 10) + (size_t)qblk * BS;
    if (qblk < S_SEL) {
        if (tid < BS) ms_g[msbase + tid] = (1u << (qblk + 1)) - 1u;
    } else {
        int h2 = lane >> 5, l32 = lane & 31;
#pragma unroll
        for (int pass = 0; pass < 4; pass++) {
            int row = w * 8 + pass * 2 + h2;
            float val = Ss[row * 33 + l32];
            int cnt = 0;
#pragma unroll
            for (int kk = 1; kk < 32; kk++) {
                int jj = (l32 + kk) & 31;
                float ov = __shfl(val, h2 * 32 + jj);
                if ((ov > val) || (ov == val && jj < l32)) cnt++;
            }
            bool sel = (cnt < S_SEL) && (val > -2.9e38f);
            unsigned long long bal = __ballot(sel);
            unsigned mask = (unsigned)(h2 ? (bal >> 32) : (bal & 0xffffffffULL));
            if (l32 == 0) ms_g[msbase + row] = mask;
        }
    }
    // ---- epilogue o_cmp ----
#pragma unroll
    for (int mtl = 0; mtl < 2; mtl++) {
#pragma unroll
        for (int i = 0; i < 4; i++) {
            int mrow = mtl * 16 + quad * 4 + i;
            int gm = qblk * BS + mrow;
            float gc = g[(size_t)((b * NMAX + gm) * H + h) * 2];
            float* dst = o_cmp_j + (size_t)(o0 + gm) * HD + h * D;
            dst[(2 * w + 0) * 16 + r] = accC[mtl][0][i] * gc;
            dst[(2 * w + 1) * 16 + r] = accC[mtl][1][i] * gc;
        }
    }
}

// ---------------------------------------------------------------------------
// K3b: selected attention — r7 structure (single barrier/iter, wave-local
// PV, K+V double-buffered LDS, register prefetch one FULL iteration ahead,
// KP=136 aligned, LPT). New: XCD-AWARE block mapping — all 64 blocks of a
// (b,h) land on ONE XCD (blockIdx%8 round-robins XCDs), so that head's
// kb16+vt_blk (~0.5MB; 4 heads/XCD ~2MB) stays resident in the private
// 4MB L2 instead of being re-fetched by all 8.
// Race-freedom with ONE barrier/iter: commit(i) targets buf[(i+1)%2], whose
// last readers finished before BAR(i-1), and whose next readers start after
// BAR(i). Ps write->read is same-wave (compiler lgkmcnt). fp32 partials ->
// atomicAdd into pre-zeroed o_slc_j (plain store for single-chunk tiles).
// ---------------------------------------------------------------------------
__global__ __launch_bounds__(256) void slc_attn(
    const float* __restrict__ q, const unsigned short* __restrict__ kb16,
    const unsigned short* __restrict__ vt_blk, const float* __restrict__ g,
    const int* __restrict__ offs, const unsigned* __restrict__ ms_g,
    float* __restrict__ o_slc_j) {
    int x = blockIdx.x;                 // grid = B*H*16*MC, XCD-grouped mapping
    int xcd = x & (NXCD - 1);
    int rest = x >> 3;
    int group = rest >> 6;              // 64 = 16 mtiles * MC chunks
    int inner = rest & 63;
    int bh = group * NXCD + xcd;        // all 64 blocks of bh on one XCD
    int b = bh >> 3, h = bh & 7;
    int chunk = inner & (MC - 1);
    int mtile = 15 - (inner >> 2);      // LPT: longest blocks dispatch first
    int o0 = offs[b];
    int len = offs[b + 1] - o0;
    if (mtile * 64 >= len) return;      // uniform exit (lens are multiples of 64)
    int qmax = 2 * mtile + 1;
    int kb0 = chunk * CHUNK;
    if (kb0 > qmax) return;
    int kend = min(qmax, kb0 + CHUNK - 1);

    // single pool: Kbuf0|Kbuf1 (32xKP) | VTbuf0|VTbuf1 (128x40) | Ps (64x40)
    __shared__ __align__(16) unsigned short pool[2 * 32 * KP + 2 * 5120 + 2560];
    __shared__ unsigned Ms[64];
    unsigned short* Kst0 = pool;                      // 4352
    unsigned short* Kst1 = pool + 32 * KP;            // 4352
    unsigned short* Vst0 = pool + 2 * 32 * KP;        // 5120
    unsigned short* Vst1 = pool + 2 * 32 * KP + 5120; // 5120
    unsigned short* Ps   = pool + 2 * 32 * KP + 10240;// 2560

    int tid = threadIdx.x;
    int w = tid >> 6, lane = tid & 63;
    int r = lane & 15, quad = lane >> 4;
    int stg_j = tid >> 3, stg_dc = tid & 7;

    if (tid < 64)
        Ms[tid] = ms_g[((size_t)bh << 10) + mtile * 64 + tid];

    // Q fragments (plane 0): wave w -> rows 16w + r
    short8 qs[4];
    {
        const float* qrow = q + (size_t)(o0 + mtile * 64 + w * 16 + r) * HD + h * D;
#pragma unroll
        for (int s = 0; s < 4; s++) {
            const float* p0 = qrow + s * 32 + quad * 8;
            float xv[8];
            *(float4*)(xv) = *(const float4*)p0;
            *(float4*)(xv + 4) = *(const float4*)(p0 + 4);
            short8 f;
#pragma unroll
            for (int i = 0; i < 8; i++) f[i] = (short)f2bf(xv[i]);
            qs[s] = f;
        }
    }
    f32x4 acc[8];                       // wave-local: rows [16w,16w+16), all 128 d
#pragma unroll
    for (int a = 0; a < 8; a++) acc[a] = (f32x4){0.f, 0.f, 0.f, 0.f};

    size_t vtbase = (size_t)(bh * NB) * 4096;
    int vd = tid >> 1, vhf = tid & 1;

    // prestage kb0 into Kst0 / Vst0
    {
        const unsigned short* ks = kb16 + (size_t)(o0 + kb0 * BS + stg_j) * HD + h * D + stg_dc * 16;
        short8 k0 = *(const short8*)ks;
        short8 k1 = *(const short8*)(ks + 8);
        *(short8*)(Kst0 + stg_j * KP + stg_dc * 16) = k0;
        *(short8*)(Kst0 + stg_j * KP + stg_dc * 16 + 8) = k1;
        const unsigned short* vs = vt_blk + vtbase + (size_t)kb0 * 4096 + tid * 16;
        short8 v0 = *(const short8*)vs;
        short8 v1 = *(const short8*)(vs + 8);
        *(short8*)(Vst0 + vd * 40 + vhf * 16) = v0;
        *(short8*)(Vst0 + vd * 40 + vhf * 16 + 8) = v1;
    }
    __syncthreads();

    int c = 0;
    for (int kb = kb0; kb <= kend; kb++) {
        short8 pk0, pk1, pv0, pv1;
        bool pf = (kb < kend);
        if (pf) {                       // prefetch kb+1 into registers
            const unsigned short* ks = kb16 + (size_t)(o0 + (kb + 1) * BS + stg_j) * HD + h * D + stg_dc * 16;
            pk0 = *(const short8*)ks;
            pk1 = *(const short8*)(ks + 8);
            const unsigned short* vs = vt_blk + vtbase + (size_t)(kb + 1) * 4096 + tid * 16;
            pv0 = *(const short8*)vs;
            pv1 = *(const short8*)(vs + 8);
        }
        // QK: wave w -> rows [16w,16w+16), both j-frags
        unsigned short* K = c ? Kst1 : Kst0;
        unsigned short* V = c ? Vst1 : Vst0;
        f32x4 s0 = (f32x4){0.f, 0.f, 0.f, 0.f};
        f32x4 s1 = (f32x4){0.f, 0.f, 0.f, 0.f};
#pragma unroll
        for (int s = 0; s < 4; s++) {
            short8 kf0 = *(const short8*)(K + r * KP + s * 32 + quad * 8);
            short8 kf1 = *(const short8*)(K + (16 + r) * KP + s * 32 + quad * 8);
            s0 = MFMA16(qs[s], kf0, s0);
            s1 = MFMA16(qs[s], kf1, s1);
        }
        // mask + silu -> OWN Ps slice (rows 16w..16w+15; wave-local)
#pragma unroll
        for (int jf = 0; jf < 2; jf++) {
            f32x4 svv = jf ? s1 : s0;
            int colj = jf * 16 + r;
            int kpos = kb * BS + colj;
#pragma unroll
            for (int i = 0; i < 4; i++) {
                int mrow = w * 16 + quad * 4 + i;
                int mpos = mtile * 64 + mrow;
                float p = (((Ms[mrow] >> kb) & 1u) && (kpos <= mpos))
                          ? silu(svv[i] * SCALE) : 0.f;
                Ps[mrow * 40 + colj] = f2bf(p);
            }
        }
        // PV: A = own P slice (same-wave LDS turnaround), B = 8 V^T d-frags
        {
            short8 pf8 = *(const short8*)(Ps + (w * 16 + r) * 40 + quad * 8);
#pragma unroll
            for (int nf = 0; nf < 8; nf++) {
                short8 vf = *(const short8*)(V + (nf * 16 + r) * 40 + quad * 8);
                acc[nf] = MFMA16(pf8, vf, acc[nf]);
            }
        }
        if (pf) {                       // commit prefetch into the other buffer
            unsigned short* Kn = c ? Kst0 : Kst1;
            unsigned short* Vn = c ? Vst0 : Vst1;
            *(short8*)(Kn + stg_j * KP + stg_dc * 16) = pk0;
            *(short8*)(Kn + stg_j * KP + stg_dc * 16 + 8) = pk1;
            *(short8*)(Vn + vd * 40 + vhf * 16) = pv0;
            *(short8*)(Vn + vd * 40 + vhf * 16 + 8) = pv1;
        }
        __syncthreads();                // single barrier per iteration
        c ^= 1;
    }

    // epilogue: wave w writes its rows [16w,16w+16), all 128 d
    bool single = (qmax < CHUNK);
#pragma unroll
    for (int i = 0; i < 4; i++) {
        int mrow = w * 16 + quad * 4 + i;
        int gm = mtile * 64 + mrow;
        float gs = g[(size_t)((b * NMAX + gm) * H + h) * 2 + 1];
        float* dst = o_slc_j + (size_t)(o0 + gm) * HD + h * D;
#pragma unroll
        for (int nf = 0; nf < 8; nf++) {
            float v0 = acc[nf][i] * gs;
            if (single) dst[nf * 16 + r] = v0;
            else        atomicAdd(dst + nf * 16 + r, v0);
        }
    }
}

// ---------------------------------------------------------------------------
// K4 (FALLBACK only — used when ws can't hold bf16 scratch and it aliases
// kp): padded qp, kp. Runs AFTER attention.
// ---------------------------------------------------------------------------
__global__ __launch_bounds__(256) void pad_qk_kernel(
    const float* __restrict__ q, const float* __restrict__ k,
    const int* __restrict__ offs,
    float* __restrict__ qp, float* __restrict__ kp) {
    int idx = blockIdx.x * 256 + threadIdx.x;       // float4 index over [B,n,H,D/4]
    int d4 = idx & 31;
    int h  = (idx >> 5) & 7;
    int m  = (idx >> 8) & (NMAX - 1);
    int b  = idx >> 18;
    int o0 = offs[b];
    int len = offs[b + 1] - o0;
    float4 qv = make_float4(0.f, 0.f, 0.f, 0.f);
    float4 kv = qv;
    if (m < len) {
        size_t src = (size_t)(o0 + m) * HD + h * D + d4 * 4;
        qv = *(const float4*)(q + src);
        kv = *(const float4*)(k + src);
    }
    *(float4*)(qp + (size_t)idx * 4) = qv;
    *(float4*)(kp + (size_t)idx * 4) = kv;
}

// ---------------------------------------------------------------------------
// K5: LayerNorm(1024) per stream, gate by u, sum -> out (oc may alias out)
// ---------------------------------------------------------------------------
__global__ __launch_bounds__(256) void ln_combine_kernel(
    const float* __restrict__ oc, const float* __restrict__ os,
    const float* __restrict__ u, float* __restrict__ out) {
    int t = blockIdx.x, tid = threadIdx.x;
    size_t base = (size_t)t * HD;
    float4 xc = *(const float4*)(oc + base + tid * 4);
    float4 xs = *(const float4*)(os + base + tid * 4);
    float4 uu = *(const float4*)(u + base + tid * 4);
    float s_c = xc.x + xc.y + xc.z + xc.w;
    float q_c = xc.x * xc.x + xc.y * xc.y + xc.z * xc.z + xc.w * xc.w;
    float s_s = xs.x + xs.y + xs.z + xs.w;
    float q_s = xs.x * xs.x + xs.y * xs.y + xs.z * xs.z + xs.w * xs.w;
#pragma unroll
    for (int off = 32; off > 0; off >>= 1) {
        s_c += __shfl_xor(s_c, off); q_c += __shfl_xor(q_c, off);
        s_s += __shfl_xor(s_s, off); q_s += __shfl_xor(q_s, off);
    }
    __shared__ float red[4][4];
    int w = tid >> 6, lane = tid & 63;
    if (lane == 0) {
        red[w][0] = s_c; red[w][1] = q_c; red[w][2] = s_s; red[w][3] = q_s;
    }
    __syncthreads();
    float tsc = red[0][0] + red[1][0] + red[2][0] + red[3][0];
    float tqc = red[0][1] + red[1][1] + red[2][1] + red[3][1];
    float tss = red[0][2] + red[1][2] + red[2][2] + red[3][2];
    float tqs = red[0][3] + red[1][3] + red[2][3] + red[3][3];
    const float inv = 1.f / 1024.f;
    float mc = tsc * inv, vc = tqc * inv - mc * mc;
    float ms = tss * inv, vs = tqs * inv - ms * ms;
    float rc = rsqrtf(vc + 1e-5f), rs = rsqrtf(vs + 1e-5f);
    float4 o;
    o.x = ((xc.x - mc) * rc + (xs.x - ms) * rs) * uu.x;
    o.y = ((xc.y - mc) * rc + (xs.y - ms) * rs) * uu.y;
    o.z = ((xc.z - mc) * rc + (xs.z - ms) * rs) * uu.z;
    o.w = ((xc.w - mc) * rc + (xs.w - ms) * rs) * uu.w;
    *(float4*)(out + base + tid * 4) = o;
}

// ---------------------------------------------------------------------------
extern "C" void kernel_launch(void* const* d_in, const int* in_sizes, int n_in,
                              void* d_out, int out_size, void* d_ws, size_t ws_size,
                              hipStream_t stream) {
    const float* q  = (const float*)d_in[0];
    const float* k  = (const float*)d_in[1];
    const float* v  = (const float*)d_in[2];
    const float* u  = (const float*)d_in[3];
    const float* Wg = (const float*)d_in[4];
    const float* bg = (const float*)d_in[5];
    const int* offs = (const int*)d_in[6];   // int32 (jnp default, x64 off)

    int B = in_sizes[6] - 1;
    int T = in_sizes[0] / HD;

    float* out = (float*)d_out;
    float* qp  = out + (size_t)T * HD;
    float* kp  = qp + (size_t)B * NMAX * HD;

    float* o_cmp_j = out;   // aliases final out (safe: see ln_combine)

    size_t plane = (size_t)B * H * NB * 128;        // elems per kc plane
    char* w = (char*)d_ws;
    unsigned short* kc0 = (unsigned short*)w;  w += plane * 2;
    unsigned short* kc1 = (unsigned short*)w;  w += plane * 2;
    unsigned short* kc2 = (unsigned short*)w;  w += plane * 2;
    unsigned short* vt_cmp = (unsigned short*)w; w += plane * 2;
    float* g     = (float*)w;            w += (size_t)B * NMAX * H * 2 * 4;
    unsigned* ms_g = (unsigned*)w;       w += (size_t)B * H * NMAX * 4;
    float* o_slc_j = (float*)w;          w += (size_t)T * HD * 4;

    // bf16 scratch: prefer ws tail (enables fused pad); else kp region
    size_t kb16_bytes = (size_t)T * HD * 2;
    size_t vt_bytes   = (size_t)B * H * NB * 128 * 32 * 2;
    size_t used = (size_t)(w - (char*)d_ws);
    bool fused_pad = (used + kb16_bytes + vt_bytes <= ws_size);
    char* scr = fused_pad ? w : (char*)kp;
    unsigned short* kb16  = (unsigned short*)scr;
    unsigned short* vt_blk = (unsigned short*)(scr + kb16_bytes);

    int prepBlocks = B * H * NB;
    int cmpAttnBlocks = B * H * NB;
    int slcBlocks  = B * H * 16 * MC;
    int padBlocks  = (B * NMAX * HD / 4) / 256;

    prep_kernel<<<prepBlocks, 256, 0, stream>>>(q, k, v, Wg, bg, offs, kb16, vt_blk,
                                                g, kc0, kc1, kc2, vt_cmp, o_slc_j,
                                                fused_pad ? qp : nullptr,
                                                fused_pad ? kp : nullptr);
    cmp_attn<<<cmpAttnBlocks, 256, 0, stream>>>(q, kc0, kc1, kc2, vt_cmp, g,
                                                offs, ms_g, o_cmp_j);
    slc_attn<<<slcBlocks, 256, 0, stream>>>(q, kb16, vt_blk, g, offs, ms_g, o_slc_j);
    if (!fused_pad)
        pad_qk_kernel<<<padBlocks, 256, 0, stream>>>(q, k, offs, qp, kp);
    ln_combine_kernel<<<T, 256, 0, stream>>>(o_cmp_j, o_slc_j, u, out);
}

// Round 9
// 187.746 us; speedup vs baseline: 1.4205x; 1.0610x over previous
//
#include <hip/hip_runtime.h>
#include <hip/hip_bf16.h>
#include <cmath>

#define H 8
#define D 128
#define HD 1024            // H*D
#define NMAX 1024
#define BS 32
#define NB 32
#define S_SEL 8
#define CHUNK 8            // kb blocks per slc_attn workgroup
#define MC 4               // chunks per mtile (NB/CHUNK)
#define KP 136             // K LDS pitch (shorts). MUST be mult of 8 (16B align for b128!)
#define NXCD 8
#define SCALE 0.08838834764831845f   // 1/sqrt(128)
#define SENT -3.0e38f

typedef __attribute__((ext_vector_type(8))) short short8;   // 8 bf16 = 4 VGPRs
typedef __attribute__((ext_vector_type(4))) float f32x4;    // MFMA acc

#define MFMA16(a, b, c) __builtin_amdgcn_mfma_f32_16x16x32_bf16(a, b, c, 0, 0, 0)

// fast silu: v_exp_f32 + v_rcp_f32 (~5 inst vs ~25 for libm expf + div).
// Feeds bf16 P values — bf16 rounding (2^-8) dominates native-exp err (2^-20).
__device__ __forceinline__ float silu(float x) {
    return x * __builtin_amdgcn_rcpf(1.f + __expf(-x));
}
__device__ __forceinline__ float sigmoid_fast(float x) {
    return __builtin_amdgcn_rcpf(1.f + __expf(-x));
}
__device__ __forceinline__ unsigned short f2bf(float x) {
    return __builtin_bit_cast(unsigned short, __float2bfloat16(x));
}
__device__ __forceinline__ float bfup(unsigned short b) {
    unsigned u = (unsigned)b << 16;
    return __builtin_bit_cast(float, u);
}
// 3-term bf16 split: x ~= b0 + b1 + b2 with |err| ~ 2^-27 |x|
__device__ __forceinline__ void split3(float x, unsigned short& b0,
                                       unsigned short& b1, unsigned short& b2) {
    b0 = f2bf(x);
    float r1 = x - bfup(b0);
    b1 = f2bf(r1);
    float r2 = r1 - bfup(b1);
    b2 = f2bf(r2);
}

// ---------------------------------------------------------------------------
// K1 prep: per (b,h,nt) 32-token block:
//   - kb16[tok][h][d]   : bf16 copy of K (straight convert, coalesced)
//   - vt_blk[bh][nt][d][j]: bf16 V^T in 8KB contiguous blocks (LDS transpose)
//   - g[b,m,h,{0,1}]    : gates (8-lane reduction, lanes share (tok,h))
//   - kc0/1/2[bh][nt][d]: split3 bf16 planes of the K block-mean
//   - vt_cmp[bh][d][nt] : bf16 V block-mean, transposed
//   - FUSED: qp/kp padded outputs + o_slc_j zeroing (replaces 2 dispatches)
// Invalid blocks (nt*BS >= len) zero kc/vt_cmp slots and their qp/kp slices.
// All lengths are multiples of 64, so valid blocks are fully valid.
// ---------------------------------------------------------------------------
__global__ __launch_bounds__(256) void prep_kernel(
    const float* __restrict__ q, const float* __restrict__ k,
    const float* __restrict__ v, const float* __restrict__ Wg,
    const float* __restrict__ bg, const int* __restrict__ offs,
    unsigned short* __restrict__ kb16, unsigned short* __restrict__ vt_blk,
    float* __restrict__ g, unsigned short* __restrict__ kc0,
    unsigned short* __restrict__ kc1, unsigned short* __restrict__ kc2,
    unsigned short* __restrict__ vt_cmp, float* __restrict__ o_slc,
    float* __restrict__ qp, float* __restrict__ kp) {
    int x = blockIdx.x;
    int nt = x & (NB - 1);
    int h = (x >> 5) & 7;
    int b = x >> 8;
    int o0 = offs[b];
    int len = offs[b + 1] - o0;
    int tid = threadIdx.x;
    size_t bh = (size_t)(b * H + h);
    int j = tid >> 3, dc = tid & 7;
    size_t pbase = (size_t)((b * NMAX + nt * BS + j)) * HD + h * D + dc * 16;
    if (nt * BS >= len) {
        if (tid < 128) {
            kc0[(bh * NB + nt) * 128 + tid] = 0;
            kc1[(bh * NB + nt) * 128 + tid] = 0;
            kc2[(bh * NB + nt) * 128 + tid] = 0;
            vt_cmp[(bh * 128 + tid) * NB + nt] = 0;
        }
        if (qp) {                       // zero padding region of qp/kp
            float4 z = make_float4(0.f, 0.f, 0.f, 0.f);
#pragma unroll
            for (int i = 0; i < 4; i++) {
                *(float4*)(qp + pbase + i * 4) = z;
                *(float4*)(kp + pbase + i * 4) = z;
            }
        }
        return;
    }

    __shared__ __align__(16) unsigned short tile[128 * 40];
    __shared__ float redK[4][128];
    __shared__ float redV[4][128];
    int w = tid >> 6, lane = tid & 63;
    size_t base = (size_t)(o0 + nt * BS + j) * HD + h * D + dc * 16;

    // zero this token/head slice of o_slc (replaces memset dispatch)
    {
        float4 z = make_float4(0.f, 0.f, 0.f, 0.f);
#pragma unroll
        for (int i = 0; i < 4; i++) *(float4*)(o_slc + base + i * 4) = z;
    }

    // K -> kb16 (bf16) + kp (fused pad) + block-mean partial
    {
        float xv[16];
        *(float4*)(xv + 0)  = *(const float4*)(k + base);
        *(float4*)(xv + 4)  = *(const float4*)(k + base + 4);
        *(float4*)(xv + 8)  = *(const float4*)(k + base + 8);
        *(float4*)(xv + 12) = *(const float4*)(k + base + 12);
        short8 lo, hi;
#pragma unroll
        for (int i = 0; i < 8; i++) { lo[i] = (short)f2bf(xv[i]); hi[i] = (short)f2bf(xv[8 + i]); }
        *(short8*)(kb16 + base) = lo;
        *(short8*)(kb16 + base + 8) = hi;
        if (kp) {
#pragma unroll
            for (int i = 0; i < 4; i++) *(float4*)(kp + pbase + i * 4) = *(float4*)(xv + i * 4);
        }
        // butterfly over the wave's 8 j-lanes (lane bits 3,4,5)
#pragma unroll
        for (int i = 0; i < 16; i++) {
            float s = xv[i];
            s += __shfl_xor(s, 8); s += __shfl_xor(s, 16); s += __shfl_xor(s, 32);
            if (lane < 8) redK[w][lane * 16 + i] = s;
        }
    }
    // V -> LDS transpose tile[d][j] + block-mean partial
    {
        float xv[16];
        *(float4*)(xv + 0)  = *(const float4*)(v + base);
        *(float4*)(xv + 4)  = *(const float4*)(v + base + 4);
        *(float4*)(xv + 8)  = *(const float4*)(v + base + 8);
        *(float4*)(xv + 12) = *(const float4*)(v + base + 12);
#pragma unroll
        for (int i = 0; i < 16; i++) tile[(dc * 16 + i) * 40 + j] = f2bf(xv[i]);
#pragma unroll
        for (int i = 0; i < 16; i++) {
            float s = xv[i];
            s += __shfl_xor(s, 8); s += __shfl_xor(s, 16); s += __shfl_xor(s, 32);
            if (lane < 8) redV[w][lane * 16 + i] = s;
        }
    }
    // gates (dot over this thread's 16 dims) + qp (fused pad)
    {
        float xv[16];
        *(float4*)(xv + 0)  = *(const float4*)(q + base);
        *(float4*)(xv + 4)  = *(const float4*)(q + base + 4);
        *(float4*)(xv + 8)  = *(const float4*)(q + base + 8);
        *(float4*)(xv + 12) = *(const float4*)(q + base + 12);
        if (qp) {
#pragma unroll
            for (int i = 0; i < 4; i++) *(float4*)(qp + pbase + i * 4) = *(float4*)(xv + i * 4);
        }
        float p0 = 0.f, p1 = 0.f;
#pragma unroll
        for (int i = 0; i < 16; i++) {
            int wb = (h * D + dc * 16 + i) * 3;
            p0 += xv[i] * Wg[wb + 0];
            p1 += xv[i] * Wg[wb + 1];
        }
#pragma unroll
        for (int off = 4; off > 0; off >>= 1) {
            p0 += __shfl_xor(p0, off);
            p1 += __shfl_xor(p1, off);
        }
        if (dc == 0) {
            float g0 = sigmoid_fast(p0 + bg[h * 3 + 0]);
            float g1 = sigmoid_fast(p1 + bg[h * 3 + 1]);
            float* gp = g + (size_t)((b * NMAX + nt * BS + j) * H + h) * 2;
            gp[0] = g0; gp[1] = g1;
        }
    }
    __syncthreads();
    // tile -> vt_blk (contiguous 8KB per (bh,nt))
    {
        int d = tid >> 1, hf = tid & 1;
        short8 a = *(const short8*)(tile + d * 40 + hf * 16);
        short8 c = *(const short8*)(tile + d * 40 + hf * 16 + 8);
        size_t ob = ((bh * NB + nt) * 128 + (size_t)d) * 32 + hf * 16;
        *(short8*)(vt_blk + ob) = a;
        *(short8*)(vt_blk + ob + 8) = c;
    }
    // means -> kc planes / vt_cmp
    if (tid < 128) {
        int d = tid;
        const float inv = 1.f / 32.f;
        float km = (redK[0][d] + redK[1][d] + redK[2][d] + redK[3][d]) * inv;
        float vm = (redV[0][d] + redV[1][d] + redV[2][d] + redV[3][d]) * inv;
        unsigned short e0, e1, e2;
        split3(km, e0, e1, e2);
        kc0[(bh * NB + nt) * 128 + d] = e0;
        kc1[(bh * NB + nt) * 128 + d] = e1;
        kc2[(bh * NB + nt) * 128 + d] = e2;
        vt_cmp[(bh * 128 + d) * NB + nt] = f2bf(vm);
    }
}

// ---------------------------------------------------------------------------
// K3a: compressed attention + top-8 selection, 64-ROW tile (2 qblks) per WG,
// fully WAVE-LOCAL (slc-proven shape). Wave w owns rows [16w,16w+16):
//  - loads/split3s ONLY its own Q rows (old version did it 2x per row),
//  - computes both QK j-frags itself (jf=1 skipped when qtile<8: cols 16-31
//    fully non-causal),
//  - selection IN REGISTERS: lane r of each 16-lane quad-group holds cols
//    {r, 16+r} of one row; rank = #{(vc,-c) > (v,-idx)} via 15 shfl_xor +
//    2 ballots -> Ms mask (same set as iterative max-pick w/ idx tiebreak),
//  - PV wave-local (A = own P rows, B = 8 vt_cmp d-frags).
// No Ss array, ONE barrier per block. qblk dispatch LPT-reversed.
// MFMA layouts (m89/m120): A[m=lane&15][k=quad*8+j]; C/D col=lane&15,
// row=quad*4+reg.
// ---------------------------------------------------------------------------
__global__ __launch_bounds__(256) void cmp_attn(
    const float* __restrict__ q, const unsigned short* __restrict__ kc0,
    const unsigned short* __restrict__ kc1, const unsigned short* __restrict__ kc2,
    const unsigned short* __restrict__ vt_cmp, const float* __restrict__ g,
    const int* __restrict__ offs, unsigned* __restrict__ ms_g,
    float* __restrict__ o_cmp_j) {
    int x = blockIdx.x;                 // (b*H + h)*16 + qtile_idx
    int qtile = 15 - (x & 15);          // reversed: long blocks dispatch first
    int h = (x >> 4) & 7;
    int b = x >> 7;
    int o0 = offs[b];
    int len = offs[b + 1] - o0;
    if (qtile * 64 >= len) return;
    size_t bh = (size_t)(b * H + h);
    int qmax = 2 * qtile + 1;           // last causal kc block for this tile

    // pool: R0/R1/R2 kc planes (32x136), R3 vt_cmp^T (128x40), Ps (64x40)
    __shared__ __align__(16) unsigned short pool[3 * 4352 + 5120 + 2560];
    unsigned short* R0 = pool;            // 4352
    unsigned short* R1 = pool + 4352;     // 4352
    unsigned short* R2 = pool + 8704;     // 4352
    unsigned short* R3 = pool + 13056;    // 5120
    unsigned short* Ps = pool + 18176;    // 2560 (64x40)

    int tid = threadIdx.x;
    int w = tid >> 6, lane = tid & 63;
    int r = lane & 15, quad = lane >> 4;
    int stg_j = tid >> 3, stg_dc = tid & 7;
    size_t msbase = (bh << 10) + (size_t)qtile * 64;

    // ---- stage kc planes (causal rows only) + vt_cmp ----
    if (stg_j <= qmax) {
        size_t src = (bh * NB + stg_j) * 128 + stg_dc * 16;
        int ofs = stg_j * 136 + stg_dc * 16;
        short8 a0 = *(const short8*)(kc0 + src);
        short8 b0 = *(const short8*)(kc0 + src + 8);
        short8 a1 = *(const short8*)(kc1 + src);
        short8 b1 = *(const short8*)(kc1 + src + 8);
        short8 a2 = *(const short8*)(kc2 + src);
        short8 b2 = *(const short8*)(kc2 + src + 8);
        *(short8*)(R0 + ofs) = a0; *(short8*)(R0 + ofs + 8) = b0;
        *(short8*)(R1 + ofs) = a1; *(short8*)(R1 + ofs + 8) = b1;
        *(short8*)(R2 + ofs) = a2; *(short8*)(R2 + ofs + 8) = b2;
    }
    {
        int d = tid >> 1, hf = tid & 1;
        short8 vv = *(const short8*)(vt_cmp + (bh * 128 + d) * NB + hf * 16);
        short8 vw = *(const short8*)(vt_cmp + (bh * 128 + d) * NB + hf * 16 + 8);
        *(short8*)(R3 + d * 40 + hf * 16) = vv;
        *(short8*)(R3 + d * 40 + hf * 16 + 8) = vw;
    }
    __syncthreads();                    // the only barrier

    // ---- Q fragments (3 planes) for OWN rows ----
    short8 qf0[4], qf1[4], qf2[4];
    {
        const float* qrow = q + (size_t)(o0 + qtile * 64 + w * 16 + r) * HD + h * D;
#pragma unroll
        for (int s = 0; s < 4; s++) {
            const float* p0 = qrow + s * 32 + quad * 8;
            float xv[8];
            *(float4*)(xv) = *(const float4*)p0;
            *(float4*)(xv + 4) = *(const float4*)(p0 + 4);
            short8 f0, f1, f2;
#pragma unroll
            for (int i = 0; i < 8; i++) {
                unsigned short e0, e1, e2;
                split3(xv[i], e0, e1, e2);
                f0[i] = (short)e0; f1[i] = (short)e1; f2[i] = (short)e2;
            }
            qf0[s] = f0; qf1[s] = f1; qf2[s] = f2;
        }
    }
    // ---- QK (6 product rounds, small terms first), per j-frag ----
    auto qk6 = [&](int krow) {
        f32x4 sv = (f32x4){0.f, 0.f, 0.f, 0.f};
#pragma unroll
        for (int s = 0; s < 4; s++) {
            int ofs = krow * 136 + s * 32 + quad * 8;
            short8 k0 = *(const short8*)(R0 + ofs);
            short8 k1 = *(const short8*)(R1 + ofs);
            short8 k2 = *(const short8*)(R2 + ofs);
            sv = MFMA16(qf1[s], k1, sv);
            sv = MFMA16(qf0[s], k2, sv);
            sv = MFMA16(qf2[s], k0, sv);
            sv = MFMA16(qf0[s], k1, sv);
            sv = MFMA16(qf1[s], k0, sv);
            sv = MFMA16(qf0[s], k0, sv);
        }
        return sv;
    };
    f32x4 s0 = qk6(r);
    f32x4 s1 = (f32x4){0.f, 0.f, 0.f, 0.f};
    if (qtile >= 8) s1 = qk6(16 + r);   // cols 16-31 all non-causal otherwise

    // ---- mask + silu -> own Ps rows; raw scores kept in regs for selection
    float v0[4], v1[4];
#pragma unroll
    for (int jf = 0; jf < 2; jf++) {
        f32x4 svv = jf ? s1 : s0;
        int colj = jf * 16 + r;
#pragma unroll
        for (int i = 0; i < 4; i++) {
            int mrow = w * 16 + quad * 4 + i;
            int qb = 2 * qtile + (mrow >> 5);
            bool causal = (colj <= qb);
            float sc = svv[i] * SCALE;
            float val = causal ? sc : SENT;
            if (jf) v1[i] = val; else v0[i] = val;
            Ps[mrow * 40 + colj] = f2bf(causal ? silu(sc) : 0.f);
        }
    }
    // ---- selection -> ms_g ----
    if (qtile < 4) {                    // both qblks < S_SEL: trivial masks
        if (tid < 64)
            ms_g[msbase + tid] = (1u << (2 * qtile + (tid >> 5) + 1)) - 1u;
    } else {                            // rank in registers + ballot
#pragma unroll
        for (int i = 0; i < 4; i++) {
            float a = v0[i], bb = v1[i];
            int cnt0 = (bb > a) ? 1 : 0;          // (16+r) beats r only if strictly greater
            int cnt1 = (a >= bb) ? 1 : 0;         // r beats 16+r on ties
#pragma unroll
            for (int m = 1; m < 16; m++) {
                float pa = __shfl_xor(a, m);      // stays in 16-lane quad-group
                float pb = __shfl_xor(bb, m);
                int pc = r ^ m;
                cnt0 += ((pa > a) || (pa == a && pc < r)) ? 1 : 0;
                cnt0 += (pb > a) ? 1 : 0;         // col 16+pc > r: no tie count
                cnt1 += ((pa > bb) || (pa == bb)) ? 1 : 0;   // pc < 16+r always
                cnt1 += ((pb > bb) || (pb == bb && pc < r)) ? 1 : 0;
            }
            bool sel0 = (cnt0 < S_SEL) && (a > -2.9e38f);
            bool sel1 = (cnt1 < S_SEL) && (bb > -2.9e38f);
            unsigned long long bal0 = __ballot(sel0);
            unsigned long long bal1 = __ballot(sel1);
            unsigned mask = (unsigned)((bal0 >> (16 * quad)) & 0xFFFFull)
                          | ((unsigned)((bal1 >> (16 * quad)) & 0xFFFFull) << 16);
            if (r == 0) ms_g[msbase + w * 16 + quad * 4 + i] = mask;
        }
    }
    // ---- PV -> o_cmp (wave-local: A = own P rows, B = 8 d-frags) ----
    f32x4 acc[8];
#pragma unroll
    for (int a = 0; a < 8; a++) acc[a] = (f32x4){0.f, 0.f, 0.f, 0.f};
    {
        short8 pf8 = *(const short8*)(Ps + (w * 16 + r) * 40 + quad * 8);
#pragma unroll
        for (int nf = 0; nf < 8; nf++) {
            short8 vf = *(const short8*)(R3 + (nf * 16 + r) * 40 + quad * 8);
            acc[nf] = MFMA16(pf8, vf, acc[nf]);
        }
    }
    // ---- epilogue o_cmp ----
#pragma unroll
    for (int i = 0; i < 4; i++) {
        int mrow = w * 16 + quad * 4 + i;
        int gm = qtile * 64 + mrow;
        float gc = g[(size_t)((b * NMAX + gm) * H + h) * 2];
        float* dst = o_cmp_j + (size_t)(o0 + gm) * HD + h * D;
#pragma unroll
        for (int nf = 0; nf < 8; nf++)
            dst[nf * 16 + r] = acc[nf][i] * gc;
    }
}

// ---------------------------------------------------------------------------
// K3b: selected attention — r8 structure (single barrier/iter, wave-local
// PV, K+V double-buffered LDS, register prefetch one FULL iteration ahead,
// KP=136 aligned, LPT, XCD-AWARE mapping: all 64 blocks of a (b,h) land on
// ONE XCD so its kb16+vt_blk (~0.5MB) stays L2-resident — FETCH 26.5->13.7MB
// measured r8).
// Race-freedom with ONE barrier/iter: commit(i) targets buf[(i+1)%2], whose
// last readers finished before BAR(i-1), and whose next readers start after
// BAR(i). Ps write->read is same-wave (compiler lgkmcnt). fp32 partials ->
// atomicAdd into pre-zeroed o_slc_j (plain store for single-chunk tiles).
// ---------------------------------------------------------------------------
__global__ __launch_bounds__(256) void slc_attn(
    const float* __restrict__ q, const unsigned short* __restrict__ kb16,
    const unsigned short* __restrict__ vt_blk, const float* __restrict__ g,
    const int* __restrict__ offs, const unsigned* __restrict__ ms_g,
    float* __restrict__ o_slc_j) {
    int x = blockIdx.x;                 // grid = B*H*16*MC, XCD-grouped mapping
    int xcd = x & (NXCD - 1);
    int rest = x >> 3;
    int group = rest >> 6;              // 64 = 16 mtiles * MC chunks
    int inner = rest & 63;
    int bh = group * NXCD + xcd;        // all 64 blocks of bh on one XCD
    int b = bh >> 3, h = bh & 7;
    int chunk = inner & (MC - 1);
    int mtile = 15 - (inner >> 2);      // LPT: longest blocks dispatch first
    int o0 = offs[b];
    int len = offs[b + 1] - o0;
    if (mtile * 64 >= len) return;      // uniform exit (lens are multiples of 64)
    int qmax = 2 * mtile + 1;
    int kb0 = chunk * CHUNK;
    if (kb0 > qmax) return;
    int kend = min(qmax, kb0 + CHUNK - 1);

    // single pool: Kbuf0|Kbuf1 (32xKP) | VTbuf0|VTbuf1 (128x40) | Ps (64x40)
    __shared__ __align__(16) unsigned short pool[2 * 32 * KP + 2 * 5120 + 2560];
    __shared__ unsigned Ms[64];
    unsigned short* Kst0 = pool;                      // 4352
    unsigned short* Kst1 = pool + 32 * KP;            // 4352
    unsigned short* Vst0 = pool + 2 * 32 * KP;        // 5120
    unsigned short* Vst1 = pool + 2 * 32 * KP + 5120; // 5120
    unsigned short* Ps   = pool + 2 * 32 * KP + 10240;// 2560

    int tid = threadIdx.x;
    int w = tid >> 6, lane = tid & 63;
    int r = lane & 15, quad = lane >> 4;
    int stg_j = tid >> 3, stg_dc = tid & 7;

    if (tid < 64)
        Ms[tid] = ms_g[((size_t)bh << 10) + mtile * 64 + tid];

    // Q fragments (plane 0): wave w -> rows 16w + r
    short8 qs[4];
    {
        const float* qrow = q + (size_t)(o0 + mtile * 64 + w * 16 + r) * HD + h * D;
#pragma unroll
        for (int s = 0; s < 4; s++) {
            const float* p0 = qrow + s * 32 + quad * 8;
            float xv[8];
            *(float4*)(xv) = *(const float4*)p0;
            *(float4*)(xv + 4) = *(const float4*)(p0 + 4);
            short8 f;
#pragma unroll
            for (int i = 0; i < 8; i++) f[i] = (short)f2bf(xv[i]);
            qs[s] = f;
        }
    }
    f32x4 acc[8];                       // wave-local: rows [16w,16w+16), all 128 d
#pragma unroll
    for (int a = 0; a < 8; a++) acc[a] = (f32x4){0.f, 0.f, 0.f, 0.f};

    size_t vtbase = (size_t)(bh * NB) * 4096;
    int vd = tid >> 1, vhf = tid & 1;

    // prestage kb0 into Kst0 / Vst0
    {
        const unsigned short* ks = kb16 + (size_t)(o0 + kb0 * BS + stg_j) * HD + h * D + stg_dc * 16;
        short8 k0 = *(const short8*)ks;
        short8 k1 = *(const short8*)(ks + 8);
        *(short8*)(Kst0 + stg_j * KP + stg_dc * 16) = k0;
        *(short8*)(Kst0 + stg_j * KP + stg_dc * 16 + 8) = k1;
        const unsigned short* vs = vt_blk + vtbase + (size_t)kb0 * 4096 + tid * 16;
        short8 v0 = *(const short8*)vs;
        short8 v1 = *(const short8*)(vs + 8);
        *(short8*)(Vst0 + vd * 40 + vhf * 16) = v0;
        *(short8*)(Vst0 + vd * 40 + vhf * 16 + 8) = v1;
    }
    __syncthreads();

    int c = 0;
    for (int kb = kb0; kb <= kend; kb++) {
        short8 pk0, pk1, pv0, pv1;
        bool pf = (kb < kend);
        if (pf) {                       // prefetch kb+1 into registers
            const unsigned short* ks = kb16 + (size_t)(o0 + (kb + 1) * BS + stg_j) * HD + h * D + stg_dc * 16;
            pk0 = *(const short8*)ks;
            pk1 = *(const short8*)(ks + 8);
            const unsigned short* vs = vt_blk + vtbase + (size_t)(kb + 1) * 4096 + tid * 16;
            pv0 = *(const short8*)vs;
            pv1 = *(const short8*)(vs + 8);
        }
        // QK: wave w -> rows [16w,16w+16), both j-frags
        unsigned short* K = c ? Kst1 : Kst0;
        unsigned short* V = c ? Vst1 : Vst0;
        f32x4 s0 = (f32x4){0.f, 0.f, 0.f, 0.f};
        f32x4 s1 = (f32x4){0.f, 0.f, 0.f, 0.f};
#pragma unroll
        for (int s = 0; s < 4; s++) {
            short8 kf0 = *(const short8*)(K + r * KP + s * 32 + quad * 8);
            short8 kf1 = *(const short8*)(K + (16 + r) * KP + s * 32 + quad * 8);
            s0 = MFMA16(qs[s], kf0, s0);
            s1 = MFMA16(qs[s], kf1, s1);
        }
        // mask + silu -> OWN Ps slice (rows 16w..16w+15; wave-local)
#pragma unroll
        for (int jf = 0; jf < 2; jf++) {
            f32x4 svv = jf ? s1 : s0;
            int colj = jf * 16 + r;
            int kpos = kb * BS + colj;
#pragma unroll
            for (int i = 0; i < 4; i++) {
                int mrow = w * 16 + quad * 4 + i;
                int mpos = mtile * 64 + mrow;
                float p = (((Ms[mrow] >> kb) & 1u) && (kpos <= mpos))
                          ? silu(svv[i] * SCALE) : 0.f;
                Ps[mrow * 40 + colj] = f2bf(p);
            }
        }
        // PV: A = own P slice (same-wave LDS turnaround), B = 8 V^T d-frags
        {
            short8 pf8 = *(const short8*)(Ps + (w * 16 + r) * 40 + quad * 8);
#pragma unroll
            for (int nf = 0; nf < 8; nf++) {
                short8 vf = *(const short8*)(V + (nf * 16 + r) * 40 + quad * 8);
                acc[nf] = MFMA16(pf8, vf, acc[nf]);
            }
        }
        if (pf) {                       // commit prefetch into the other buffer
            unsigned short* Kn = c ? Kst0 : Kst1;
            unsigned short* Vn = c ? Vst0 : Vst1;
            *(short8*)(Kn + stg_j * KP + stg_dc * 16) = pk0;
            *(short8*)(Kn + stg_j * KP + stg_dc * 16 + 8) = pk1;
            *(short8*)(Vn + vd * 40 + vhf * 16) = pv0;
            *(short8*)(Vn + vd * 40 + vhf * 16 + 8) = pv1;
        }
        __syncthreads();                // single barrier per iteration
        c ^= 1;
    }

    // epilogue: wave w writes its rows [16w,16w+16), all 128 d
    bool single = (qmax < CHUNK);
#pragma unroll
    for (int i = 0; i < 4; i++) {
        int mrow = w * 16 + quad * 4 + i;
        int gm = mtile * 64 + mrow;
        float gs = g[(size_t)((b * NMAX + gm) * H + h) * 2 + 1];
        float* dst = o_slc_j + (size_t)(o0 + gm) * HD + h * D;
#pragma unroll
        for (int nf = 0; nf < 8; nf++) {
            float v0 = acc[nf][i] * gs;
            if (single) dst[nf * 16 + r] = v0;
            else        atomicAdd(dst + nf * 16 + r, v0);
        }
    }
}

// ---------------------------------------------------------------------------
// K4 (FALLBACK only — used when ws can't hold bf16 scratch and it aliases
// kp): padded qp, kp. Runs AFTER attention.
// ---------------------------------------------------------------------------
__global__ __launch_bounds__(256) void pad_qk_kernel(
    const float* __restrict__ q, const float* __restrict__ k,
    const int* __restrict__ offs,
    float* __restrict__ qp, float* __restrict__ kp) {
    int idx = blockIdx.x * 256 + threadIdx.x;       // float4 index over [B,n,H,D/4]
    int d4 = idx & 31;
    int h  = (idx >> 5) & 7;
    int m  = (idx >> 8) & (NMAX - 1);
    int b  = idx >> 18;
    int o0 = offs[b];
    int len = offs[b + 1] - o0;
    float4 qv = make_float4(0.f, 0.f, 0.f, 0.f);
    float4 kv = qv;
    if (m < len) {
        size_t src = (size_t)(o0 + m) * HD + h * D + d4 * 4;
        qv = *(const float4*)(q + src);
        kv = *(const float4*)(k + src);
    }
    *(float4*)(qp + (size_t)idx * 4) = qv;
    *(float4*)(kp + (size_t)idx * 4) = kv;
}

// ---------------------------------------------------------------------------
// K5: LayerNorm(1024) per stream, gate by u, sum -> out (oc may alias out)
// ---------------------------------------------------------------------------
__global__ __launch_bounds__(256) void ln_combine_kernel(
    const float* __restrict__ oc, const float* __restrict__ os,
    const float* __restrict__ u, float* __restrict__ out) {
    int t = blockIdx.x, tid = threadIdx.x;
    size_t base = (size_t)t * HD;
    float4 xc = *(const float4*)(oc + base + tid * 4);
    float4 xs = *(const float4*)(os + base + tid * 4);
    float4 uu = *(const float4*)(u + base + tid * 4);
    float s_c = xc.x + xc.y + xc.z + xc.w;
    float q_c = xc.x * xc.x + xc.y * xc.y + xc.z * xc.z + xc.w * xc.w;
    float s_s = xs.x + xs.y + xs.z + xs.w;
    float q_s = xs.x * xs.x + xs.y * xs.y + xs.z * xs.z + xs.w * xs.w;
#pragma unroll
    for (int off = 32; off > 0; off >>= 1) {
        s_c += __shfl_xor(s_c, off); q_c += __shfl_xor(q_c, off);
        s_s += __shfl_xor(s_s, off); q_s += __shfl_xor(q_s, off);
    }
    __shared__ float red[4][4];
    int w = tid >> 6, lane = tid & 63;
    if (lane == 0) {
        red[w][0] = s_c; red[w][1] = q_c; red[w][2] = s_s; red[w][3] = q_s;
    }
    __syncthreads();
    float tsc = red[0][0] + red[1][0] + red[2][0] + red[3][0];
    float tqc = red[0][1] + red[1][1] + red[2][1] + red[3][1];
    float tss = red[0][2] + red[1][2] + red[2][2] + red[3][2];
    float tqs = red[0][3] + red[1][3] + red[2][3] + red[3][3];
    const float inv = 1.f / 1024.f;
    float mc = tsc * inv, vc = tqc * inv - mc * mc;
    float ms = tss * inv, vs = tqs * inv - ms * ms;
    float rc = rsqrtf(vc + 1e-5f), rs = rsqrtf(vs + 1e-5f);
    float4 o;
    o.x = ((xc.x - mc) * rc + (xs.x - ms) * rs) * uu.x;
    o.y = ((xc.y - mc) * rc + (xs.y - ms) * rs) * uu.y;
    o.z = ((xc.z - mc) * rc + (xs.z - ms) * rs) * uu.z;
    o.w = ((xc.w - mc) * rc + (xs.w - ms) * rs) * uu.w;
    *(float4*)(out + base + tid * 4) = o;
}

// ---------------------------------------------------------------------------
extern "C" void kernel_launch(void* const* d_in, const int* in_sizes, int n_in,
                              void* d_out, int out_size, void* d_ws, size_t ws_size,
                              hipStream_t stream) {
    const float* q  = (const float*)d_in[0];
    const float* k  = (const float*)d_in[1];
    const float* v  = (const float*)d_in[2];
    const float* u  = (const float*)d_in[3];
    const float* Wg = (const float*)d_in[4];
    const float* bg = (const float*)d_in[5];
    const int* offs = (const int*)d_in[6];   // int32 (jnp default, x64 off)

    int B = in_sizes[6] - 1;
    int T = in_sizes[0] / HD;

    float* out = (float*)d_out;
    float* qp  = out + (size_t)T * HD;
    float* kp  = qp + (size_t)B * NMAX * HD;

    float* o_cmp_j = out;   // aliases final out (safe: see ln_combine)

    size_t plane = (size_t)B * H * NB * 128;        // elems per kc plane
    char* w = (char*)d_ws;
    unsigned short* kc0 = (unsigned short*)w;  w += plane * 2;
    unsigned short* kc1 = (unsigned short*)w;  w += plane * 2;
    unsigned short* kc2 = (unsigned short*)w;  w += plane * 2;
    unsigned short* vt_cmp = (unsigned short*)w; w += plane * 2;
    float* g     = (float*)w;            w += (size_t)B * NMAX * H * 2 * 4;
    unsigned* ms_g = (unsigned*)w;       w += (size_t)B * H * NMAX * 4;
    float* o_slc_j = (float*)w;          w += (size_t)T * HD * 4;

    // bf16 scratch: prefer ws tail (enables fused pad); else kp region
    size_t kb16_bytes = (size_t)T * HD * 2;
    size_t vt_bytes   = (size_t)B * H * NB * 128 * 32 * 2;
    size_t used = (size_t)(w - (char*)d_ws);
    bool fused_pad = (used + kb16_bytes + vt_bytes <= ws_size);
    char* scr = fused_pad ? w : (char*)kp;
    unsigned short* kb16  = (unsigned short*)scr;
    unsigned short* vt_blk = (unsigned short*)(scr + kb16_bytes);

    int prepBlocks = B * H * NB;
    int cmpAttnBlocks = B * H * 16;
    int slcBlocks  = B * H * 16 * MC;
    int padBlocks  = (B * NMAX * HD / 4) / 256;

    prep_kernel<<<prepBlocks, 256, 0, stream>>>(q, k, v, Wg, bg, offs, kb16, vt_blk,
                                                g, kc0, kc1, kc2, vt_cmp, o_slc_j,
                                                fused_pad ? qp : nullptr,
                                                fused_pad ? kp : nullptr);
    cmp_attn<<<cmpAttnBlocks, 256, 0, stream>>>(q, kc0, kc1, kc2, vt_cmp, g,
                                                offs, ms_g, o_cmp_j);
    slc_attn<<<slcBlocks, 256, 0, stream>>>(q, kb16, vt_blk, g, offs, ms_g, o_slc_j);
    if (!fused_pad)
        pad_qk_kernel<<<padBlocks, 256, 0, stream>>>(q, k, offs, qp, kp);
    ln_combine_kernel<<<T, 256, 0, stream>>>(o_cmp_j, o_slc_j, u, out);
}

// Round 10
// 186.269 us; speedup vs baseline: 1.4318x; 1.0079x over previous
//
#include <hip/hip_runtime.h>
#include <hip/hip_bf16.h>
#include <cmath>

#define H 8
#define D 128
#define HD 1024            // H*D
#define NMAX 1024
#define BS 32
#define NB 32
#define S_SEL 8
#define CHUNK 8            // kb blocks per slc_attn workgroup
#define MC 4               // chunks per mtile (NB/CHUNK)
#define KP 136             // K LDS pitch (shorts). MUST be mult of 8 (16B align for b128!)
#define NXCD 8
#define SCALE 0.08838834764831845f   // 1/sqrt(128)
#define SENT -3.0e38f

typedef __attribute__((ext_vector_type(8))) short short8;   // 8 bf16 = 4 VGPRs
typedef __attribute__((ext_vector_type(4))) float f32x4;    // MFMA acc

#define MFMA16(a, b, c) __builtin_amdgcn_mfma_f32_16x16x32_bf16(a, b, c, 0, 0, 0)

// fast silu: v_exp_f32 + v_rcp_f32 (~5 inst vs ~25 for libm expf + div).
// Feeds bf16 P values — bf16 rounding (2^-8) dominates native-exp err (2^-20).
__device__ __forceinline__ float silu(float x) {
    return x * __builtin_amdgcn_rcpf(1.f + __expf(-x));
}
__device__ __forceinline__ float sigmoid_fast(float x) {
    return __builtin_amdgcn_rcpf(1.f + __expf(-x));
}
__device__ __forceinline__ unsigned short f2bf(float x) {
    return __builtin_bit_cast(unsigned short, __float2bfloat16(x));
}
__device__ __forceinline__ float bfup(unsigned short b) {
    unsigned u = (unsigned)b << 16;
    return __builtin_bit_cast(float, u);
}
// 3-term bf16 split: x ~= b0 + b1 + b2 with |err| ~ 2^-27 |x|
__device__ __forceinline__ void split3(float x, unsigned short& b0,
                                       unsigned short& b1, unsigned short& b2) {
    b0 = f2bf(x);
    float r1 = x - bfup(b0);
    b1 = f2bf(r1);
    float r2 = r1 - bfup(b1);
    b2 = f2bf(r2);
}

// ---------------------------------------------------------------------------
// K1 prep: per (b,h,nt) 32-token block:
//   - kb16[tok][h][d]   : bf16 copy of K (straight convert, coalesced)
//   - vt_blk[bh][nt][d][j]: bf16 V^T in 8KB contiguous blocks (LDS transpose)
//   - g[b,m,h,{0,1}]    : gates (8-lane reduction, lanes share (tok,h))
//   - kc0/1/2[bh][nt][d]: split3 bf16 planes of the K block-mean
//   - vt_cmp[bh][d][nt] : bf16 V block-mean, transposed
//   - FUSED: qp/kp padded outputs + o_slc_j zeroing (only nt>=8 — rows in
//     single-chunk mtiles get plain stores from slc, no zero needed)
// Invalid blocks (nt*BS >= len) zero kc/vt_cmp slots and their qp/kp slices.
// All lengths are multiples of 64, so valid blocks are fully valid.
// ---------------------------------------------------------------------------
__global__ __launch_bounds__(256) void prep_kernel(
    const float* __restrict__ q, const float* __restrict__ k,
    const float* __restrict__ v, const float* __restrict__ Wg,
    const float* __restrict__ bg, const int* __restrict__ offs,
    unsigned short* __restrict__ kb16, unsigned short* __restrict__ vt_blk,
    float* __restrict__ g, unsigned short* __restrict__ kc0,
    unsigned short* __restrict__ kc1, unsigned short* __restrict__ kc2,
    unsigned short* __restrict__ vt_cmp, float* __restrict__ o_slc,
    float* __restrict__ qp, float* __restrict__ kp) {
    int x = blockIdx.x;
    int nt = x & (NB - 1);
    int h = (x >> 5) & 7;
    int b = x >> 8;
    int o0 = offs[b];
    int len = offs[b + 1] - o0;
    int tid = threadIdx.x;
    size_t bh = (size_t)(b * H + h);
    int j = tid >> 3, dc = tid & 7;
    size_t pbase = (size_t)((b * NMAX + nt * BS + j)) * HD + h * D + dc * 16;
    if (nt * BS >= len) {
        if (tid < 128) {
            kc0[(bh * NB + nt) * 128 + tid] = 0;
            kc1[(bh * NB + nt) * 128 + tid] = 0;
            kc2[(bh * NB + nt) * 128 + tid] = 0;
            vt_cmp[(bh * 128 + tid) * NB + nt] = 0;
        }
        if (qp) {                       // zero padding region of qp/kp
            float4 z = make_float4(0.f, 0.f, 0.f, 0.f);
#pragma unroll
            for (int i = 0; i < 4; i++) {
                *(float4*)(qp + pbase + i * 4) = z;
                *(float4*)(kp + pbase + i * 4) = z;
            }
        }
        return;
    }

    __shared__ __align__(16) unsigned short tile[128 * 40];
    __shared__ float redK[4][128];
    __shared__ float redV[4][128];
    int w = tid >> 6, lane = tid & 63;
    size_t base = (size_t)(o0 + nt * BS + j) * HD + h * D + dc * 16;

    // zero this token/head slice of o_slc — ONLY rows that slc atomically
    // accumulates into (multi-chunk mtiles, nt >= 8; nt < 8 gets plain store)
    if (nt >= 8) {
        float4 z = make_float4(0.f, 0.f, 0.f, 0.f);
#pragma unroll
        for (int i = 0; i < 4; i++) *(float4*)(o_slc + base + i * 4) = z;
    }

    // K -> kb16 (bf16) + kp (fused pad) + block-mean partial
    {
        float xv[16];
        *(float4*)(xv + 0)  = *(const float4*)(k + base);
        *(float4*)(xv + 4)  = *(const float4*)(k + base + 4);
        *(float4*)(xv + 8)  = *(const float4*)(k + base + 8);
        *(float4*)(xv + 12) = *(const float4*)(k + base + 12);
        short8 lo, hi;
#pragma unroll
        for (int i = 0; i < 8; i++) { lo[i] = (short)f2bf(xv[i]); hi[i] = (short)f2bf(xv[8 + i]); }
        *(short8*)(kb16 + base) = lo;
        *(short8*)(kb16 + base + 8) = hi;
        if (kp) {
#pragma unroll
            for (int i = 0; i < 4; i++) *(float4*)(kp + pbase + i * 4) = *(float4*)(xv + i * 4);
        }
        // butterfly over the wave's 8 j-lanes (lane bits 3,4,5)
#pragma unroll
        for (int i = 0; i < 16; i++) {
            float s = xv[i];
            s += __shfl_xor(s, 8); s += __shfl_xor(s, 16); s += __shfl_xor(s, 32);
            if (lane < 8) redK[w][lane * 16 + i] = s;
        }
    }
    // V -> LDS transpose tile[d][j] + block-mean partial
    {
        float xv[16];
        *(float4*)(xv + 0)  = *(const float4*)(v + base);
        *(float4*)(xv + 4)  = *(const float4*)(v + base + 4);
        *(float4*)(xv + 8)  = *(const float4*)(v + base + 8);
        *(float4*)(xv + 12) = *(const float4*)(v + base + 12);
#pragma unroll
        for (int i = 0; i < 16; i++) tile[(dc * 16 + i) * 40 + j] = f2bf(xv[i]);
#pragma unroll
        for (int i = 0; i < 16; i++) {
            float s = xv[i];
            s += __shfl_xor(s, 8); s += __shfl_xor(s, 16); s += __shfl_xor(s, 32);
            if (lane < 8) redV[w][lane * 16 + i] = s;
        }
    }
    // gates (dot over this thread's 16 dims) + qp (fused pad)
    {
        float xv[16];
        *(float4*)(xv + 0)  = *(const float4*)(q + base);
        *(float4*)(xv + 4)  = *(const float4*)(q + base + 4);
        *(float4*)(xv + 8)  = *(const float4*)(q + base + 8);
        *(float4*)(xv + 12) = *(const float4*)(q + base + 12);
        if (qp) {
#pragma unroll
            for (int i = 0; i < 4; i++) *(float4*)(qp + pbase + i * 4) = *(float4*)(xv + i * 4);
        }
        float p0 = 0.f, p1 = 0.f;
#pragma unroll
        for (int i = 0; i < 16; i++) {
            int wb = (h * D + dc * 16 + i) * 3;
            p0 += xv[i] * Wg[wb + 0];
            p1 += xv[i] * Wg[wb + 1];
        }
#pragma unroll
        for (int off = 4; off > 0; off >>= 1) {
            p0 += __shfl_xor(p0, off);
            p1 += __shfl_xor(p1, off);
        }
        if (dc == 0) {
            float g0 = sigmoid_fast(p0 + bg[h * 3 + 0]);
            float g1 = sigmoid_fast(p1 + bg[h * 3 + 1]);
            float* gp = g + (size_t)((b * NMAX + nt * BS + j) * H + h) * 2;
            gp[0] = g0; gp[1] = g1;
        }
    }
    __syncthreads();
    // tile -> vt_blk (contiguous 8KB per (bh,nt))
    {
        int d = tid >> 1, hf = tid & 1;
        short8 a = *(const short8*)(tile + d * 40 + hf * 16);
        short8 c = *(const short8*)(tile + d * 40 + hf * 16 + 8);
        size_t ob = ((bh * NB + nt) * 128 + (size_t)d) * 32 + hf * 16;
        *(short8*)(vt_blk + ob) = a;
        *(short8*)(vt_blk + ob + 8) = c;
    }
    // means -> kc planes / vt_cmp
    if (tid < 128) {
        int d = tid;
        const float inv = 1.f / 32.f;
        float km = (redK[0][d] + redK[1][d] + redK[2][d] + redK[3][d]) * inv;
        float vm = (redV[0][d] + redV[1][d] + redV[2][d] + redV[3][d]) * inv;
        unsigned short e0, e1, e2;
        split3(km, e0, e1, e2);
        kc0[(bh * NB + nt) * 128 + d] = e0;
        kc1[(bh * NB + nt) * 128 + d] = e1;
        kc2[(bh * NB + nt) * 128 + d] = e2;
        vt_cmp[(bh * 128 + d) * NB + nt] = f2bf(vm);
    }
}

// ---------------------------------------------------------------------------
// K3a: compressed attention + top-8 selection, 64-ROW tile (2 qblks) per WG,
// fully WAVE-LOCAL (slc-proven shape, r9-verified). Wave w owns rows
// [16w,16w+16); selection in registers via 15 shfl_xor + 2 ballots; one
// barrier per block. qblk dispatch LPT-reversed.
// MFMA layouts (m89/m120): A[m=lane&15][k=quad*8+j]; C/D col=lane&15,
// row=quad*4+reg.
// ---------------------------------------------------------------------------
__global__ __launch_bounds__(256) void cmp_attn(
    const float* __restrict__ q, const unsigned short* __restrict__ kc0,
    const unsigned short* __restrict__ kc1, const unsigned short* __restrict__ kc2,
    const unsigned short* __restrict__ vt_cmp, const float* __restrict__ g,
    const int* __restrict__ offs, unsigned* __restrict__ ms_g,
    float* __restrict__ o_cmp_j) {
    int x = blockIdx.x;                 // (b*H + h)*16 + qtile_idx
    int qtile = 15 - (x & 15);          // reversed: long blocks dispatch first
    int h = (x >> 4) & 7;
    int b = x >> 7;
    int o0 = offs[b];
    int len = offs[b + 1] - o0;
    if (qtile * 64 >= len) return;
    size_t bh = (size_t)(b * H + h);
    int qmax = 2 * qtile + 1;           // last causal kc block for this tile

    // pool: R0/R1/R2 kc planes (32x136), R3 vt_cmp^T (128x40), Ps (64x40)
    __shared__ __align__(16) unsigned short pool[3 * 4352 + 5120 + 2560];
    unsigned short* R0 = pool;            // 4352
    unsigned short* R1 = pool + 4352;     // 4352
    unsigned short* R2 = pool + 8704;     // 4352
    unsigned short* R3 = pool + 13056;    // 5120
    unsigned short* Ps = pool + 18176;    // 2560 (64x40)

    int tid = threadIdx.x;
    int w = tid >> 6, lane = tid & 63;
    int r = lane & 15, quad = lane >> 4;
    int stg_j = tid >> 3, stg_dc = tid & 7;
    size_t msbase = (bh << 10) + (size_t)qtile * 64;

    // ---- stage kc planes (causal rows only) + vt_cmp ----
    if (stg_j <= qmax) {
        size_t src = (bh * NB + stg_j) * 128 + stg_dc * 16;
        int ofs = stg_j * 136 + stg_dc * 16;
        short8 a0 = *(const short8*)(kc0 + src);
        short8 b0 = *(const short8*)(kc0 + src + 8);
        short8 a1 = *(const short8*)(kc1 + src);
        short8 b1 = *(const short8*)(kc1 + src + 8);
        short8 a2 = *(const short8*)(kc2 + src);
        short8 b2 = *(const short8*)(kc2 + src + 8);
        *(short8*)(R0 + ofs) = a0; *(short8*)(R0 + ofs + 8) = b0;
        *(short8*)(R1 + ofs) = a1; *(short8*)(R1 + ofs + 8) = b1;
        *(short8*)(R2 + ofs) = a2; *(short8*)(R2 + ofs + 8) = b2;
    }
    {
        int d = tid >> 1, hf = tid & 1;
        short8 vv = *(const short8*)(vt_cmp + (bh * 128 + d) * NB + hf * 16);
        short8 vw = *(const short8*)(vt_cmp + (bh * 128 + d) * NB + hf * 16 + 8);
        *(short8*)(R3 + d * 40 + hf * 16) = vv;
        *(short8*)(R3 + d * 40 + hf * 16 + 8) = vw;
    }
    __syncthreads();                    // the only barrier

    // ---- Q fragments (3 planes) for OWN rows ----
    short8 qf0[4], qf1[4], qf2[4];
    {
        const float* qrow = q + (size_t)(o0 + qtile * 64 + w * 16 + r) * HD + h * D;
#pragma unroll
        for (int s = 0; s < 4; s++) {
            const float* p0 = qrow + s * 32 + quad * 8;
            float xv[8];
            *(float4*)(xv) = *(const float4*)p0;
            *(float4*)(xv + 4) = *(const float4*)(p0 + 4);
            short8 f0, f1, f2;
#pragma unroll
            for (int i = 0; i < 8; i++) {
                unsigned short e0, e1, e2;
                split3(xv[i], e0, e1, e2);
                f0[i] = (short)e0; f1[i] = (short)e1; f2[i] = (short)e2;
            }
            qf0[s] = f0; qf1[s] = f1; qf2[s] = f2;
        }
    }
    // ---- QK (6 product rounds, small terms first), per j-frag ----
    auto qk6 = [&](int krow) {
        f32x4 sv = (f32x4){0.f, 0.f, 0.f, 0.f};
#pragma unroll
        for (int s = 0; s < 4; s++) {
            int ofs = krow * 136 + s * 32 + quad * 8;
            short8 k0 = *(const short8*)(R0 + ofs);
            short8 k1 = *(const short8*)(R1 + ofs);
            short8 k2 = *(const short8*)(R2 + ofs);
            sv = MFMA16(qf1[s], k1, sv);
            sv = MFMA16(qf0[s], k2, sv);
            sv = MFMA16(qf2[s], k0, sv);
            sv = MFMA16(qf0[s], k1, sv);
            sv = MFMA16(qf1[s], k0, sv);
            sv = MFMA16(qf0[s], k0, sv);
        }
        return sv;
    };
    f32x4 s0 = qk6(r);
    f32x4 s1 = (f32x4){0.f, 0.f, 0.f, 0.f};
    if (qtile >= 8) s1 = qk6(16 + r);   // cols 16-31 all non-causal otherwise

    // ---- mask + silu -> own Ps rows; raw scores kept in regs for selection
    float v0[4], v1[4];
#pragma unroll
    for (int jf = 0; jf < 2; jf++) {
        f32x4 svv = jf ? s1 : s0;
        int colj = jf * 16 + r;
#pragma unroll
        for (int i = 0; i < 4; i++) {
            int mrow = w * 16 + quad * 4 + i;
            int qb = 2 * qtile + (mrow >> 5);
            bool causal = (colj <= qb);
            float sc = svv[i] * SCALE;
            float val = causal ? sc : SENT;
            if (jf) v1[i] = val; else v0[i] = val;
            Ps[mrow * 40 + colj] = f2bf(causal ? silu(sc) : 0.f);
        }
    }
    // ---- selection -> ms_g ----
    if (qtile < 4) {                    // both qblks < S_SEL: trivial masks
        if (tid < 64)
            ms_g[msbase + tid] = (1u << (2 * qtile + (tid >> 5) + 1)) - 1u;
    } else {                            // rank in registers + ballot
#pragma unroll
        for (int i = 0; i < 4; i++) {
            float a = v0[i], bb = v1[i];
            int cnt0 = (bb > a) ? 1 : 0;          // (16+r) beats r only if strictly greater
            int cnt1 = (a >= bb) ? 1 : 0;         // r beats 16+r on ties
#pragma unroll
            for (int m = 1; m < 16; m++) {
                float pa = __shfl_xor(a, m);      // stays in 16-lane quad-group
                float pb = __shfl_xor(bb, m);
                int pc = r ^ m;
                cnt0 += ((pa > a) || (pa == a && pc < r)) ? 1 : 0;
                cnt0 += (pb > a) ? 1 : 0;         // col 16+pc > r: no tie count
                cnt1 += ((pa > bb) || (pa == bb)) ? 1 : 0;   // pc < 16+r always
                cnt1 += ((pb > bb) || (pb == bb && pc < r)) ? 1 : 0;
            }
            bool sel0 = (cnt0 < S_SEL) && (a > -2.9e38f);
            bool sel1 = (cnt1 < S_SEL) && (bb > -2.9e38f);
            unsigned long long bal0 = __ballot(sel0);
            unsigned long long bal1 = __ballot(sel1);
            unsigned mask = (unsigned)((bal0 >> (16 * quad)) & 0xFFFFull)
                          | ((unsigned)((bal1 >> (16 * quad)) & 0xFFFFull) << 16);
            if (r == 0) ms_g[msbase + w * 16 + quad * 4 + i] = mask;
        }
    }
    // ---- PV -> o_cmp (wave-local: A = own P rows, B = 8 d-frags) ----
    f32x4 acc[8];
#pragma unroll
    for (int a = 0; a < 8; a++) acc[a] = (f32x4){0.f, 0.f, 0.f, 0.f};
    {
        short8 pf8 = *(const short8*)(Ps + (w * 16 + r) * 40 + quad * 8);
#pragma unroll
        for (int nf = 0; nf < 8; nf++) {
            short8 vf = *(const short8*)(R3 + (nf * 16 + r) * 40 + quad * 8);
            acc[nf] = MFMA16(pf8, vf, acc[nf]);
        }
    }
    // ---- epilogue o_cmp ----
#pragma unroll
    for (int i = 0; i < 4; i++) {
        int mrow = w * 16 + quad * 4 + i;
        int gm = qtile * 64 + mrow;
        float gc = g[(size_t)((b * NMAX + gm) * H + h) * 2];
        float* dst = o_cmp_j + (size_t)(o0 + gm) * HD + h * D;
#pragma unroll
        for (int nf = 0; nf < 8; nf++)
            dst[nf * 16 + r] = acc[nf][i] * gc;
    }
}

// ---------------------------------------------------------------------------
// K3b: selected attention — r9 structure, V MOVED FROM LDS TO REGISTERS:
// vt_blk is L2-resident after the XCD-aware mapping (r8: FETCH 26.5->13.7MB),
// so V^T B-frags load direct from global at ~L2 latency, issued at iteration
// top and covered by the QK phase (8 chained MFMAs + ds_reads). This was
// r3's regression ONLY because vt_blk then missed to HBM (~900cy). LDS drops
// 43.5->22.3KB; __launch_bounds__(256,4) caps VGPR at 128 -> 4 blocks/CU
// (was 3). K stays double-buffered in LDS w/ full-iteration register
// prefetch; single barrier/iter; wave-local PV; LPT; XCD mapping.
// fp32 partials -> atomicAdd into pre-zeroed o_slc_j (plain store for
// single-chunk tiles).
// ---------------------------------------------------------------------------
__global__ __launch_bounds__(256, 4) void slc_attn(
    const float* __restrict__ q, const unsigned short* __restrict__ kb16,
    const unsigned short* __restrict__ vt_blk, const float* __restrict__ g,
    const int* __restrict__ offs, const unsigned* __restrict__ ms_g,
    float* __restrict__ o_slc_j) {
    int x = blockIdx.x;                 // grid = B*H*16*MC, XCD-grouped mapping
    int xcd = x & (NXCD - 1);
    int rest = x >> 3;
    int group = rest >> 6;              // 64 = 16 mtiles * MC chunks
    int inner = rest & 63;
    int bh = group * NXCD + xcd;        // all 64 blocks of bh on one XCD
    int b = bh >> 3, h = bh & 7;
    int chunk = inner & (MC - 1);
    int mtile = 15 - (inner >> 2);      // LPT: longest blocks dispatch first
    int o0 = offs[b];
    int len = offs[b + 1] - o0;
    if (mtile * 64 >= len) return;      // uniform exit (lens are multiples of 64)
    int qmax = 2 * mtile + 1;
    int kb0 = chunk * CHUNK;
    if (kb0 > qmax) return;
    int kend = min(qmax, kb0 + CHUNK - 1);

    // pool: Kbuf0|Kbuf1 (32xKP) | Ps (64x40)  — V now lives in registers
    __shared__ __align__(16) unsigned short pool[2 * 32 * KP + 2560];
    __shared__ unsigned Ms[64];
    unsigned short* Kst0 = pool;                      // 8704 B
    unsigned short* Kst1 = pool + 32 * KP;            // 8704 B
    unsigned short* Ps   = pool + 2 * 32 * KP;        // 5120 B

    int tid = threadIdx.x;
    int w = tid >> 6, lane = tid & 63;
    int r = lane & 15, quad = lane >> 4;
    int stg_j = tid >> 3, stg_dc = tid & 7;

    if (tid < 64)
        Ms[tid] = ms_g[((size_t)bh << 10) + mtile * 64 + tid];

    // Q fragments (plane 0): wave w -> rows 16w + r
    short8 qs[4];
    {
        const float* qrow = q + (size_t)(o0 + mtile * 64 + w * 16 + r) * HD + h * D;
#pragma unroll
        for (int s = 0; s < 4; s++) {
            const float* p0 = qrow + s * 32 + quad * 8;
            float xv[8];
            *(float4*)(xv) = *(const float4*)p0;
            *(float4*)(xv + 4) = *(const float4*)(p0 + 4);
            short8 f;
#pragma unroll
            for (int i = 0; i < 8; i++) f[i] = (short)f2bf(xv[i]);
            qs[s] = f;
        }
    }
    f32x4 acc[8];                       // wave-local: rows [16w,16w+16), all 128 d
#pragma unroll
    for (int a = 0; a < 8; a++) acc[a] = (f32x4){0.f, 0.f, 0.f, 0.f};

    size_t vtbase = (size_t)(bh * NB) * 4096;

    // prestage kb0 K into Kst0
    {
        const unsigned short* ks = kb16 + (size_t)(o0 + kb0 * BS + stg_j) * HD + h * D + stg_dc * 16;
        short8 k0 = *(const short8*)ks;
        short8 k1 = *(const short8*)(ks + 8);
        *(short8*)(Kst0 + stg_j * KP + stg_dc * 16) = k0;
        *(short8*)(Kst0 + stg_j * KP + stg_dc * 16 + 8) = k1;
    }
    __syncthreads();

    int c = 0;
    for (int kb = kb0; kb <= kend; kb++) {
        // V^T B-frags for THIS kb: direct from global (L2-resident; each
        // nf-load is a fully-coalesced 1KB wave read). Issued first so the
        // QK phase below covers the latency.
        short8 vf[8];
        {
            const unsigned short* vsrc = vt_blk + vtbase + (size_t)kb * 4096;
#pragma unroll
            for (int nf = 0; nf < 8; nf++)
                vf[nf] = *(const short8*)(vsrc + (nf * 16 + r) * 32 + quad * 8);
        }
        // prefetch K kb+1 into registers
        short8 pk0, pk1;
        bool pf = (kb < kend);
        if (pf) {
            const unsigned short* ks = kb16 + (size_t)(o0 + (kb + 1) * BS + stg_j) * HD + h * D + stg_dc * 16;
            pk0 = *(const short8*)ks;
            pk1 = *(const short8*)(ks + 8);
        }
        // QK: wave w -> rows [16w,16w+16), both j-frags
        unsigned short* K = c ? Kst1 : Kst0;
        f32x4 s0 = (f32x4){0.f, 0.f, 0.f, 0.f};
        f32x4 s1 = (f32x4){0.f, 0.f, 0.f, 0.f};
#pragma unroll
        for (int s = 0; s < 4; s++) {
            short8 kf0 = *(const short8*)(K + r * KP + s * 32 + quad * 8);
            short8 kf1 = *(const short8*)(K + (16 + r) * KP + s * 32 + quad * 8);
            s0 = MFMA16(qs[s], kf0, s0);
            s1 = MFMA16(qs[s], kf1, s1);
        }
        // mask + silu -> OWN Ps slice (rows 16w..16w+15; wave-local)
#pragma unroll
        for (int jf = 0; jf < 2; jf++) {
            f32x4 svv = jf ? s1 : s0;
            int colj = jf * 16 + r;
            int kpos = kb * BS + colj;
#pragma unroll
            for (int i = 0; i < 4; i++) {
                int mrow = w * 16 + quad * 4 + i;
                int mpos = mtile * 64 + mrow;
                float p = (((Ms[mrow] >> kb) & 1u) && (kpos <= mpos))
                          ? silu(svv[i] * SCALE) : 0.f;
                Ps[mrow * 40 + colj] = f2bf(p);
            }
        }
        // PV: A = own P slice (same-wave LDS turnaround), B = vf[nf] regs
        {
            short8 pf8 = *(const short8*)(Ps + (w * 16 + r) * 40 + quad * 8);
#pragma unroll
            for (int nf = 0; nf < 8; nf++)
                acc[nf] = MFMA16(pf8, vf[nf], acc[nf]);
        }
        if (pf) {                       // commit prefetched K into other buffer
            unsigned short* Kn = c ? Kst0 : Kst1;
            *(short8*)(Kn + stg_j * KP + stg_dc * 16) = pk0;
            *(short8*)(Kn + stg_j * KP + stg_dc * 16 + 8) = pk1;
        }
        __syncthreads();                // single barrier per iteration
        c ^= 1;
    }

    // epilogue: wave w writes its rows [16w,16w+16), all 128 d
    bool single = (qmax < CHUNK);
#pragma unroll
    for (int i = 0; i < 4; i++) {
        int mrow = w * 16 + quad * 4 + i;
        int gm = mtile * 64 + mrow;
        float gs = g[(size_t)((b * NMAX + gm) * H + h) * 2 + 1];
        float* dst = o_slc_j + (size_t)(o0 + gm) * HD + h * D;
#pragma unroll
        for (int nf = 0; nf < 8; nf++) {
            float v0 = acc[nf][i] * gs;
            if (single) dst[nf * 16 + r] = v0;
            else        atomicAdd(dst + nf * 16 + r, v0);
        }
    }
}

// ---------------------------------------------------------------------------
// K4 (FALLBACK only — used when ws can't hold bf16 scratch and it aliases
// kp): padded qp, kp. Runs AFTER attention.
// ---------------------------------------------------------------------------
__global__ __launch_bounds__(256) void pad_qk_kernel(
    const float* __restrict__ q, const float* __restrict__ k,
    const int* __restrict__ offs,
    float* __restrict__ qp, float* __restrict__ kp) {
    int idx = blockIdx.x * 256 + threadIdx.x;       // float4 index over [B,n,H,D/4]
    int d4 = idx & 31;
    int h  = (idx >> 5) & 7;
    int m  = (idx >> 8) & (NMAX - 1);
    int b  = idx >> 18;
    int o0 = offs[b];
    int len = offs[b + 1] - o0;
    float4 qv = make_float4(0.f, 0.f, 0.f, 0.f);
    float4 kv = qv;
    if (m < len) {
        size_t src = (size_t)(o0 + m) * HD + h * D + d4 * 4;
        qv = *(const float4*)(q + src);
        kv = *(const float4*)(k + src);
    }
    *(float4*)(qp + (size_t)idx * 4) = qv;
    *(float4*)(kp + (size_t)idx * 4) = kv;
}

// ---------------------------------------------------------------------------
// K5: LayerNorm(1024) per stream, gate by u, sum -> out (oc may alias out)
// ---------------------------------------------------------------------------
__global__ __launch_bounds__(256) void ln_combine_kernel(
    const float* __restrict__ oc, const float* __restrict__ os,
    const float* __restrict__ u, float* __restrict__ out) {
    int t = blockIdx.x, tid = threadIdx.x;
    size_t base = (size_t)t * HD;
    float4 xc = *(const float4*)(oc + base + tid * 4);
    float4 xs = *(const float4*)(os + base + tid * 4);
    float4 uu = *(const float4*)(u + base + tid * 4);
    float s_c = xc.x + xc.y + xc.z + xc.w;
    float q_c = xc.x * xc.x + xc.y * xc.y + xc.z * xc.z + xc.w * xc.w;
    float s_s = xs.x + xs.y + xs.z + xs.w;
    float q_s = xs.x * xs.x + xs.y * xs.y + xs.z * xs.z + xs.w * xs.w;
#pragma unroll
    for (int off = 32; off > 0; off >>= 1) {
        s_c += __shfl_xor(s_c, off); q_c += __shfl_xor(q_c, off);
        s_s += __shfl_xor(s_s, off); q_s += __shfl_xor(q_s, off);
    }
    __shared__ float red[4][4];
    int w = tid >> 6, lane = tid & 63;
    if (lane == 0) {
        red[w][0] = s_c; red[w][1] = q_c; red[w][2] = s_s; red[w][3] = q_s;
    }
    __syncthreads();
    float tsc = red[0][0] + red[1][0] + red[2][0] + red[3][0];
    float tqc = red[0][1] + red[1][1] + red[2][1] + red[3][1];
    float tss = red[0][2] + red[1][2] + red[2][2] + red[3][2];
    float tqs = red[0][3] + red[1][3] + red[2][3] + red[3][3];
    const float inv = 1.f / 1024.f;
    float mc = tsc * inv, vc = tqc * inv - mc * mc;
    float ms = tss * inv, vs = tqs * inv - ms * ms;
    float rc = rsqrtf(vc + 1e-5f), rs = rsqrtf(vs + 1e-5f);
    float4 o;
    o.x = ((xc.x - mc) * rc + (xs.x - ms) * rs) * uu.x;
    o.y = ((xc.y - mc) * rc + (xs.y - ms) * rs) * uu.y;
    o.z = ((xc.z - mc) * rc + (xs.z - ms) * rs) * uu.z;
    o.w = ((xc.w - mc) * rc + (xs.w - ms) * rs) * uu.w;
    *(float4*)(out + base + tid * 4) = o;
}

// ---------------------------------------------------------------------------
extern "C" void kernel_launch(void* const* d_in, const int* in_sizes, int n_in,
                              void* d_out, int out_size, void* d_ws, size_t ws_size,
                              hipStream_t stream) {
    const float* q  = (const float*)d_in[0];
    const float* k  = (const float*)d_in[1];
    const float* v  = (const float*)d_in[2];
    const float* u  = (const float*)d_in[3];
    const float* Wg = (const float*)d_in[4];
    const float* bg = (const float*)d_in[5];
    const int* offs = (const int*)d_in[6];   // int32 (jnp default, x64 off)

    int B = in_sizes[6] - 1;
    int T = in_sizes[0] / HD;

    float* out = (float*)d_out;
    float* qp  = out + (size_t)T * HD;
    float* kp  = qp + (size_t)B * NMAX * HD;

    float* o_cmp_j = out;   // aliases final out (safe: see ln_combine)

    size_t plane = (size_t)B * H * NB * 128;        // elems per kc plane
    char* w = (char*)d_ws;
    unsigned short* kc0 = (unsigned short*)w;  w += plane * 2;
    unsigned short* kc1 = (unsigned short*)w;  w += plane * 2;
    unsigned short* kc2 = (unsigned short*)w;  w += plane * 2;
    unsigned short* vt_cmp = (unsigned short*)w; w += plane * 2;
    float* g     = (float*)w;            w += (size_t)B * NMAX * H * 2 * 4;
    unsigned* ms_g = (unsigned*)w;       w += (size_t)B * H * NMAX * 4;
    float* o_slc_j = (float*)w;          w += (size_t)T * HD * 4;

    // bf16 scratch: prefer ws tail (enables fused pad); else kp region
    size_t kb16_bytes = (size_t)T * HD * 2;
    size_t vt_bytes   = (size_t)B * H * NB * 128 * 32 * 2;
    size_t used = (size_t)(w - (char*)d_ws);
    bool fused_pad = (used + kb16_bytes + vt_bytes <= ws_size);
    char* scr = fused_pad ? w : (char*)kp;
    unsigned short* kb16  = (unsigned short*)scr;
    unsigned short* vt_blk = (unsigned short*)(scr + kb16_bytes);

    int prepBlocks = B * H * NB;
    int cmpAttnBlocks = B * H * 16;
    int slcBlocks  = B * H * 16 * MC;
    int padBlocks  = (B * NMAX * HD / 4) / 256;

    prep_kernel<<<prepBlocks, 256, 0, stream>>>(q, k, v, Wg, bg, offs, kb16, vt_blk,
                                                g, kc0, kc1, kc2, vt_cmp, o_slc_j,
                                                fused_pad ? qp : nullptr,
                                                fused_pad ? kp : nullptr);
    cmp_attn<<<cmpAttnBlocks, 256, 0, stream>>>(q, kc0, kc1, kc2, vt_cmp, g,
                                                offs, ms_g, o_cmp_j);
    slc_attn<<<slcBlocks, 256, 0, stream>>>(q, kb16, vt_blk, g, offs, ms_g, o_slc_j);
    if (!fused_pad)
        pad_qk_kernel<<<padBlocks, 256, 0, stream>>>(q, k, offs, qp, kp);
    ln_combine_kernel<<<T, 256, 0, stream>>>(o_cmp_j, o_slc_j, u, out);
}

// Round 11
// 184.607 us; speedup vs baseline: 1.4447x; 1.0090x over previous
//
#include <hip/hip_runtime.h>
#include <hip/hip_bf16.h>
#include <cmath>

#define H 8
#define D 128
#define HD 1024            // H*D
#define NMAX 1024
#define BS 32
#define NB 32
#define S_SEL 8
#define CHUNK 8            // kb blocks per slc_attn workgroup
#define MC 4               // chunks per mtile (NB/CHUNK)
#define KP 136             // K LDS pitch (shorts). MUST be mult of 8 (16B align for b128!)
#define NXCD 8
#define SCALE 0.08838834764831845f   // 1/sqrt(128)
#define SENT -3.0e38f

typedef __attribute__((ext_vector_type(8))) short short8;   // 8 bf16 = 4 VGPRs
typedef __attribute__((ext_vector_type(4))) float f32x4;    // MFMA acc

#define MFMA16(a, b, c) __builtin_amdgcn_mfma_f32_16x16x32_bf16(a, b, c, 0, 0, 0)

// fast silu: v_exp_f32 + v_rcp_f32 (~5 inst vs ~25 for libm expf + div).
// Feeds bf16 P values — bf16 rounding (2^-8) dominates native-exp err (2^-20).
__device__ __forceinline__ float silu(float x) {
    return x * __builtin_amdgcn_rcpf(1.f + __expf(-x));
}
__device__ __forceinline__ float sigmoid_fast(float x) {
    return __builtin_amdgcn_rcpf(1.f + __expf(-x));
}
__device__ __forceinline__ unsigned short f2bf(float x) {
    return __builtin_bit_cast(unsigned short, __float2bfloat16(x));
}
__device__ __forceinline__ float bfup(unsigned short b) {
    unsigned u = (unsigned)b << 16;
    return __builtin_bit_cast(float, u);
}
// 3-term bf16 split: x ~= b0 + b1 + b2 with |err| ~ 2^-27 |x|
__device__ __forceinline__ void split3(float x, unsigned short& b0,
                                       unsigned short& b1, unsigned short& b2) {
    b0 = f2bf(x);
    float r1 = x - bfup(b0);
    b1 = f2bf(r1);
    float r2 = r1 - bfup(b1);
    b2 = f2bf(r2);
}

// ---------------------------------------------------------------------------
// K1 prep: per (b,h,nt) 32-token block:
//   - kb16[tok][h][d]   : bf16 copy of K (straight convert, coalesced)
//   - vt_blk[bh][nt][d][j]: bf16 V^T in 8KB contiguous blocks (LDS transpose)
//   - g[b,m,h,{0,1}]    : gates (8-lane reduction, lanes share (tok,h))
//   - kc0/1/2[bh][nt][d]: split3 bf16 planes of the K block-mean
//   - vt_cmp[bh][d][nt] : bf16 V block-mean, transposed
//   - FUSED: qp/kp padded outputs + o_slc_j zeroing (only nt>=8 — rows in
//     single-chunk mtiles get plain stores from slc, no zero needed)
// Invalid blocks (nt*BS >= len) zero kc/vt_cmp slots and their qp/kp slices.
// All lengths are multiples of 64, so valid blocks are fully valid.
// ---------------------------------------------------------------------------
__global__ __launch_bounds__(256) void prep_kernel(
    const float* __restrict__ q, const float* __restrict__ k,
    const float* __restrict__ v, const float* __restrict__ Wg,
    const float* __restrict__ bg, const int* __restrict__ offs,
    unsigned short* __restrict__ kb16, unsigned short* __restrict__ vt_blk,
    float* __restrict__ g, unsigned short* __restrict__ kc0,
    unsigned short* __restrict__ kc1, unsigned short* __restrict__ kc2,
    unsigned short* __restrict__ vt_cmp, float* __restrict__ o_slc,
    float* __restrict__ qp, float* __restrict__ kp) {
    int x = blockIdx.x;
    int nt = x & (NB - 1);
    int h = (x >> 5) & 7;
    int b = x >> 8;
    int o0 = offs[b];
    int len = offs[b + 1] - o0;
    int tid = threadIdx.x;
    size_t bh = (size_t)(b * H + h);
    int j = tid >> 3, dc = tid & 7;
    size_t pbase = (size_t)((b * NMAX + nt * BS + j)) * HD + h * D + dc * 16;
    if (nt * BS >= len) {
        if (tid < 128) {
            kc0[(bh * NB + nt) * 128 + tid] = 0;
            kc1[(bh * NB + nt) * 128 + tid] = 0;
            kc2[(bh * NB + nt) * 128 + tid] = 0;
            vt_cmp[(bh * 128 + tid) * NB + nt] = 0;
        }
        if (qp) {                       // zero padding region of qp/kp
            float4 z = make_float4(0.f, 0.f, 0.f, 0.f);
#pragma unroll
            for (int i = 0; i < 4; i++) {
                *(float4*)(qp + pbase + i * 4) = z;
                *(float4*)(kp + pbase + i * 4) = z;
            }
        }
        return;
    }

    __shared__ __align__(16) unsigned short tile[128 * 40];
    __shared__ float redK[4][128];
    __shared__ float redV[4][128];
    int w = tid >> 6, lane = tid & 63;
    size_t base = (size_t)(o0 + nt * BS + j) * HD + h * D + dc * 16;

    // zero this token/head slice of o_slc — ONLY rows that slc atomically
    // accumulates into (multi-chunk mtiles, nt >= 8; nt < 8 gets plain store)
    if (nt >= 8) {
        float4 z = make_float4(0.f, 0.f, 0.f, 0.f);
#pragma unroll
        for (int i = 0; i < 4; i++) *(float4*)(o_slc + base + i * 4) = z;
    }

    // K -> kb16 (bf16) + kp (fused pad) + block-mean partial
    {
        float xv[16];
        *(float4*)(xv + 0)  = *(const float4*)(k + base);
        *(float4*)(xv + 4)  = *(const float4*)(k + base + 4);
        *(float4*)(xv + 8)  = *(const float4*)(k + base + 8);
        *(float4*)(xv + 12) = *(const float4*)(k + base + 12);
        short8 lo, hi;
#pragma unroll
        for (int i = 0; i < 8; i++) { lo[i] = (short)f2bf(xv[i]); hi[i] = (short)f2bf(xv[8 + i]); }
        *(short8*)(kb16 + base) = lo;
        *(short8*)(kb16 + base + 8) = hi;
        if (kp) {
#pragma unroll
            for (int i = 0; i < 4; i++) *(float4*)(kp + pbase + i * 4) = *(float4*)(xv + i * 4);
        }
        // butterfly over the wave's 8 j-lanes (lane bits 3,4,5)
#pragma unroll
        for (int i = 0; i < 16; i++) {
            float s = xv[i];
            s += __shfl_xor(s, 8); s += __shfl_xor(s, 16); s += __shfl_xor(s, 32);
            if (lane < 8) redK[w][lane * 16 + i] = s;
        }
    }
    // V -> LDS transpose tile[d][j] + block-mean partial
    {
        float xv[16];
        *(float4*)(xv + 0)  = *(const float4*)(v + base);
        *(float4*)(xv + 4)  = *(const float4*)(v + base + 4);
        *(float4*)(xv + 8)  = *(const float4*)(v + base + 8);
        *(float4*)(xv + 12) = *(const float4*)(v + base + 12);
#pragma unroll
        for (int i = 0; i < 16; i++) tile[(dc * 16 + i) * 40 + j] = f2bf(xv[i]);
#pragma unroll
        for (int i = 0; i < 16; i++) {
            float s = xv[i];
            s += __shfl_xor(s, 8); s += __shfl_xor(s, 16); s += __shfl_xor(s, 32);
            if (lane < 8) redV[w][lane * 16 + i] = s;
        }
    }
    // gates (dot over this thread's 16 dims) + qp (fused pad)
    {
        float xv[16];
        *(float4*)(xv + 0)  = *(const float4*)(q + base);
        *(float4*)(xv + 4)  = *(const float4*)(q + base + 4);
        *(float4*)(xv + 8)  = *(const float4*)(q + base + 8);
        *(float4*)(xv + 12) = *(const float4*)(q + base + 12);
        if (qp) {
#pragma unroll
            for (int i = 0; i < 4; i++) *(float4*)(qp + pbase + i * 4) = *(float4*)(xv + i * 4);
        }
        float p0 = 0.f, p1 = 0.f;
#pragma unroll
        for (int i = 0; i < 16; i++) {
            int wb = (h * D + dc * 16 + i) * 3;
            p0 += xv[i] * Wg[wb + 0];
            p1 += xv[i] * Wg[wb + 1];
        }
#pragma unroll
        for (int off = 4; off > 0; off >>= 1) {
            p0 += __shfl_xor(p0, off);
            p1 += __shfl_xor(p1, off);
        }
        if (dc == 0) {
            float g0 = sigmoid_fast(p0 + bg[h * 3 + 0]);
            float g1 = sigmoid_fast(p1 + bg[h * 3 + 1]);
            float* gp = g + (size_t)((b * NMAX + nt * BS + j) * H + h) * 2;
            gp[0] = g0; gp[1] = g1;
        }
    }
    __syncthreads();
    // tile -> vt_blk (contiguous 8KB per (bh,nt))
    {
        int d = tid >> 1, hf = tid & 1;
        short8 a = *(const short8*)(tile + d * 40 + hf * 16);
        short8 c = *(const short8*)(tile + d * 40 + hf * 16 + 8);
        size_t ob = ((bh * NB + nt) * 128 + (size_t)d) * 32 + hf * 16;
        *(short8*)(vt_blk + ob) = a;
        *(short8*)(vt_blk + ob + 8) = c;
    }
    // means -> kc planes / vt_cmp
    if (tid < 128) {
        int d = tid;
        const float inv = 1.f / 32.f;
        float km = (redK[0][d] + redK[1][d] + redK[2][d] + redK[3][d]) * inv;
        float vm = (redV[0][d] + redV[1][d] + redV[2][d] + redV[3][d]) * inv;
        unsigned short e0, e1, e2;
        split3(km, e0, e1, e2);
        kc0[(bh * NB + nt) * 128 + d] = e0;
        kc1[(bh * NB + nt) * 128 + d] = e1;
        kc2[(bh * NB + nt) * 128 + d] = e2;
        vt_cmp[(bh * 128 + d) * NB + nt] = f2bf(vm);
    }
}

// ---------------------------------------------------------------------------
// K3a: compressed attention + top-8 selection, 64-ROW tile (2 qblks) per WG,
// fully WAVE-LOCAL (slc-proven shape, r9-verified). Wave w owns rows
// [16w,16w+16); selection in registers via 15 shfl_xor + 2 ballots; one
// barrier per block. qblk dispatch LPT-reversed.
// MFMA layouts (m89/m120): A[m=lane&15][k=quad*8+j]; C/D col=lane&15,
// row=quad*4+reg.
// ---------------------------------------------------------------------------
__global__ __launch_bounds__(256) void cmp_attn(
    const float* __restrict__ q, const unsigned short* __restrict__ kc0,
    const unsigned short* __restrict__ kc1, const unsigned short* __restrict__ kc2,
    const unsigned short* __restrict__ vt_cmp, const float* __restrict__ g,
    const int* __restrict__ offs, unsigned* __restrict__ ms_g,
    float* __restrict__ o_cmp_j) {
    int x = blockIdx.x;                 // (b*H + h)*16 + qtile_idx
    int qtile = 15 - (x & 15);          // reversed: long blocks dispatch first
    int h = (x >> 4) & 7;
    int b = x >> 7;
    int o0 = offs[b];
    int len = offs[b + 1] - o0;
    if (qtile * 64 >= len) return;
    size_t bh = (size_t)(b * H + h);
    int qmax = 2 * qtile + 1;           // last causal kc block for this tile

    // pool: R0/R1/R2 kc planes (32x136), R3 vt_cmp^T (128x40), Ps (64x40)
    __shared__ __align__(16) unsigned short pool[3 * 4352 + 5120 + 2560];
    unsigned short* R0 = pool;            // 4352
    unsigned short* R1 = pool + 4352;     // 4352
    unsigned short* R2 = pool + 8704;     // 4352
    unsigned short* R3 = pool + 13056;    // 5120
    unsigned short* Ps = pool + 18176;    // 2560 (64x40)

    int tid = threadIdx.x;
    int w = tid >> 6, lane = tid & 63;
    int r = lane & 15, quad = lane >> 4;
    int stg_j = tid >> 3, stg_dc = tid & 7;
    size_t msbase = (bh << 10) + (size_t)qtile * 64;

    // ---- stage kc planes (causal rows only) + vt_cmp ----
    if (stg_j <= qmax) {
        size_t src = (bh * NB + stg_j) * 128 + stg_dc * 16;
        int ofs = stg_j * 136 + stg_dc * 16;
        short8 a0 = *(const short8*)(kc0 + src);
        short8 b0 = *(const short8*)(kc0 + src + 8);
        short8 a1 = *(const short8*)(kc1 + src);
        short8 b1 = *(const short8*)(kc1 + src + 8);
        short8 a2 = *(const short8*)(kc2 + src);
        short8 b2 = *(const short8*)(kc2 + src + 8);
        *(short8*)(R0 + ofs) = a0; *(short8*)(R0 + ofs + 8) = b0;
        *(short8*)(R1 + ofs) = a1; *(short8*)(R1 + ofs + 8) = b1;
        *(short8*)(R2 + ofs) = a2; *(short8*)(R2 + ofs + 8) = b2;
    }
    {
        int d = tid >> 1, hf = tid & 1;
        short8 vv = *(const short8*)(vt_cmp + (bh * 128 + d) * NB + hf * 16);
        short8 vw = *(const short8*)(vt_cmp + (bh * 128 + d) * NB + hf * 16 + 8);
        *(short8*)(R3 + d * 40 + hf * 16) = vv;
        *(short8*)(R3 + d * 40 + hf * 16 + 8) = vw;
    }
    __syncthreads();                    // the only barrier

    // ---- Q fragments (3 planes) for OWN rows ----
    short8 qf0[4], qf1[4], qf2[4];
    {
        const float* qrow = q + (size_t)(o0 + qtile * 64 + w * 16 + r) * HD + h * D;
#pragma unroll
        for (int s = 0; s < 4; s++) {
            const float* p0 = qrow + s * 32 + quad * 8;
            float xv[8];
            *(float4*)(xv) = *(const float4*)p0;
            *(float4*)(xv + 4) = *(const float4*)(p0 + 4);
            short8 f0, f1, f2;
#pragma unroll
            for (int i = 0; i < 8; i++) {
                unsigned short e0, e1, e2;
                split3(xv[i], e0, e1, e2);
                f0[i] = (short)e0; f1[i] = (short)e1; f2[i] = (short)e2;
            }
            qf0[s] = f0; qf1[s] = f1; qf2[s] = f2;
        }
    }
    // ---- QK (6 product rounds, small terms first), per j-frag ----
    auto qk6 = [&](int krow) {
        f32x4 sv = (f32x4){0.f, 0.f, 0.f, 0.f};
#pragma unroll
        for (int s = 0; s < 4; s++) {
            int ofs = krow * 136 + s * 32 + quad * 8;
            short8 k0 = *(const short8*)(R0 + ofs);
            short8 k1 = *(const short8*)(R1 + ofs);
            short8 k2 = *(const short8*)(R2 + ofs);
            sv = MFMA16(qf1[s], k1, sv);
            sv = MFMA16(qf0[s], k2, sv);
            sv = MFMA16(qf2[s], k0, sv);
            sv = MFMA16(qf0[s], k1, sv);
            sv = MFMA16(qf1[s], k0, sv);
            sv = MFMA16(qf0[s], k0, sv);
        }
        return sv;
    };
    f32x4 s0 = qk6(r);
    f32x4 s1 = (f32x4){0.f, 0.f, 0.f, 0.f};
    if (qtile >= 8) s1 = qk6(16 + r);   // cols 16-31 all non-causal otherwise

    // ---- mask + silu -> own Ps rows; raw scores kept in regs for selection
    float v0[4], v1[4];
#pragma unroll
    for (int jf = 0; jf < 2; jf++) {
        f32x4 svv = jf ? s1 : s0;
        int colj = jf * 16 + r;
#pragma unroll
        for (int i = 0; i < 4; i++) {
            int mrow = w * 16 + quad * 4 + i;
            int qb = 2 * qtile + (mrow >> 5);
            bool causal = (colj <= qb);
            float sc = svv[i] * SCALE;
            float val = causal ? sc : SENT;
            if (jf) v1[i] = val; else v0[i] = val;
            Ps[mrow * 40 + colj] = f2bf(causal ? silu(sc) : 0.f);
        }
    }
    // ---- selection -> ms_g ----
    if (qtile < 4) {                    // both qblks < S_SEL: trivial masks
        if (tid < 64)
            ms_g[msbase + tid] = (1u << (2 * qtile + (tid >> 5) + 1)) - 1u;
    } else {                            // rank in registers + ballot
#pragma unroll
        for (int i = 0; i < 4; i++) {
            float a = v0[i], bb = v1[i];
            int cnt0 = (bb > a) ? 1 : 0;          // (16+r) beats r only if strictly greater
            int cnt1 = (a >= bb) ? 1 : 0;         // r beats 16+r on ties
#pragma unroll
            for (int m = 1; m < 16; m++) {
                float pa = __shfl_xor(a, m);      // stays in 16-lane quad-group
                float pb = __shfl_xor(bb, m);
                int pc = r ^ m;
                cnt0 += ((pa > a) || (pa == a && pc < r)) ? 1 : 0;
                cnt0 += (pb > a) ? 1 : 0;         // col 16+pc > r: no tie count
                cnt1 += ((pa > bb) || (pa == bb)) ? 1 : 0;   // pc < 16+r always
                cnt1 += ((pb > bb) || (pb == bb && pc < r)) ? 1 : 0;
            }
            bool sel0 = (cnt0 < S_SEL) && (a > -2.9e38f);
            bool sel1 = (cnt1 < S_SEL) && (bb > -2.9e38f);
            unsigned long long bal0 = __ballot(sel0);
            unsigned long long bal1 = __ballot(sel1);
            unsigned mask = (unsigned)((bal0 >> (16 * quad)) & 0xFFFFull)
                          | ((unsigned)((bal1 >> (16 * quad)) & 0xFFFFull) << 16);
            if (r == 0) ms_g[msbase + w * 16 + quad * 4 + i] = mask;
        }
    }
    // ---- PV -> o_cmp (wave-local: A = own P rows, B = 8 d-frags) ----
    f32x4 acc[8];
#pragma unroll
    for (int a = 0; a < 8; a++) acc[a] = (f32x4){0.f, 0.f, 0.f, 0.f};
    {
        short8 pf8 = *(const short8*)(Ps + (w * 16 + r) * 40 + quad * 8);
#pragma unroll
        for (int nf = 0; nf < 8; nf++) {
            short8 vf = *(const short8*)(R3 + (nf * 16 + r) * 40 + quad * 8);
            acc[nf] = MFMA16(pf8, vf, acc[nf]);
        }
    }
    // ---- epilogue o_cmp ----
#pragma unroll
    for (int i = 0; i < 4; i++) {
        int mrow = w * 16 + quad * 4 + i;
        int gm = qtile * 64 + mrow;
        float gc = g[(size_t)((b * NMAX + gm) * H + h) * 2];
        float* dst = o_cmp_j + (size_t)(o0 + gm) * HD + h * D;
#pragma unroll
        for (int nf = 0; nf < 8; nf++)
            dst[nf * 16 + r] = acc[nf][i] * gc;
    }
}

// ---------------------------------------------------------------------------
// K3b: selected attention — r8-measured-best structure EXACTLY (40.7us):
// K+V double-buffered in LDS, register prefetch of BOTH one FULL iteration
// ahead, single barrier/iter, wave-local PV, KP=136 aligned, LPT, XCD-aware
// mapping (all 64 blocks of a (b,h) on one XCD; FETCH 26.5->13.7MB).
// r10's V-from-global variant REGRESSED (45.4us): same-iteration global
// loads sit on the critical path even L2-resident — everything the MFMA
// phase consumes must be staged/prefetched a full iteration ahead.
// Race-freedom with ONE barrier/iter: commit(i) targets buf[(i+1)%2], whose
// last readers finished before BAR(i-1), and whose next readers start after
// BAR(i). Ps write->read is same-wave (compiler lgkmcnt). fp32 partials ->
// atomicAdd into pre-zeroed o_slc_j (plain store for single-chunk tiles).
// ---------------------------------------------------------------------------
__global__ __launch_bounds__(256) void slc_attn(
    const float* __restrict__ q, const unsigned short* __restrict__ kb16,
    const unsigned short* __restrict__ vt_blk, const float* __restrict__ g,
    const int* __restrict__ offs, const unsigned* __restrict__ ms_g,
    float* __restrict__ o_slc_j) {
    int x = blockIdx.x;                 // grid = B*H*16*MC, XCD-grouped mapping
    int xcd = x & (NXCD - 1);
    int rest = x >> 3;
    int group = rest >> 6;              // 64 = 16 mtiles * MC chunks
    int inner = rest & 63;
    int bh = group * NXCD + xcd;        // all 64 blocks of bh on one XCD
    int b = bh >> 3, h = bh & 7;
    int chunk = inner & (MC - 1);
    int mtile = 15 - (inner >> 2);      // LPT: longest blocks dispatch first
    int o0 = offs[b];
    int len = offs[b + 1] - o0;
    if (mtile * 64 >= len) return;      // uniform exit (lens are multiples of 64)
    int qmax = 2 * mtile + 1;
    int kb0 = chunk * CHUNK;
    if (kb0 > qmax) return;
    int kend = min(qmax, kb0 + CHUNK - 1);

    // single pool: Kbuf0|Kbuf1 (32xKP) | VTbuf0|VTbuf1 (128x40) | Ps (64x40)
    __shared__ __align__(16) unsigned short pool[2 * 32 * KP + 2 * 5120 + 2560];
    __shared__ unsigned Ms[64];
    unsigned short* Kst0 = pool;                      // 4352
    unsigned short* Kst1 = pool + 32 * KP;            // 4352
    unsigned short* Vst0 = pool + 2 * 32 * KP;        // 5120
    unsigned short* Vst1 = pool + 2 * 32 * KP + 5120; // 5120
    unsigned short* Ps   = pool + 2 * 32 * KP + 10240;// 2560

    int tid = threadIdx.x;
    int w = tid >> 6, lane = tid & 63;
    int r = lane & 15, quad = lane >> 4;
    int stg_j = tid >> 3, stg_dc = tid & 7;

    if (tid < 64)
        Ms[tid] = ms_g[((size_t)bh << 10) + mtile * 64 + tid];

    // Q fragments (plane 0): wave w -> rows 16w + r
    short8 qs[4];
    {
        const float* qrow = q + (size_t)(o0 + mtile * 64 + w * 16 + r) * HD + h * D;
#pragma unroll
        for (int s = 0; s < 4; s++) {
            const float* p0 = qrow + s * 32 + quad * 8;
            float xv[8];
            *(float4*)(xv) = *(const float4*)p0;
            *(float4*)(xv + 4) = *(const float4*)(p0 + 4);
            short8 f;
#pragma unroll
            for (int i = 0; i < 8; i++) f[i] = (short)f2bf(xv[i]);
            qs[s] = f;
        }
    }
    f32x4 acc[8];                       // wave-local: rows [16w,16w+16), all 128 d
#pragma unroll
    for (int a = 0; a < 8; a++) acc[a] = (f32x4){0.f, 0.f, 0.f, 0.f};

    size_t vtbase = (size_t)(bh * NB) * 4096;
    int vd = tid >> 1, vhf = tid & 1;

    // prestage kb0 into Kst0 / Vst0
    {
        const unsigned short* ks = kb16 + (size_t)(o0 + kb0 * BS + stg_j) * HD + h * D + stg_dc * 16;
        short8 k0 = *(const short8*)ks;
        short8 k1 = *(const short8*)(ks + 8);
        *(short8*)(Kst0 + stg_j * KP + stg_dc * 16) = k0;
        *(short8*)(Kst0 + stg_j * KP + stg_dc * 16 + 8) = k1;
        const unsigned short* vs = vt_blk + vtbase + (size_t)kb0 * 4096 + tid * 16;
        short8 v0 = *(const short8*)vs;
        short8 v1 = *(const short8*)(vs + 8);
        *(short8*)(Vst0 + vd * 40 + vhf * 16) = v0;
        *(short8*)(Vst0 + vd * 40 + vhf * 16 + 8) = v1;
    }
    __syncthreads();

    int c = 0;
    for (int kb = kb0; kb <= kend; kb++) {
        short8 pk0, pk1, pv0, pv1;
        bool pf = (kb < kend);
        if (pf) {                       // prefetch kb+1 into registers
            const unsigned short* ks = kb16 + (size_t)(o0 + (kb + 1) * BS + stg_j) * HD + h * D + stg_dc * 16;
            pk0 = *(const short8*)ks;
            pk1 = *(const short8*)(ks + 8);
            const unsigned short* vs = vt_blk + vtbase + (size_t)(kb + 1) * 4096 + tid * 16;
            pv0 = *(const short8*)vs;
            pv1 = *(const short8*)(vs + 8);
        }
        // QK: wave w -> rows [16w,16w+16), both j-frags
        unsigned short* K = c ? Kst1 : Kst0;
        unsigned short* V = c ? Vst1 : Vst0;
        f32x4 s0 = (f32x4){0.f, 0.f, 0.f, 0.f};
        f32x4 s1 = (f32x4){0.f, 0.f, 0.f, 0.f};
#pragma unroll
        for (int s = 0; s < 4; s++) {
            short8 kf0 = *(const short8*)(K + r * KP + s * 32 + quad * 8);
            short8 kf1 = *(const short8*)(K + (16 + r) * KP + s * 32 + quad * 8);
            s0 = MFMA16(qs[s], kf0, s0);
            s1 = MFMA16(qs[s], kf1, s1);
        }
        // mask + silu -> OWN Ps slice (rows 16w..16w+15; wave-local)
#pragma unroll
        for (int jf = 0; jf < 2; jf++) {
            f32x4 svv = jf ? s1 : s0;
            int colj = jf * 16 + r;
            int kpos = kb * BS + colj;
#pragma unroll
            for (int i = 0; i < 4; i++) {
                int mrow = w * 16 + quad * 4 + i;
                int mpos = mtile * 64 + mrow;
                float p = (((Ms[mrow] >> kb) & 1u) && (kpos <= mpos))
                          ? silu(svv[i] * SCALE) : 0.f;
                Ps[mrow * 40 + colj] = f2bf(p);
            }
        }
        // PV: A = own P slice (same-wave LDS turnaround), B = 8 V^T d-frags
        {
            short8 pf8 = *(const short8*)(Ps + (w * 16 + r) * 40 + quad * 8);
#pragma unroll
            for (int nf = 0; nf < 8; nf++) {
                short8 vf = *(const short8*)(V + (nf * 16 + r) * 40 + quad * 8);
                acc[nf] = MFMA16(pf8, vf, acc[nf]);
            }
        }
        if (pf) {                       // commit prefetch into the other buffer
            unsigned short* Kn = c ? Kst0 : Kst1;
            unsigned short* Vn = c ? Vst0 : Vst1;
            *(short8*)(Kn + stg_j * KP + stg_dc * 16) = pk0;
            *(short8*)(Kn + stg_j * KP + stg_dc * 16 + 8) = pk1;
            *(short8*)(Vn + vd * 40 + vhf * 16) = pv0;
            *(short8*)(Vn + vd * 40 + vhf * 16 + 8) = pv1;
        }
        __syncthreads();                // single barrier per iteration
        c ^= 1;
    }

    // epilogue: wave w writes its rows [16w,16w+16), all 128 d
    bool single = (qmax < CHUNK);
#pragma unroll
    for (int i = 0; i < 4; i++) {
        int mrow = w * 16 + quad * 4 + i;
        int gm = mtile * 64 + mrow;
        float gs = g[(size_t)((b * NMAX + gm) * H + h) * 2 + 1];
        float* dst = o_slc_j + (size_t)(o0 + gm) * HD + h * D;
#pragma unroll
        for (int nf = 0; nf < 8; nf++) {
            float v0 = acc[nf][i] * gs;
            if (single) dst[nf * 16 + r] = v0;
            else        atomicAdd(dst + nf * 16 + r, v0);
        }
    }
}

// ---------------------------------------------------------------------------
// K4 (FALLBACK only — used when ws can't hold bf16 scratch and it aliases
// kp): padded qp, kp. Runs AFTER attention.
// ---------------------------------------------------------------------------
__global__ __launch_bounds__(256) void pad_qk_kernel(
    const float* __restrict__ q, const float* __restrict__ k,
    const int* __restrict__ offs,
    float* __restrict__ qp, float* __restrict__ kp) {
    int idx = blockIdx.x * 256 + threadIdx.x;       // float4 index over [B,n,H,D/4]
    int d4 = idx & 31;
    int h  = (idx >> 5) & 7;
    int m  = (idx >> 8) & (NMAX - 1);
    int b  = idx >> 18;
    int o0 = offs[b];
    int len = offs[b + 1] - o0;
    float4 qv = make_float4(0.f, 0.f, 0.f, 0.f);
    float4 kv = qv;
    if (m < len) {
        size_t src = (size_t)(o0 + m) * HD + h * D + d4 * 4;
        qv = *(const float4*)(q + src);
        kv = *(const float4*)(k + src);
    }
    *(float4*)(qp + (size_t)idx * 4) = qv;
    *(float4*)(kp + (size_t)idx * 4) = kv;
}

// ---------------------------------------------------------------------------
// K5: LayerNorm(1024) per stream, gate by u, sum -> out (oc may alias out)
// ---------------------------------------------------------------------------
__global__ __launch_bounds__(256) void ln_combine_kernel(
    const float* __restrict__ oc, const float* __restrict__ os,
    const float* __restrict__ u, float* __restrict__ out) {
    int t = blockIdx.x, tid = threadIdx.x;
    size_t base = (size_t)t * HD;
    float4 xc = *(const float4*)(oc + base + tid * 4);
    float4 xs = *(const float4*)(os + base + tid * 4);
    float4 uu = *(const float4*)(u + base + tid * 4);
    float s_c = xc.x + xc.y + xc.z + xc.w;
    float q_c = xc.x * xc.x + xc.y * xc.y + xc.z * xc.z + xc.w * xc.w;
    float s_s = xs.x + xs.y + xs.z + xs.w;
    float q_s = xs.x * xs.x + xs.y * xs.y + xs.z * xs.z + xs.w * xs.w;
#pragma unroll
    for (int off = 32; off > 0; off >>= 1) {
        s_c += __shfl_xor(s_c, off); q_c += __shfl_xor(q_c, off);
        s_s += __shfl_xor(s_s, off); q_s += __shfl_xor(q_s, off);
    }
    __shared__ float red[4][4];
    int w = tid >> 6, lane = tid & 63;
    if (lane == 0) {
        red[w][0] = s_c; red[w][1] = q_c; red[w][2] = s_s; red[w][3] = q_s;
    }
    __syncthreads();
    float tsc = red[0][0] + red[1][0] + red[2][0] + red[3][0];
    float tqc = red[0][1] + red[1][1] + red[2][1] + red[3][1];
    float tss = red[0][2] + red[1][2] + red[2][2] + red[3][2];
    float tqs = red[0][3] + red[1][3] + red[2][3] + red[3][3];
    const float inv = 1.f / 1024.f;
    float mc = tsc * inv, vc = tqc * inv - mc * mc;
    float ms = tss * inv, vs = tqs * inv - ms * ms;
    float rc = rsqrtf(vc + 1e-5f), rs = rsqrtf(vs + 1e-5f);
    float4 o;
    o.x = ((xc.x - mc) * rc + (xs.x - ms) * rs) * uu.x;
    o.y = ((xc.y - mc) * rc + (xs.y - ms) * rs) * uu.y;
    o.z = ((xc.z - mc) * rc + (xs.z - ms) * rs) * uu.z;
    o.w = ((xc.w - mc) * rc + (xs.w - ms) * rs) * uu.w;
    *(float4*)(out + base + tid * 4) = o;
}

// ---------------------------------------------------------------------------
extern "C" void kernel_launch(void* const* d_in, const int* in_sizes, int n_in,
                              void* d_out, int out_size, void* d_ws, size_t ws_size,
                              hipStream_t stream) {
    const float* q  = (const float*)d_in[0];
    const float* k  = (const float*)d_in[1];
    const float* v  = (const float*)d_in[2];
    const float* u  = (const float*)d_in[3];
    const float* Wg = (const float*)d_in[4];
    const float* bg = (const float*)d_in[5];
    const int* offs = (const int*)d_in[6];   // int32 (jnp default, x64 off)

    int B = in_sizes[6] - 1;
    int T = in_sizes[0] / HD;

    float* out = (float*)d_out;
    float* qp  = out + (size_t)T * HD;
    float* kp  = qp + (size_t)B * NMAX * HD;

    float* o_cmp_j = out;   // aliases final out (safe: see ln_combine)

    size_t plane = (size_t)B * H * NB * 128;        // elems per kc plane
    char* w = (char*)d_ws;
    unsigned short* kc0 = (unsigned short*)w;  w += plane * 2;
    unsigned short* kc1 = (unsigned short*)w;  w += plane * 2;
    unsigned short* kc2 = (unsigned short*)w;  w += plane * 2;
    unsigned short* vt_cmp = (unsigned short*)w; w += plane * 2;
    float* g     = (float*)w;            w += (size_t)B * NMAX * H * 2 * 4;
    unsigned* ms_g = (unsigned*)w;       w += (size_t)B * H * NMAX * 4;
    float* o_slc_j = (float*)w;          w += (size_t)T * HD * 4;

    // bf16 scratch: prefer ws tail (enables fused pad); else kp region
    size_t kb16_bytes = (size_t)T * HD * 2;
    size_t vt_bytes   = (size_t)B * H * NB * 128 * 32 * 2;
    size_t used = (size_t)(w - (char*)d_ws);
    bool fused_pad = (used + kb16_bytes + vt_bytes <= ws_size);
    char* scr = fused_pad ? w : (char*)kp;
    unsigned short* kb16  = (unsigned short*)scr;
    unsigned short* vt_blk = (unsigned short*)(scr + kb16_bytes);

    int prepBlocks = B * H * NB;
    int cmpAttnBlocks = B * H * 16;
    int slcBlocks  = B * H * 16 * MC;
    int padBlocks  = (B * NMAX * HD / 4) / 256;

    prep_kernel<<<prepBlocks, 256, 0, stream>>>(q, k, v, Wg, bg, offs, kb16, vt_blk,
                                                g, kc0, kc1, kc2, vt_cmp, o_slc_j,
                                                fused_pad ? qp : nullptr,
                                                fused_pad ? kp : nullptr);
    cmp_attn<<<cmpAttnBlocks, 256, 0, stream>>>(q, kc0, kc1, kc2, vt_cmp, g,
                                                offs, ms_g, o_cmp_j);
    slc_attn<<<slcBlocks, 256, 0, stream>>>(q, kb16, vt_blk, g, offs, ms_g, o_slc_j);
    if (!fused_pad)
        pad_qk_kernel<<<padBlocks, 256, 0, stream>>>(q, k, offs, qp, kp);
    ln_combine_kernel<<<T, 256, 0, stream>>>(o_cmp_j, o_slc_j, u, out);
}

// Round 12
// 183.714 us; speedup vs baseline: 1.4517x; 1.0049x over previous
//
#include <hip/hip_runtime.h>
#include <hip/hip_bf16.h>
#include <cmath>

#define H 8
#define D 128
#define HD 1024            // H*D
#define NMAX 1024
#define BS 32
#define NB 32
#define S_SEL 8
#define CHUNK 8            // kb blocks per slc_attn workgroup
#define MC 4               // chunks per mtile (NB/CHUNK)
#define KP 136             // K LDS pitch (shorts). MUST be mult of 8 (16B align for b128!)
#define NXCD 8
#define SCALE 0.08838834764831845f   // 1/sqrt(128)
#define SENT -3.0e38f

typedef __attribute__((ext_vector_type(8))) short short8;   // 8 bf16 = 4 VGPRs
typedef __attribute__((ext_vector_type(4))) float f32x4;    // MFMA acc

#define MFMA16(a, b, c) __builtin_amdgcn_mfma_f32_16x16x32_bf16(a, b, c, 0, 0, 0)

// fast silu: v_exp_f32 + v_rcp_f32 (~5 inst vs ~25 for libm expf + div).
// Feeds bf16 P values — bf16 rounding (2^-8) dominates native-exp err (2^-20).
__device__ __forceinline__ float silu(float x) {
    return x * __builtin_amdgcn_rcpf(1.f + __expf(-x));
}
__device__ __forceinline__ float sigmoid_fast(float x) {
    return __builtin_amdgcn_rcpf(1.f + __expf(-x));
}
__device__ __forceinline__ unsigned short f2bf(float x) {
    return __builtin_bit_cast(unsigned short, __float2bfloat16(x));
}
__device__ __forceinline__ float bfup(unsigned short b) {
    unsigned u = (unsigned)b << 16;
    return __builtin_bit_cast(float, u);
}
// 3-term bf16 split: x ~= b0 + b1 + b2 with |err| ~ 2^-27 |x|
__device__ __forceinline__ void split3(float x, unsigned short& b0,
                                       unsigned short& b1, unsigned short& b2) {
    b0 = f2bf(x);
    float r1 = x - bfup(b0);
    b1 = f2bf(r1);
    float r2 = r1 - bfup(b1);
    b2 = f2bf(r2);
}

// ---------------------------------------------------------------------------
// K1 prep: per (b,h,nt) 32-token block:
//   - kb16[tok][h][d]   : bf16 copy of K (straight convert, coalesced)
//   - vt_blk[bh][nt][d][j]: bf16 V^T in 8KB contiguous blocks (LDS transpose)
//   - g[b,m,h,{0,1}]    : gates (8-lane reduction, lanes share (tok,h))
//   - kc0/1/2[bh][nt][d]: split3 bf16 planes of the K block-mean
//   - vt_cmp[bh][d][nt] : bf16 V block-mean, transposed
//   - FUSED: qp/kp padded outputs + o_slc_j zeroing (only nt>=8 — rows in
//     single-chunk mtiles get plain stores from slc, no zero needed)
// Invalid blocks (nt*BS >= len) zero kc/vt_cmp slots and their qp/kp slices.
// All lengths are multiples of 64, so valid blocks are fully valid.
// ---------------------------------------------------------------------------
__global__ __launch_bounds__(256) void prep_kernel(
    const float* __restrict__ q, const float* __restrict__ k,
    const float* __restrict__ v, const float* __restrict__ Wg,
    const float* __restrict__ bg, const int* __restrict__ offs,
    unsigned short* __restrict__ kb16, unsigned short* __restrict__ vt_blk,
    float* __restrict__ g, unsigned short* __restrict__ kc0,
    unsigned short* __restrict__ kc1, unsigned short* __restrict__ kc2,
    unsigned short* __restrict__ vt_cmp, float* __restrict__ o_slc,
    float* __restrict__ qp, float* __restrict__ kp) {
    int x = blockIdx.x;
    int nt = x & (NB - 1);
    int h = (x >> 5) & 7;
    int b = x >> 8;
    int o0 = offs[b];
    int len = offs[b + 1] - o0;
    int tid = threadIdx.x;
    size_t bh = (size_t)(b * H + h);
    int j = tid >> 3, dc = tid & 7;
    size_t pbase = (size_t)((b * NMAX + nt * BS + j)) * HD + h * D + dc * 16;
    if (nt * BS >= len) {
        if (tid < 128) {
            kc0[(bh * NB + nt) * 128 + tid] = 0;
            kc1[(bh * NB + nt) * 128 + tid] = 0;
            kc2[(bh * NB + nt) * 128 + tid] = 0;
            vt_cmp[(bh * 128 + tid) * NB + nt] = 0;
        }
        if (qp) {                       // zero padding region of qp/kp
            float4 z = make_float4(0.f, 0.f, 0.f, 0.f);
#pragma unroll
            for (int i = 0; i < 4; i++) {
                *(float4*)(qp + pbase + i * 4) = z;
                *(float4*)(kp + pbase + i * 4) = z;
            }
        }
        return;
    }

    __shared__ __align__(16) unsigned short tile[128 * 40];
    __shared__ float redK[4][128];
    __shared__ float redV[4][128];
    int w = tid >> 6, lane = tid & 63;
    size_t base = (size_t)(o0 + nt * BS + j) * HD + h * D + dc * 16;

    // zero this token/head slice of o_slc — ONLY rows that slc atomically
    // accumulates into (multi-chunk mtiles, nt >= 8; nt < 8 gets plain store)
    if (nt >= 8) {
        float4 z = make_float4(0.f, 0.f, 0.f, 0.f);
#pragma unroll
        for (int i = 0; i < 4; i++) *(float4*)(o_slc + base + i * 4) = z;
    }

    // K -> kb16 (bf16) + kp (fused pad) + block-mean partial
    {
        float xv[16];
        *(float4*)(xv + 0)  = *(const float4*)(k + base);
        *(float4*)(xv + 4)  = *(const float4*)(k + base + 4);
        *(float4*)(xv + 8)  = *(const float4*)(k + base + 8);
        *(float4*)(xv + 12) = *(const float4*)(k + base + 12);
        short8 lo, hi;
#pragma unroll
        for (int i = 0; i < 8; i++) { lo[i] = (short)f2bf(xv[i]); hi[i] = (short)f2bf(xv[8 + i]); }
        *(short8*)(kb16 + base) = lo;
        *(short8*)(kb16 + base + 8) = hi;
        if (kp) {
#pragma unroll
            for (int i = 0; i < 4; i++) *(float4*)(kp + pbase + i * 4) = *(float4*)(xv + i * 4);
        }
        // butterfly over the wave's 8 j-lanes (lane bits 3,4,5)
#pragma unroll
        for (int i = 0; i < 16; i++) {
            float s = xv[i];
            s += __shfl_xor(s, 8); s += __shfl_xor(s, 16); s += __shfl_xor(s, 32);
            if (lane < 8) redK[w][lane * 16 + i] = s;
        }
    }
    // V -> LDS transpose tile[d][j] + block-mean partial
    {
        float xv[16];
        *(float4*)(xv + 0)  = *(const float4*)(v + base);
        *(float4*)(xv + 4)  = *(const float4*)(v + base + 4);
        *(float4*)(xv + 8)  = *(const float4*)(v + base + 8);
        *(float4*)(xv + 12) = *(const float4*)(v + base + 12);
#pragma unroll
        for (int i = 0; i < 16; i++) tile[(dc * 16 + i) * 40 + j] = f2bf(xv[i]);
#pragma unroll
        for (int i = 0; i < 16; i++) {
            float s = xv[i];
            s += __shfl_xor(s, 8); s += __shfl_xor(s, 16); s += __shfl_xor(s, 32);
            if (lane < 8) redV[w][lane * 16 + i] = s;
        }
    }
    // gates (dot over this thread's 16 dims) + qp (fused pad)
    {
        float xv[16];
        *(float4*)(xv + 0)  = *(const float4*)(q + base);
        *(float4*)(xv + 4)  = *(const float4*)(q + base + 4);
        *(float4*)(xv + 8)  = *(const float4*)(q + base + 8);
        *(float4*)(xv + 12) = *(const float4*)(q + base + 12);
        if (qp) {
#pragma unroll
            for (int i = 0; i < 4; i++) *(float4*)(qp + pbase + i * 4) = *(float4*)(xv + i * 4);
        }
        float p0 = 0.f, p1 = 0.f;
#pragma unroll
        for (int i = 0; i < 16; i++) {
            int wb = (h * D + dc * 16 + i) * 3;
            p0 += xv[i] * Wg[wb + 0];
            p1 += xv[i] * Wg[wb + 1];
        }
#pragma unroll
        for (int off = 4; off > 0; off >>= 1) {
            p0 += __shfl_xor(p0, off);
            p1 += __shfl_xor(p1, off);
        }
        if (dc == 0) {
            float g0 = sigmoid_fast(p0 + bg[h * 3 + 0]);
            float g1 = sigmoid_fast(p1 + bg[h * 3 + 1]);
            float* gp = g + (size_t)((b * NMAX + nt * BS + j) * H + h) * 2;
            gp[0] = g0; gp[1] = g1;
        }
    }
    __syncthreads();
    // tile -> vt_blk (contiguous 8KB per (bh,nt))
    {
        int d = tid >> 1, hf = tid & 1;
        short8 a = *(const short8*)(tile + d * 40 + hf * 16);
        short8 c = *(const short8*)(tile + d * 40 + hf * 16 + 8);
        size_t ob = ((bh * NB + nt) * 128 + (size_t)d) * 32 + hf * 16;
        *(short8*)(vt_blk + ob) = a;
        *(short8*)(vt_blk + ob + 8) = c;
    }
    // means -> kc planes / vt_cmp
    if (tid < 128) {
        int d = tid;
        const float inv = 1.f / 32.f;
        float km = (redK[0][d] + redK[1][d] + redK[2][d] + redK[3][d]) * inv;
        float vm = (redV[0][d] + redV[1][d] + redV[2][d] + redV[3][d]) * inv;
        unsigned short e0, e1, e2;
        split3(km, e0, e1, e2);
        kc0[(bh * NB + nt) * 128 + d] = e0;
        kc1[(bh * NB + nt) * 128 + d] = e1;
        kc2[(bh * NB + nt) * 128 + d] = e2;
        vt_cmp[(bh * 128 + d) * NB + nt] = f2bf(vm);
    }
}

// ---------------------------------------------------------------------------
// K3a: compressed attention + top-8 selection, 64-ROW tile (2 qblks) per WG,
// fully WAVE-LOCAL (slc-proven shape, r9-verified). Wave w owns rows
// [16w,16w+16); selection in registers via 15 shfl_xor + 2 ballots; one
// barrier per block. qblk dispatch LPT-reversed.
// MFMA layouts (m89/m120): A[m=lane&15][k=quad*8+j]; C/D col=lane&15,
// row=quad*4+reg.
// ---------------------------------------------------------------------------
__global__ __launch_bounds__(256) void cmp_attn(
    const float* __restrict__ q, const unsigned short* __restrict__ kc0,
    const unsigned short* __restrict__ kc1, const unsigned short* __restrict__ kc2,
    const unsigned short* __restrict__ vt_cmp, const float* __restrict__ g,
    const int* __restrict__ offs, unsigned* __restrict__ ms_g,
    float* __restrict__ o_cmp_j) {
    int x = blockIdx.x;                 // (b*H + h)*16 + qtile_idx
    int qtile = 15 - (x & 15);          // reversed: long blocks dispatch first
    int h = (x >> 4) & 7;
    int b = x >> 7;
    int o0 = offs[b];
    int len = offs[b + 1] - o0;
    if (qtile * 64 >= len) return;
    size_t bh = (size_t)(b * H + h);
    int qmax = 2 * qtile + 1;           // last causal kc block for this tile

    // pool: R0/R1/R2 kc planes (32x136), R3 vt_cmp^T (128x40), Ps (64x40)
    __shared__ __align__(16) unsigned short pool[3 * 4352 + 5120 + 2560];
    unsigned short* R0 = pool;            // 4352
    unsigned short* R1 = pool + 4352;     // 4352
    unsigned short* R2 = pool + 8704;     // 4352
    unsigned short* R3 = pool + 13056;    // 5120
    unsigned short* Ps = pool + 18176;    // 2560 (64x40)

    int tid = threadIdx.x;
    int w = tid >> 6, lane = tid & 63;
    int r = lane & 15, quad = lane >> 4;
    int stg_j = tid >> 3, stg_dc = tid & 7;
    size_t msbase = (bh << 10) + (size_t)qtile * 64;

    // ---- stage kc planes (causal rows only) + vt_cmp ----
    if (stg_j <= qmax) {
        size_t src = (bh * NB + stg_j) * 128 + stg_dc * 16;
        int ofs = stg_j * 136 + stg_dc * 16;
        short8 a0 = *(const short8*)(kc0 + src);
        short8 b0 = *(const short8*)(kc0 + src + 8);
        short8 a1 = *(const short8*)(kc1 + src);
        short8 b1 = *(const short8*)(kc1 + src + 8);
        short8 a2 = *(const short8*)(kc2 + src);
        short8 b2 = *(const short8*)(kc2 + src + 8);
        *(short8*)(R0 + ofs) = a0; *(short8*)(R0 + ofs + 8) = b0;
        *(short8*)(R1 + ofs) = a1; *(short8*)(R1 + ofs + 8) = b1;
        *(short8*)(R2 + ofs) = a2; *(short8*)(R2 + ofs + 8) = b2;
    }
    {
        int d = tid >> 1, hf = tid & 1;
        short8 vv = *(const short8*)(vt_cmp + (bh * 128 + d) * NB + hf * 16);
        short8 vw = *(const short8*)(vt_cmp + (bh * 128 + d) * NB + hf * 16 + 8);
        *(short8*)(R3 + d * 40 + hf * 16) = vv;
        *(short8*)(R3 + d * 40 + hf * 16 + 8) = vw;
    }
    __syncthreads();                    // the only barrier

    // ---- Q fragments (3 planes) for OWN rows ----
    short8 qf0[4], qf1[4], qf2[4];
    {
        const float* qrow = q + (size_t)(o0 + qtile * 64 + w * 16 + r) * HD + h * D;
#pragma unroll
        for (int s = 0; s < 4; s++) {
            const float* p0 = qrow + s * 32 + quad * 8;
            float xv[8];
            *(float4*)(xv) = *(const float4*)p0;
            *(float4*)(xv + 4) = *(const float4*)(p0 + 4);
            short8 f0, f1, f2;
#pragma unroll
            for (int i = 0; i < 8; i++) {
                unsigned short e0, e1, e2;
                split3(xv[i], e0, e1, e2);
                f0[i] = (short)e0; f1[i] = (short)e1; f2[i] = (short)e2;
            }
            qf0[s] = f0; qf1[s] = f1; qf2[s] = f2;
        }
    }
    // ---- QK (6 product rounds, small terms first), per j-frag ----
    auto qk6 = [&](int krow) {
        f32x4 sv = (f32x4){0.f, 0.f, 0.f, 0.f};
#pragma unroll
        for (int s = 0; s < 4; s++) {
            int ofs = krow * 136 + s * 32 + quad * 8;
            short8 k0 = *(const short8*)(R0 + ofs);
            short8 k1 = *(const short8*)(R1 + ofs);
            short8 k2 = *(const short8*)(R2 + ofs);
            sv = MFMA16(qf1[s], k1, sv);
            sv = MFMA16(qf0[s], k2, sv);
            sv = MFMA16(qf2[s], k0, sv);
            sv = MFMA16(qf0[s], k1, sv);
            sv = MFMA16(qf1[s], k0, sv);
            sv = MFMA16(qf0[s], k0, sv);
        }
        return sv;
    };
    f32x4 s0 = qk6(r);
    f32x4 s1 = (f32x4){0.f, 0.f, 0.f, 0.f};
    if (qtile >= 8) s1 = qk6(16 + r);   // cols 16-31 all non-causal otherwise

    // ---- mask + silu -> own Ps rows; raw scores kept in regs for selection
    float v0[4], v1[4];
#pragma unroll
    for (int jf = 0; jf < 2; jf++) {
        f32x4 svv = jf ? s1 : s0;
        int colj = jf * 16 + r;
#pragma unroll
        for (int i = 0; i < 4; i++) {
            int mrow = w * 16 + quad * 4 + i;
            int qb = 2 * qtile + (mrow >> 5);
            bool causal = (colj <= qb);
            float sc = svv[i] * SCALE;
            float val = causal ? sc : SENT;
            if (jf) v1[i] = val; else v0[i] = val;
            Ps[mrow * 40 + colj] = f2bf(causal ? silu(sc) : 0.f);
        }
    }
    // ---- selection -> ms_g ----
    if (qtile < 4) {                    // both qblks < S_SEL: trivial masks
        if (tid < 64)
            ms_g[msbase + tid] = (1u << (2 * qtile + (tid >> 5) + 1)) - 1u;
    } else {                            // rank in registers + ballot
#pragma unroll
        for (int i = 0; i < 4; i++) {
            float a = v0[i], bb = v1[i];
            int cnt0 = (bb > a) ? 1 : 0;          // (16+r) beats r only if strictly greater
            int cnt1 = (a >= bb) ? 1 : 0;         // r beats 16+r on ties
#pragma unroll
            for (int m = 1; m < 16; m++) {
                float pa = __shfl_xor(a, m);      // stays in 16-lane quad-group
                float pb = __shfl_xor(bb, m);
                int pc = r ^ m;
                cnt0 += ((pa > a) || (pa == a && pc < r)) ? 1 : 0;
                cnt0 += (pb > a) ? 1 : 0;         // col 16+pc > r: no tie count
                cnt1 += ((pa > bb) || (pa == bb)) ? 1 : 0;   // pc < 16+r always
                cnt1 += ((pb > bb) || (pb == bb && pc < r)) ? 1 : 0;
            }
            bool sel0 = (cnt0 < S_SEL) && (a > -2.9e38f);
            bool sel1 = (cnt1 < S_SEL) && (bb > -2.9e38f);
            unsigned long long bal0 = __ballot(sel0);
            unsigned long long bal1 = __ballot(sel1);
            unsigned mask = (unsigned)((bal0 >> (16 * quad)) & 0xFFFFull)
                          | ((unsigned)((bal1 >> (16 * quad)) & 0xFFFFull) << 16);
            if (r == 0) ms_g[msbase + w * 16 + quad * 4 + i] = mask;
        }
    }
    // ---- PV -> o_cmp (wave-local: A = own P rows, B = 8 d-frags) ----
    f32x4 acc[8];
#pragma unroll
    for (int a = 0; a < 8; a++) acc[a] = (f32x4){0.f, 0.f, 0.f, 0.f};
    {
        short8 pf8 = *(const short8*)(Ps + (w * 16 + r) * 40 + quad * 8);
#pragma unroll
        for (int nf = 0; nf < 8; nf++) {
            short8 vf = *(const short8*)(R3 + (nf * 16 + r) * 40 + quad * 8);
            acc[nf] = MFMA16(pf8, vf, acc[nf]);
        }
    }
    // ---- epilogue o_cmp ----
#pragma unroll
    for (int i = 0; i < 4; i++) {
        int mrow = w * 16 + quad * 4 + i;
        int gm = qtile * 64 + mrow;
        float gc = g[(size_t)((b * NMAX + gm) * H + h) * 2];
        float* dst = o_cmp_j + (size_t)(o0 + gm) * HD + h * D;
#pragma unroll
        for (int nf = 0; nf < 8; nf++)
            dst[nf * 16 + r] = acc[nf][i] * gc;
    }
}

// ---------------------------------------------------------------------------
// K3b: selected attention — r11 structure + DIM-SPLIT for parallelism:
// block = (b,h,mtile,chunk,dhalf). slc is GRID-limited (r10/r11: occupancy
// stuck at 13% regardless of LDS capacity), so double the blocks by having
// each compute full QK scores (redundant x2 — MfmaUtil is 5%, free) but
// PV + epilogue for only 64 of 128 output dims:
//   blocks 864->1728, V LDS halves (33KB total -> 4 resident/CU), total
//   writes unchanged, no added atomics, K/Q re-reads are L2-hits under the
//   XCD grouping.
// Else identical to r11: K+V double-buffered LDS, register prefetch one
// FULL iteration ahead (r10 re-proved same-iteration global loads always
// lengthen the chain), single barrier/iter, wave-local PV, KP=136, LPT,
// XCD-aware mapping. fp32 partials -> atomicAdd into pre-zeroed o_slc_j
// (plain store for single-chunk tiles).
// ---------------------------------------------------------------------------
__global__ __launch_bounds__(256) void slc_attn(
    const float* __restrict__ q, const unsigned short* __restrict__ kb16,
    const unsigned short* __restrict__ vt_blk, const float* __restrict__ g,
    const int* __restrict__ offs, const unsigned* __restrict__ ms_g,
    float* __restrict__ o_slc_j) {
    int x = blockIdx.x;                 // grid = B*H*16*MC*2, XCD-grouped
    int xcd = x & (NXCD - 1);
    int rest = x >> 3;
    int group = rest >> 7;              // 128 = 16 mtiles * MC chunks * 2 dhalf
    int inner = rest & 127;
    int bh = group * NXCD + xcd;        // all 128 blocks of bh on one XCD
    int b = bh >> 3, h = bh & 7;
    int dhalf = inner & 1;
    int chunk = (inner >> 1) & (MC - 1);
    int mtile = 15 - (inner >> 3);      // LPT: longest blocks dispatch first
    int o0 = offs[b];
    int len = offs[b + 1] - o0;
    if (mtile * 64 >= len) return;      // uniform exit (lens are multiples of 64)
    int qmax = 2 * mtile + 1;
    int kb0 = chunk * CHUNK;
    if (kb0 > qmax) return;
    int kend = min(qmax, kb0 + CHUNK - 1);

    // pool: Kbuf0|Kbuf1 (32xKP) | VTbuf0|VTbuf1 (64x40) | Ps (64x40) = ~33KB
    __shared__ __align__(16) unsigned short pool[2 * 32 * KP + 2 * 2560 + 2560];
    __shared__ unsigned Ms[64];
    unsigned short* Kst0 = pool;                      // 4352
    unsigned short* Kst1 = pool + 32 * KP;            // 4352
    unsigned short* Vst0 = pool + 2 * 32 * KP;        // 2560
    unsigned short* Vst1 = pool + 2 * 32 * KP + 2560; // 2560
    unsigned short* Ps   = pool + 2 * 32 * KP + 5120; // 2560

    int tid = threadIdx.x;
    int w = tid >> 6, lane = tid & 63;
    int r = lane & 15, quad = lane >> 4;
    int stg_j = tid >> 3, stg_dc = tid & 7;

    if (tid < 64)
        Ms[tid] = ms_g[((size_t)bh << 10) + mtile * 64 + tid];

    // Q fragments (plane 0): wave w -> rows 16w + r
    short8 qs[4];
    {
        const float* qrow = q + (size_t)(o0 + mtile * 64 + w * 16 + r) * HD + h * D;
#pragma unroll
        for (int s = 0; s < 4; s++) {
            const float* p0 = qrow + s * 32 + quad * 8;
            float xv[8];
            *(float4*)(xv) = *(const float4*)p0;
            *(float4*)(xv + 4) = *(const float4*)(p0 + 4);
            short8 f;
#pragma unroll
            for (int i = 0; i < 8; i++) f[i] = (short)f2bf(xv[i]);
            qs[s] = f;
        }
    }
    f32x4 acc[4];                       // wave-local: own rows, 64 of 128 dims
#pragma unroll
    for (int a = 0; a < 4; a++) acc[a] = (f32x4){0.f, 0.f, 0.f, 0.f};

    size_t vtbase = (size_t)(bh * NB) * 4096 + dhalf * 2048;  // this block's 64 d-rows
    int vd = tid >> 2, vq = tid & 3;    // 64 rows x 4 threads x 8 shorts

    // prestage kb0 into Kst0 / Vst0
    {
        const unsigned short* ks = kb16 + (size_t)(o0 + kb0 * BS + stg_j) * HD + h * D + stg_dc * 16;
        short8 k0 = *(const short8*)ks;
        short8 k1 = *(const short8*)(ks + 8);
        *(short8*)(Kst0 + stg_j * KP + stg_dc * 16) = k0;
        *(short8*)(Kst0 + stg_j * KP + stg_dc * 16 + 8) = k1;
        short8 v0 = *(const short8*)(vt_blk + vtbase + (size_t)kb0 * 4096 + vd * 32 + vq * 8);
        *(short8*)(Vst0 + vd * 40 + vq * 8) = v0;
    }
    __syncthreads();

    int c = 0;
    for (int kb = kb0; kb <= kend; kb++) {
        short8 pk0, pk1, pv0;
        bool pf = (kb < kend);
        if (pf) {                       // prefetch kb+1 into registers
            const unsigned short* ks = kb16 + (size_t)(o0 + (kb + 1) * BS + stg_j) * HD + h * D + stg_dc * 16;
            pk0 = *(const short8*)ks;
            pk1 = *(const short8*)(ks + 8);
            pv0 = *(const short8*)(vt_blk + vtbase + (size_t)(kb + 1) * 4096 + vd * 32 + vq * 8);
        }
        // QK: wave w -> rows [16w,16w+16), both j-frags (FULL scores)
        unsigned short* K = c ? Kst1 : Kst0;
        unsigned short* V = c ? Vst1 : Vst0;
        f32x4 s0 = (f32x4){0.f, 0.f, 0.f, 0.f};
        f32x4 s1 = (f32x4){0.f, 0.f, 0.f, 0.f};
#pragma unroll
        for (int s = 0; s < 4; s++) {
            short8 kf0 = *(const short8*)(K + r * KP + s * 32 + quad * 8);
            short8 kf1 = *(const short8*)(K + (16 + r) * KP + s * 32 + quad * 8);
            s0 = MFMA16(qs[s], kf0, s0);
            s1 = MFMA16(qs[s], kf1, s1);
        }
        // mask + silu -> OWN Ps slice (rows 16w..16w+15; wave-local)
#pragma unroll
        for (int jf = 0; jf < 2; jf++) {
            f32x4 svv = jf ? s1 : s0;
            int colj = jf * 16 + r;
            int kpos = kb * BS + colj;
#pragma unroll
            for (int i = 0; i < 4; i++) {
                int mrow = w * 16 + quad * 4 + i;
                int mpos = mtile * 64 + mrow;
                float p = (((Ms[mrow] >> kb) & 1u) && (kpos <= mpos))
                          ? silu(svv[i] * SCALE) : 0.f;
                Ps[mrow * 40 + colj] = f2bf(p);
            }
        }
        // PV: A = own P slice, B = 4 V^T d-frags (this block's 64 dims)
        {
            short8 pf8 = *(const short8*)(Ps + (w * 16 + r) * 40 + quad * 8);
#pragma unroll
            for (int nf = 0; nf < 4; nf++) {
                short8 vf = *(const short8*)(V + (nf * 16 + r) * 40 + quad * 8);
                acc[nf] = MFMA16(pf8, vf, acc[nf]);
            }
        }
        if (pf) {                       // commit prefetch into the other buffer
            unsigned short* Kn = c ? Kst0 : Kst1;
            unsigned short* Vn = c ? Vst0 : Vst1;
            *(short8*)(Kn + stg_j * KP + stg_dc * 16) = pk0;
            *(short8*)(Kn + stg_j * KP + stg_dc * 16 + 8) = pk1;
            *(short8*)(Vn + vd * 40 + vq * 8) = pv0;
        }
        __syncthreads();                // single barrier per iteration
        c ^= 1;
    }

    // epilogue: wave w writes its rows [16w,16w+16), this block's 64 dims
    bool single = (qmax < CHUNK);
#pragma unroll
    for (int i = 0; i < 4; i++) {
        int mrow = w * 16 + quad * 4 + i;
        int gm = mtile * 64 + mrow;
        float gs = g[(size_t)((b * NMAX + gm) * H + h) * 2 + 1];
        float* dst = o_slc_j + (size_t)(o0 + gm) * HD + h * D + dhalf * 64;
#pragma unroll
        for (int nf = 0; nf < 4; nf++) {
            float v0 = acc[nf][i] * gs;
            if (single) dst[nf * 16 + r] = v0;
            else        atomicAdd(dst + nf * 16 + r, v0);
        }
    }
}

// ---------------------------------------------------------------------------
// K4 (FALLBACK only — used when ws can't hold bf16 scratch and it aliases
// kp): padded qp, kp. Runs AFTER attention.
// ---------------------------------------------------------------------------
__global__ __launch_bounds__(256) void pad_qk_kernel(
    const float* __restrict__ q, const float* __restrict__ k,
    const int* __restrict__ offs,
    float* __restrict__ qp, float* __restrict__ kp) {
    int idx = blockIdx.x * 256 + threadIdx.x;       // float4 index over [B,n,H,D/4]
    int d4 = idx & 31;
    int h  = (idx >> 5) & 7;
    int m  = (idx >> 8) & (NMAX - 1);
    int b  = idx >> 18;
    int o0 = offs[b];
    int len = offs[b + 1] - o0;
    float4 qv = make_float4(0.f, 0.f, 0.f, 0.f);
    float4 kv = qv;
    if (m < len) {
        size_t src = (size_t)(o0 + m) * HD + h * D + d4 * 4;
        qv = *(const float4*)(q + src);
        kv = *(const float4*)(k + src);
    }
    *(float4*)(qp + (size_t)idx * 4) = qv;
    *(float4*)(kp + (size_t)idx * 4) = kv;
}

// ---------------------------------------------------------------------------
// K5: LayerNorm(1024) per stream, gate by u, sum -> out (oc may alias out)
// ---------------------------------------------------------------------------
__global__ __launch_bounds__(256) void ln_combine_kernel(
    const float* __restrict__ oc, const float* __restrict__ os,
    const float* __restrict__ u, float* __restrict__ out) {
    int t = blockIdx.x, tid = threadIdx.x;
    size_t base = (size_t)t * HD;
    float4 xc = *(const float4*)(oc + base + tid * 4);
    float4 xs = *(const float4*)(os + base + tid * 4);
    float4 uu = *(const float4*)(u + base + tid * 4);
    float s_c = xc.x + xc.y + xc.z + xc.w;
    float q_c = xc.x * xc.x + xc.y * xc.y + xc.z * xc.z + xc.w * xc.w;
    float s_s = xs.x + xs.y + xs.z + xs.w;
    float q_s = xs.x * xs.x + xs.y * xs.y + xs.z * xs.z + xs.w * xs.w;
#pragma unroll
    for (int off = 32; off > 0; off >>= 1) {
        s_c += __shfl_xor(s_c, off); q_c += __shfl_xor(q_c, off);
        s_s += __shfl_xor(s_s, off); q_s += __shfl_xor(q_s, off);
    }
    __shared__ float red[4][4];
    int w = tid >> 6, lane = tid & 63;
    if (lane == 0) {
        red[w][0] = s_c; red[w][1] = q_c; red[w][2] = s_s; red[w][3] = q_s;
    }
    __syncthreads();
    float tsc = red[0][0] + red[1][0] + red[2][0] + red[3][0];
    float tqc = red[0][1] + red[1][1] + red[2][1] + red[3][1];
    float tss = red[0][2] + red[1][2] + red[2][2] + red[3][2];
    float tqs = red[0][3] + red[1][3] + red[2][3] + red[3][3];
    const float inv = 1.f / 1024.f;
    float mc = tsc * inv, vc = tqc * inv - mc * mc;
    float ms = tss * inv, vs = tqs * inv - ms * ms;
    float rc = rsqrtf(vc + 1e-5f), rs = rsqrtf(vs + 1e-5f);
    float4 o;
    o.x = ((xc.x - mc) * rc + (xs.x - ms) * rs) * uu.x;
    o.y = ((xc.y - mc) * rc + (xs.y - ms) * rs) * uu.y;
    o.z = ((xc.z - mc) * rc + (xs.z - ms) * rs) * uu.z;
    o.w = ((xc.w - mc) * rc + (xs.w - ms) * rs) * uu.w;
    *(float4*)(out + base + tid * 4) = o;
}

// ---------------------------------------------------------------------------
extern "C" void kernel_launch(void* const* d_in, const int* in_sizes, int n_in,
                              void* d_out, int out_size, void* d_ws, size_t ws_size,
                              hipStream_t stream) {
    const float* q  = (const float*)d_in[0];
    const float* k  = (const float*)d_in[1];
    const float* v  = (const float*)d_in[2];
    const float* u  = (const float*)d_in[3];
    const float* Wg = (const float*)d_in[4];
    const float* bg = (const float*)d_in[5];
    const int* offs = (const int*)d_in[6];   // int32 (jnp default, x64 off)

    int B = in_sizes[6] - 1;
    int T = in_sizes[0] / HD;

    float* out = (float*)d_out;
    float* qp  = out + (size_t)T * HD;
    float* kp  = qp + (size_t)B * NMAX * HD;

    float* o_cmp_j = out;   // aliases final out (safe: see ln_combine)

    size_t plane = (size_t)B * H * NB * 128;        // elems per kc plane
    char* w = (char*)d_ws;
    unsigned short* kc0 = (unsigned short*)w;  w += plane * 2;
    unsigned short* kc1 = (unsigned short*)w;  w += plane * 2;
    unsigned short* kc2 = (unsigned short*)w;  w += plane * 2;
    unsigned short* vt_cmp = (unsigned short*)w; w += plane * 2;
    float* g     = (float*)w;            w += (size_t)B * NMAX * H * 2 * 4;
    unsigned* ms_g = (unsigned*)w;       w += (size_t)B * H * NMAX * 4;
    float* o_slc_j = (float*)w;          w += (size_t)T * HD * 4;

    // bf16 scratch: prefer ws tail (enables fused pad); else kp region
    size_t kb16_bytes = (size_t)T * HD * 2;
    size_t vt_bytes   = (size_t)B * H * NB * 128 * 32 * 2;
    size_t used = (size_t)(w - (char*)d_ws);
    bool fused_pad = (used + kb16_bytes + vt_bytes <= ws_size);
    char* scr = fused_pad ? w : (char*)kp;
    unsigned short* kb16  = (unsigned short*)scr;
    unsigned short* vt_blk = (unsigned short*)(scr + kb16_bytes);

    int prepBlocks = B * H * NB;
    int cmpAttnBlocks = B * H * 16;
    int slcBlocks  = B * H * 16 * MC * 2;
    int padBlocks  = (B * NMAX * HD / 4) / 256;

    prep_kernel<<<prepBlocks, 256, 0, stream>>>(q, k, v, Wg, bg, offs, kb16, vt_blk,
                                                g, kc0, kc1, kc2, vt_cmp, o_slc_j,
                                                fused_pad ? qp : nullptr,
                                                fused_pad ? kp : nullptr);
    cmp_attn<<<cmpAttnBlocks, 256, 0, stream>>>(q, kc0, kc1, kc2, vt_cmp, g,
                                                offs, ms_g, o_cmp_j);
    slc_attn<<<slcBlocks, 256, 0, stream>>>(q, kb16, vt_blk, g, offs, ms_g, o_slc_j);
    if (!fused_pad)
        pad_qk_kernel<<<padBlocks, 256, 0, stream>>>(q, k, offs, qp, kp);
    ln_combine_kernel<<<T, 256, 0, stream>>>(o_cmp_j, o_slc_j, u, out);
}

// Round 14
// 181.758 us; speedup vs baseline: 1.4673x; 1.0108x over previous
//
#include <hip/hip_runtime.h>
#include <hip/hip_bf16.h>
#include <cmath>

#define H 8
#define D 128
#define HD 1024            // H*D
#define NMAX 1024
#define BS 32
#define NB 32
#define S_SEL 8
#define CHUNK 8            // kb blocks per slc_attn workgroup
#define MC 4               // chunks per mtile (NB/CHUNK)
#define KP 136             // K LDS pitch (shorts). MUST be mult of 8 (16B align for b128!)
#define NXCD 8
#define SCALE 0.08838834764831845f   // 1/sqrt(128)
#define SENT -3.0e38f

typedef __attribute__((ext_vector_type(8))) short short8;   // 8 bf16 = 4 VGPRs
typedef __attribute__((ext_vector_type(4))) float f32x4;    // MFMA acc

#define MFMA16(a, b, c) __builtin_amdgcn_mfma_f32_16x16x32_bf16(a, b, c, 0, 0, 0)

// fast silu: v_exp_f32 + v_rcp_f32 (~5 inst vs ~25 for libm expf + div).
// Feeds bf16 P values — bf16 rounding (2^-8) dominates native-exp err (2^-20).
__device__ __forceinline__ float silu(float x) {
    return x * __builtin_amdgcn_rcpf(1.f + __expf(-x));
}
__device__ __forceinline__ float sigmoid_fast(float x) {
    return __builtin_amdgcn_rcpf(1.f + __expf(-x));
}
__device__ __forceinline__ unsigned short f2bf(float x) {
    return __builtin_bit_cast(unsigned short, __float2bfloat16(x));
}
__device__ __forceinline__ float bfup(unsigned short b) {
    unsigned u = (unsigned)b << 16;
    return __builtin_bit_cast(float, u);
}
// 3-term bf16 split: x ~= b0 + b1 + b2 with |err| ~ 2^-27 |x|
__device__ __forceinline__ void split3(float x, unsigned short& b0,
                                       unsigned short& b1, unsigned short& b2) {
    b0 = f2bf(x);
    float r1 = x - bfup(b0);
    b1 = f2bf(r1);
    float r2 = r1 - bfup(b1);
    b2 = f2bf(r2);
}

// ---------------------------------------------------------------------------
// K1 prep: per (b,h,nt) 32-token block:
//   - kb16[tok][h][d]   : bf16 copy of K (straight convert, coalesced)
//   - vt_blk[bh][nt][d][j]: bf16 V^T in 8KB contiguous blocks (LDS transpose)
//   - g[b,m,h,{0,1}]    : gates (8-lane reduction, lanes share (tok,h))
//   - kc0/1/2[bh][nt][d]: split3 bf16 planes of the K block-mean
//   - vt_cmp[bh][d][nt] : bf16 V block-mean, transposed
//   - FUSED: qp/kp padded outputs + o_slc_j zeroing (only nt>=8 — rows in
//     single-chunk mtiles get plain stores from slc, no zero needed)
// Invalid blocks (nt*BS >= len) zero kc/vt_cmp slots and their qp/kp slices.
// All lengths are multiples of 64, so valid blocks are fully valid.
// ---------------------------------------------------------------------------
__global__ __launch_bounds__(256) void prep_kernel(
    const float* __restrict__ q, const float* __restrict__ k,
    const float* __restrict__ v, const float* __restrict__ Wg,
    const float* __restrict__ bg, const int* __restrict__ offs,
    unsigned short* __restrict__ kb16, unsigned short* __restrict__ vt_blk,
    float* __restrict__ g, unsigned short* __restrict__ kc0,
    unsigned short* __restrict__ kc1, unsigned short* __restrict__ kc2,
    unsigned short* __restrict__ vt_cmp, float* __restrict__ o_slc,
    float* __restrict__ qp, float* __restrict__ kp) {
    int x = blockIdx.x;
    int nt = x & (NB - 1);
    int h = (x >> 5) & 7;
    int b = x >> 8;
    int o0 = offs[b];
    int len = offs[b + 1] - o0;
    int tid = threadIdx.x;
    size_t bh = (size_t)(b * H + h);
    int j = tid >> 3, dc = tid & 7;
    size_t pbase = (size_t)((b * NMAX + nt * BS + j)) * HD + h * D + dc * 16;
    if (nt * BS >= len) {
        if (tid < 128) {
            kc0[(bh * NB + nt) * 128 + tid] = 0;
            kc1[(bh * NB + nt) * 128 + tid] = 0;
            kc2[(bh * NB + nt) * 128 + tid] = 0;
            vt_cmp[(bh * 128 + tid) * NB + nt] = 0;
        }
        if (qp) {                       // zero padding region of qp/kp
            float4 z = make_float4(0.f, 0.f, 0.f, 0.f);
#pragma unroll
            for (int i = 0; i < 4; i++) {
                *(float4*)(qp + pbase + i * 4) = z;
                *(float4*)(kp + pbase + i * 4) = z;
            }
        }
        return;
    }

    __shared__ __align__(16) unsigned short tile[128 * 40];
    __shared__ float redK[4][128];
    __shared__ float redV[4][128];
    int w = tid >> 6, lane = tid & 63;
    size_t base = (size_t)(o0 + nt * BS + j) * HD + h * D + dc * 16;

    // zero this token/head slice of o_slc — ONLY rows that slc atomically
    // accumulates into (multi-chunk mtiles, nt >= 8; nt < 8 gets plain store)
    if (nt >= 8) {
        float4 z = make_float4(0.f, 0.f, 0.f, 0.f);
#pragma unroll
        for (int i = 0; i < 4; i++) *(float4*)(o_slc + base + i * 4) = z;
    }

    // K -> kb16 (bf16) + kp (fused pad) + block-mean partial
    {
        float xv[16];
        *(float4*)(xv + 0)  = *(const float4*)(k + base);
        *(float4*)(xv + 4)  = *(const float4*)(k + base + 4);
        *(float4*)(xv + 8)  = *(const float4*)(k + base + 8);
        *(float4*)(xv + 12) = *(const float4*)(k + base + 12);
        short8 lo, hi;
#pragma unroll
        for (int i = 0; i < 8; i++) { lo[i] = (short)f2bf(xv[i]); hi[i] = (short)f2bf(xv[8 + i]); }
        *(short8*)(kb16 + base) = lo;
        *(short8*)(kb16 + base + 8) = hi;
        if (kp) {
#pragma unroll
            for (int i = 0; i < 4; i++) *(float4*)(kp + pbase + i * 4) = *(float4*)(xv + i * 4);
        }
        // butterfly over the wave's 8 j-lanes (lane bits 3,4,5)
#pragma unroll
        for (int i = 0; i < 16; i++) {
            float s = xv[i];
            s += __shfl_xor(s, 8); s += __shfl_xor(s, 16); s += __shfl_xor(s, 32);
            if (lane < 8) redK[w][lane * 16 + i] = s;
        }
    }
    // V -> LDS transpose tile[d][j] + block-mean partial
    {
        float xv[16];
        *(float4*)(xv + 0)  = *(const float4*)(v + base);
        *(float4*)(xv + 4)  = *(const float4*)(v + base + 4);
        *(float4*)(xv + 8)  = *(const float4*)(v + base + 8);
        *(float4*)(xv + 12) = *(const float4*)(v + base + 12);
#pragma unroll
        for (int i = 0; i < 16; i++) tile[(dc * 16 + i) * 40 + j] = f2bf(xv[i]);
#pragma unroll
        for (int i = 0; i < 16; i++) {
            float s = xv[i];
            s += __shfl_xor(s, 8); s += __shfl_xor(s, 16); s += __shfl_xor(s, 32);
            if (lane < 8) redV[w][lane * 16 + i] = s;
        }
    }
    // gates (dot over this thread's 16 dims) + qp (fused pad)
    {
        float xv[16];
        *(float4*)(xv + 0)  = *(const float4*)(q + base);
        *(float4*)(xv + 4)  = *(const float4*)(q + base + 4);
        *(float4*)(xv + 8)  = *(const float4*)(q + base + 8);
        *(float4*)(xv + 12) = *(const float4*)(q + base + 12);
        if (qp) {
#pragma unroll
            for (int i = 0; i < 4; i++) *(float4*)(qp + pbase + i * 4) = *(float4*)(xv + i * 4);
        }
        float p0 = 0.f, p1 = 0.f;
#pragma unroll
        for (int i = 0; i < 16; i++) {
            int wb = (h * D + dc * 16 + i) * 3;
            p0 += xv[i] * Wg[wb + 0];
            p1 += xv[i] * Wg[wb + 1];
        }
#pragma unroll
        for (int off = 4; off > 0; off >>= 1) {
            p0 += __shfl_xor(p0, off);
            p1 += __shfl_xor(p1, off);
        }
        if (dc == 0) {
            float g0 = sigmoid_fast(p0 + bg[h * 3 + 0]);
            float g1 = sigmoid_fast(p1 + bg[h * 3 + 1]);
            float* gp = g + (size_t)((b * NMAX + nt * BS + j) * H + h) * 2;
            gp[0] = g0; gp[1] = g1;
        }
    }
    __syncthreads();
    // tile -> vt_blk (contiguous 8KB per (bh,nt))
    {
        int d = tid >> 1, hf = tid & 1;
        short8 a = *(const short8*)(tile + d * 40 + hf * 16);
        short8 c = *(const short8*)(tile + d * 40 + hf * 16 + 8);
        size_t ob = ((bh * NB + nt) * 128 + (size_t)d) * 32 + hf * 16;
        *(short8*)(vt_blk + ob) = a;
        *(short8*)(vt_blk + ob + 8) = c;
    }
    // means -> kc planes / vt_cmp
    if (tid < 128) {
        int d = tid;
        const float inv = 1.f / 32.f;
        float km = (redK[0][d] + redK[1][d] + redK[2][d] + redK[3][d]) * inv;
        float vm = (redV[0][d] + redV[1][d] + redV[2][d] + redV[3][d]) * inv;
        unsigned short e0, e1, e2;
        split3(km, e0, e1, e2);
        kc0[(bh * NB + nt) * 128 + d] = e0;
        kc1[(bh * NB + nt) * 128 + d] = e1;
        kc2[(bh * NB + nt) * 128 + d] = e2;
        vt_cmp[(bh * 128 + d) * NB + nt] = f2bf(vm);
    }
}

// ---------------------------------------------------------------------------
// K3a: compressed attention + top-8 selection, 64-ROW tile (2 qblks) per WG,
// fully WAVE-LOCAL (slc-proven shape, r9-verified). Wave w owns rows
// [16w,16w+16); selection in registers via 15 shfl_xor + 2 ballots; one
// barrier per block. qblk dispatch LPT-reversed.
// MFMA layouts (m89/m120): A[m=lane&15][k=quad*8+j]; C/D col=lane&15,
// row=quad*4+reg.
// ---------------------------------------------------------------------------
__global__ __launch_bounds__(256) void cmp_attn(
    const float* __restrict__ q, const unsigned short* __restrict__ kc0,
    const unsigned short* __restrict__ kc1, const unsigned short* __restrict__ kc2,
    const unsigned short* __restrict__ vt_cmp, const float* __restrict__ g,
    const int* __restrict__ offs, unsigned* __restrict__ ms_g,
    float* __restrict__ o_cmp_j) {
    int x = blockIdx.x;                 // (b*H + h)*16 + qtile_idx
    int qtile = 15 - (x & 15);          // reversed: long blocks dispatch first
    int h = (x >> 4) & 7;
    int b = x >> 7;
    int o0 = offs[b];
    int len = offs[b + 1] - o0;
    if (qtile * 64 >= len) return;
    size_t bh = (size_t)(b * H + h);
    int qmax = 2 * qtile + 1;           // last causal kc block for this tile

    // pool: R0/R1/R2 kc planes (32x136), R3 vt_cmp^T (128x40), Ps (64x40)
    __shared__ __align__(16) unsigned short pool[3 * 4352 + 5120 + 2560];
    unsigned short* R0 = pool;            // 4352
    unsigned short* R1 = pool + 4352;     // 4352
    unsigned short* R2 = pool + 8704;     // 4352
    unsigned short* R3 = pool + 13056;    // 5120
    unsigned short* Ps = pool + 18176;    // 2560 (64x40)

    int tid = threadIdx.x;
    int w = tid >> 6, lane = tid & 63;
    int r = lane & 15, quad = lane >> 4;
    int stg_j = tid >> 3, stg_dc = tid & 7;
    size_t msbase = (bh << 10) + (size_t)qtile * 64;

    // ---- stage kc planes (causal rows only) + vt_cmp ----
    if (stg_j <= qmax) {
        size_t src = (bh * NB + stg_j) * 128 + stg_dc * 16;
        int ofs = stg_j * 136 + stg_dc * 16;
        short8 a0 = *(const short8*)(kc0 + src);
        short8 b0 = *(const short8*)(kc0 + src + 8);
        short8 a1 = *(const short8*)(kc1 + src);
        short8 b1 = *(const short8*)(kc1 + src + 8);
        short8 a2 = *(const short8*)(kc2 + src);
        short8 b2 = *(const short8*)(kc2 + src + 8);
        *(short8*)(R0 + ofs) = a0; *(short8*)(R0 + ofs + 8) = b0;
        *(short8*)(R1 + ofs) = a1; *(short8*)(R1 + ofs + 8) = b1;
        *(short8*)(R2 + ofs) = a2; *(short8*)(R2 + ofs + 8) = b2;
    }
    {
        int d = tid >> 1, hf = tid & 1;
        short8 vv = *(const short8*)(vt_cmp + (bh * 128 + d) * NB + hf * 16);
        short8 vw = *(const short8*)(vt_cmp + (bh * 128 + d) * NB + hf * 16 + 8);
        *(short8*)(R3 + d * 40 + hf * 16) = vv;
        *(short8*)(R3 + d * 40 + hf * 16 + 8) = vw;
    }
    __syncthreads();                    // the only barrier

    // ---- Q fragments (3 planes) for OWN rows ----
    short8 qf0[4], qf1[4], qf2[4];
    {
        const float* qrow = q + (size_t)(o0 + qtile * 64 + w * 16 + r) * HD + h * D;
#pragma unroll
        for (int s = 0; s < 4; s++) {
            const float* p0 = qrow + s * 32 + quad * 8;
            float xv[8];
            *(float4*)(xv) = *(const float4*)p0;
            *(float4*)(xv + 4) = *(const float4*)(p0 + 4);
            short8 f0, f1, f2;
#pragma unroll
            for (int i = 0; i < 8; i++) {
                unsigned short e0, e1, e2;
                split3(xv[i], e0, e1, e2);
                f0[i] = (short)e0; f1[i] = (short)e1; f2[i] = (short)e2;
            }
            qf0[s] = f0; qf1[s] = f1; qf2[s] = f2;
        }
    }
    // ---- QK (6 product rounds, small terms first), per j-frag ----
    auto qk6 = [&](int krow) {
        f32x4 sv = (f32x4){0.f, 0.f, 0.f, 0.f};
#pragma unroll
        for (int s = 0; s < 4; s++) {
            int ofs = krow * 136 + s * 32 + quad * 8;
            short8 k0 = *(const short8*)(R0 + ofs);
            short8 k1 = *(const short8*)(R1 + ofs);
            short8 k2 = *(const short8*)(R2 + ofs);
            sv = MFMA16(qf1[s], k1, sv);
            sv = MFMA16(qf0[s], k2, sv);
            sv = MFMA16(qf2[s], k0, sv);
            sv = MFMA16(qf0[s], k1, sv);
            sv = MFMA16(qf1[s], k0, sv);
            sv = MFMA16(qf0[s], k0, sv);
        }
        return sv;
    };
    f32x4 s0 = qk6(r);
    f32x4 s1 = (f32x4){0.f, 0.f, 0.f, 0.f};
    if (qtile >= 8) s1 = qk6(16 + r);   // cols 16-31 all non-causal otherwise

    // ---- mask + silu -> own Ps rows; raw scores kept in regs for selection
    float v0[4], v1[4];
#pragma unroll
    for (int jf = 0; jf < 2; jf++) {
        f32x4 svv = jf ? s1 : s0;
        int colj = jf * 16 + r;
#pragma unroll
        for (int i = 0; i < 4; i++) {
            int mrow = w * 16 + quad * 4 + i;
            int qb = 2 * qtile + (mrow >> 5);
            bool causal = (colj <= qb);
            float sc = svv[i] * SCALE;
            float val = causal ? sc : SENT;
            if (jf) v1[i] = val; else v0[i] = val;
            Ps[mrow * 40 + colj] = f2bf(causal ? silu(sc) : 0.f);
        }
    }
    // ---- selection -> ms_g ----
    if (qtile < 4) {                    // both qblks < S_SEL: trivial masks
        if (tid < 64)
            ms_g[msbase + tid] = (1u << (2 * qtile + (tid >> 5) + 1)) - 1u;
    } else {                            // rank in registers + ballot
#pragma unroll
        for (int i = 0; i < 4; i++) {
            float a = v0[i], bb = v1[i];
            int cnt0 = (bb > a) ? 1 : 0;          // (16+r) beats r only if strictly greater
            int cnt1 = (a >= bb) ? 1 : 0;         // r beats 16+r on ties
#pragma unroll
            for (int m = 1; m < 16; m++) {
                float pa = __shfl_xor(a, m);      // stays in 16-lane quad-group
                float pb = __shfl_xor(bb, m);
                int pc = r ^ m;
                cnt0 += ((pa > a) || (pa == a && pc < r)) ? 1 : 0;
                cnt0 += (pb > a) ? 1 : 0;         // col 16+pc > r: no tie count
                cnt1 += ((pa > bb) || (pa == bb)) ? 1 : 0;   // pc < 16+r always
                cnt1 += ((pb > bb) || (pb == bb && pc < r)) ? 1 : 0;
            }
            bool sel0 = (cnt0 < S_SEL) && (a > -2.9e38f);
            bool sel1 = (cnt1 < S_SEL) && (bb > -2.9e38f);
            unsigned long long bal0 = __ballot(sel0);
            unsigned long long bal1 = __ballot(sel1);
            unsigned mask = (unsigned)((bal0 >> (16 * quad)) & 0xFFFFull)
                          | ((unsigned)((bal1 >> (16 * quad)) & 0xFFFFull) << 16);
            if (r == 0) ms_g[msbase + w * 16 + quad * 4 + i] = mask;
        }
    }
    // ---- PV -> o_cmp (wave-local: A = own P rows, B = 8 d-frags) ----
    f32x4 acc[8];
#pragma unroll
    for (int a = 0; a < 8; a++) acc[a] = (f32x4){0.f, 0.f, 0.f, 0.f};
    {
        short8 pf8 = *(const short8*)(Ps + (w * 16 + r) * 40 + quad * 8);
#pragma unroll
        for (int nf = 0; nf < 8; nf++) {
            short8 vf = *(const short8*)(R3 + (nf * 16 + r) * 40 + quad * 8);
            acc[nf] = MFMA16(pf8, vf, acc[nf]);
        }
    }
    // ---- epilogue o_cmp ----
#pragma unroll
    for (int i = 0; i < 4; i++) {
        int mrow = w * 16 + quad * 4 + i;
        int gm = qtile * 64 + mrow;
        float gc = g[(size_t)((b * NMAX + gm) * H + h) * 2];
        float* dst = o_cmp_j + (size_t)(o0 + gm) * HD + h * D;
#pragma unroll
        for (int nf = 0; nf < 8; nf++)
            dst[nf * 16 + r] = acc[nf][i] * gc;
    }
}

// ---------------------------------------------------------------------------
// K3b: selected attention — r12 dim-split structure + hot-loop VALU cuts:
// r12 counters (VALUBusy 24.5% = 3x MfmaUtil) showed the mask+silu+Ps block
// dominates the iteration. This round: (1) Ms preloaded into 4 registers
// (removes per-iteration ds_reads), (2) Q pre-scaled by SCALE at fragment
// build (removes 8 v_mul/iter/thread; silu applied to raw MFMA output).
// Else identical to r12: block=(b,h,mtile,chunk,dhalf); full QK scores,
// PV+epilogue for 64 of 128 dims; K+V double-buffered LDS, register
// prefetch one FULL iteration ahead, single barrier/iter, wave-local PV,
// KP=136, LPT, XCD-aware mapping. fp32 partials -> atomicAdd into
// pre-zeroed o_slc_j (plain store for single-chunk tiles).
// ---------------------------------------------------------------------------
__global__ __launch_bounds__(256) void slc_attn(
    const float* __restrict__ q, const unsigned short* __restrict__ kb16,
    const unsigned short* __restrict__ vt_blk, const float* __restrict__ g,
    const int* __restrict__ offs, const unsigned* __restrict__ ms_g,
    float* __restrict__ o_slc_j) {
    int x = blockIdx.x;                 // grid = B*H*16*MC*2, XCD-grouped
    int xcd = x & (NXCD - 1);
    int rest = x >> 3;
    int group = rest >> 7;              // 128 = 16 mtiles * MC chunks * 2 dhalf
    int inner = rest & 127;
    int bh = group * NXCD + xcd;        // all 128 blocks of bh on one XCD
    int b = bh >> 3, h = bh & 7;
    int dhalf = inner & 1;
    int chunk = (inner >> 1) & (MC - 1);
    int mtile = 15 - (inner >> 3);      // LPT: longest blocks dispatch first
    int o0 = offs[b];
    int len = offs[b + 1] - o0;
    if (mtile * 64 >= len) return;      // uniform exit (lens are multiples of 64)
    int qmax = 2 * mtile + 1;
    int kb0 = chunk * CHUNK;
    if (kb0 > qmax) return;
    int kend = min(qmax, kb0 + CHUNK - 1);

    // pool: Kbuf0|Kbuf1 (32xKP) | VTbuf0|VTbuf1 (64x40) | Ps (64x40) = ~33KB
    __shared__ __align__(16) unsigned short pool[2 * 32 * KP + 2 * 2560 + 2560];
    __shared__ unsigned Ms[64];
    unsigned short* Kst0 = pool;                      // 4352
    unsigned short* Kst1 = pool + 32 * KP;            // 4352
    unsigned short* Vst0 = pool + 2 * 32 * KP;        // 2560
    unsigned short* Vst1 = pool + 2 * 32 * KP + 2560; // 2560
    unsigned short* Ps   = pool + 2 * 32 * KP + 5120; // 2560

    int tid = threadIdx.x;
    int w = tid >> 6, lane = tid & 63;
    int r = lane & 15, quad = lane >> 4;
    int stg_j = tid >> 3, stg_dc = tid & 7;

    if (tid < 64)
        Ms[tid] = ms_g[((size_t)bh << 10) + mtile * 64 + tid];

    // Q fragments (plane 0), PRE-SCALED by SCALE: wave w -> rows 16w + r
    short8 qs[4];
    {
        const float* qrow = q + (size_t)(o0 + mtile * 64 + w * 16 + r) * HD + h * D;
#pragma unroll
        for (int s = 0; s < 4; s++) {
            const float* p0 = qrow + s * 32 + quad * 8;
            float xv[8];
            *(float4*)(xv) = *(const float4*)p0;
            *(float4*)(xv + 4) = *(const float4*)(p0 + 4);
            short8 f;
#pragma unroll
            for (int i = 0; i < 8; i++) f[i] = (short)f2bf(xv[i] * SCALE);
            qs[s] = f;
        }
    }
    f32x4 acc[4];                       // wave-local: own rows, 64 of 128 dims
#pragma unroll
    for (int a = 0; a < 4; a++) acc[a] = (f32x4){0.f, 0.f, 0.f, 0.f};

    size_t vtbase = (size_t)(bh * NB) * 4096 + dhalf * 2048;  // this block's 64 d-rows
    int vd = tid >> 2, vq = tid & 3;    // 64 rows x 4 threads x 8 shorts

    // prestage kb0 into Kst0 / Vst0
    {
        const unsigned short* ks = kb16 + (size_t)(o0 + kb0 * BS + stg_j) * HD + h * D + stg_dc * 16;
        short8 k0 = *(const short8*)ks;
        short8 k1 = *(const short8*)(ks + 8);
        *(short8*)(Kst0 + stg_j * KP + stg_dc * 16) = k0;
        *(short8*)(Kst0 + stg_j * KP + stg_dc * 16 + 8) = k1;
        short8 v0 = *(const short8*)(vt_blk + vtbase + (size_t)kb0 * 4096 + vd * 32 + vq * 8);
        *(short8*)(Vst0 + vd * 40 + vq * 8) = v0;
    }
    __syncthreads();

    // Ms -> registers (own rows: mrow = w*16 + quad*4 + i)
    unsigned msr[4];
#pragma unroll
    for (int i = 0; i < 4; i++) msr[i] = Ms[w * 16 + quad * 4 + i];

    int c = 0;
    for (int kb = kb0; kb <= kend; kb++) {
        short8 pk0, pk1, pv0;
        bool pf = (kb < kend);
        if (pf) {                       // prefetch kb+1 into registers
            const unsigned short* ks = kb16 + (size_t)(o0 + (kb + 1) * BS + stg_j) * HD + h * D + stg_dc * 16;
            pk0 = *(const short8*)ks;
            pk1 = *(const short8*)(ks + 8);
            pv0 = *(const short8*)(vt_blk + vtbase + (size_t)(kb + 1) * 4096 + vd * 32 + vq * 8);
        }
        // QK: wave w -> rows [16w,16w+16), both j-frags (FULL scores)
        unsigned short* K = c ? Kst1 : Kst0;
        unsigned short* V = c ? Vst1 : Vst0;
        f32x4 s0 = (f32x4){0.f, 0.f, 0.f, 0.f};
        f32x4 s1 = (f32x4){0.f, 0.f, 0.f, 0.f};
#pragma unroll
        for (int s = 0; s < 4; s++) {
            short8 kf0 = *(const short8*)(K + r * KP + s * 32 + quad * 8);
            short8 kf1 = *(const short8*)(K + (16 + r) * KP + s * 32 + quad * 8);
            s0 = MFMA16(qs[s], kf0, s0);
            s1 = MFMA16(qs[s], kf1, s1);
        }
        // mask + silu -> OWN Ps slice (rows 16w..16w+15; wave-local).
        // Scores are already scaled (Q pre-scaled); Ms in registers.
#pragma unroll
        for (int jf = 0; jf < 2; jf++) {
            f32x4 svv = jf ? s1 : s0;
            int colj = jf * 16 + r;
            int kpos = kb * BS + colj;
#pragma unroll
            for (int i = 0; i < 4; i++) {
                int mrow = w * 16 + quad * 4 + i;
                int mpos = mtile * 64 + mrow;
                float p = (((msr[i] >> kb) & 1u) && (kpos <= mpos))
                          ? silu(svv[i]) : 0.f;
                Ps[mrow * 40 + colj] = f2bf(p);
            }
        }
        // PV: A = own P slice, B = 4 V^T d-frags (this block's 64 dims)
        {
            short8 pf8 = *(const short8*)(Ps + (w * 16 + r) * 40 + quad * 8);
#pragma unroll
            for (int nf = 0; nf < 4; nf++) {
                short8 vf = *(const short8*)(V + (nf * 16 + r) * 40 + quad * 8);
                acc[nf] = MFMA16(pf8, vf, acc[nf]);
            }
        }
        if (pf) {                       // commit prefetch into the other buffer
            unsigned short* Kn = c ? Kst0 : Kst1;
            unsigned short* Vn = c ? Vst0 : Vst1;
            *(short8*)(Kn + stg_j * KP + stg_dc * 16) = pk0;
            *(short8*)(Kn + stg_j * KP + stg_dc * 16 + 8) = pk1;
            *(short8*)(Vn + vd * 40 + vq * 8) = pv0;
        }
        __syncthreads();                // single barrier per iteration
        c ^= 1;
    }

    // epilogue: wave w writes its rows [16w,16w+16), this block's 64 dims
    bool single = (qmax < CHUNK);
#pragma unroll
    for (int i = 0; i < 4; i++) {
        int mrow = w * 16 + quad * 4 + i;
        int gm = mtile * 64 + mrow;
        float gs = g[(size_t)((b * NMAX + gm) * H + h) * 2 + 1];
        float* dst = o_slc_j + (size_t)(o0 + gm) * HD + h * D + dhalf * 64;
#pragma unroll
        for (int nf = 0; nf < 4; nf++) {
            float v0 = acc[nf][i] * gs;
            if (single) dst[nf * 16 + r] = v0;
            else        atomicAdd(dst + nf * 16 + r, v0);
        }
    }
}

// ---------------------------------------------------------------------------
// K4 (FALLBACK only — used when ws can't hold bf16 scratch and it aliases
// kp): padded qp, kp. Runs AFTER attention.
// ---------------------------------------------------------------------------
__global__ __launch_bounds__(256) void pad_qk_kernel(
    const float* __restrict__ q, const float* __restrict__ k,
    const int* __restrict__ offs,
    float* __restrict__ qp, float* __restrict__ kp) {
    int idx = blockIdx.x * 256 + threadIdx.x;       // float4 index over [B,n,H,D/4]
    int d4 = idx & 31;
    int h  = (idx >> 5) & 7;
    int m  = (idx >> 8) & (NMAX - 1);
    int b  = idx >> 18;
    int o0 = offs[b];
    int len = offs[b + 1] - o0;
    float4 qv = make_float4(0.f, 0.f, 0.f, 0.f);
    float4 kv = qv;
    if (m < len) {
        size_t src = (size_t)(o0 + m) * HD + h * D + d4 * 4;
        qv = *(const float4*)(q + src);
        kv = *(const float4*)(k + src);
    }
    *(float4*)(qp + (size_t)idx * 4) = qv;
    *(float4*)(kp + (size_t)idx * 4) = kv;
}

// ---------------------------------------------------------------------------
// K5: LayerNorm(1024) per stream, gate by u, sum -> out (oc may alias out)
// ---------------------------------------------------------------------------
__global__ __launch_bounds__(256) void ln_combine_kernel(
    const float* __restrict__ oc, const float* __restrict__ os,
    const float* __restrict__ u, float* __restrict__ out) {
    int t = blockIdx.x, tid = threadIdx.x;
    size_t base = (size_t)t * HD;
    float4 xc = *(const float4*)(oc + base + tid * 4);
    float4 xs = *(const float4*)(os + base + tid * 4);
    float4 uu = *(const float4*)(u + base + tid * 4);
    float s_c = xc.x + xc.y + xc.z + xc.w;
    float q_c = xc.x * xc.x + xc.y * xc.y + xc.z * xc.z + xc.w * xc.w;
    float s_s = xs.x + xs.y + xs.z + xs.w;
    float q_s = xs.x * xs.x + xs.y * xs.y + xs.z * xs.z + xs.w * xs.w;
#pragma unroll
    for (int off = 32; off > 0; off >>= 1) {
        s_c += __shfl_xor(s_c, off); q_c += __shfl_xor(q_c, off);
        s_s += __shfl_xor(s_s, off); q_s += __shfl_xor(q_s, off);
    }
    __shared__ float red[4][4];
    int w = tid >> 6, lane = tid & 63;
    if (lane == 0) {
        red[w][0] = s_c; red[w][1] = q_c; red[w][2] = s_s; red[w][3] = q_s;
    }
    __syncthreads();
    float tsc = red[0][0] + red[1][0] + red[2][0] + red[3][0];
    float tqc = red[0][1] + red[1][1] + red[2][1] + red[3][1];
    float tss = red[0][2] + red[1][2] + red[2][2] + red[3][2];
    float tqs = red[0][3] + red[1][3] + red[2][3] + red[3][3];
    const float inv = 1.f / 1024.f;
    float mc = tsc * inv, vc = tqc * inv - mc * mc;
    float ms = tss * inv, vs = tqs * inv - ms * ms;
    float rc = rsqrtf(vc + 1e-5f), rs = rsqrtf(vs + 1e-5f);
    float4 o;
    o.x = ((xc.x - mc) * rc + (xs.x - ms) * rs) * uu.x;
    o.y = ((xc.y - mc) * rc + (xs.y - ms) * rs) * uu.y;
    o.z = ((xc.z - mc) * rc + (xs.z - ms) * rs) * uu.z;
    o.w = ((xc.w - mc) * rc + (xs.w - ms) * rs) * uu.w;
    *(float4*)(out + base + tid * 4) = o;
}

// ---------------------------------------------------------------------------
extern "C" void kernel_launch(void* const* d_in, const int* in_sizes, int n_in,
                              void* d_out, int out_size, void* d_ws, size_t ws_size,
                              hipStream_t stream) {
    const float* q  = (const float*)d_in[0];
    const float* k  = (const float*)d_in[1];
    const float* v  = (const float*)d_in[2];
    const float* u  = (const float*)d_in[3];
    const float* Wg = (const float*)d_in[4];
    const float* bg = (const float*)d_in[5];
    const int* offs = (const int*)d_in[6];   // int32 (jnp default, x64 off)

    int B = in_sizes[6] - 1;
    int T = in_sizes[0] / HD;

    float* out = (float*)d_out;
    float* qp  = out + (size_t)T * HD;
    float* kp  = qp + (size_t)B * NMAX * HD;

    float* o_cmp_j = out;   // aliases final out (safe: see ln_combine)

    size_t plane = (size_t)B * H * NB * 128;        // elems per kc plane
    char* w = (char*)d_ws;
    unsigned short* kc0 = (unsigned short*)w;  w += plane * 2;
    unsigned short* kc1 = (unsigned short*)w;  w += plane * 2;
    unsigned short* kc2 = (unsigned short*)w;  w += plane * 2;
    unsigned short* vt_cmp = (unsigned short*)w; w += plane * 2;
    float* g     = (float*)w;            w += (size_t)B * NMAX * H * 2 * 4;
    unsigned* ms_g = (unsigned*)w;       w += (size_t)B * H * NMAX * 4;
    float* o_slc_j = (float*)w;          w += (size_t)T * HD * 4;

    // bf16 scratch: prefer ws tail (enables fused pad); else kp region
    size_t kb16_bytes = (size_t)T * HD * 2;
    size_t vt_bytes   = (size_t)B * H * NB * 128 * 32 * 2;
    size_t used = (size_t)(w - (char*)d_ws);
    bool fused_pad = (used + kb16_bytes + vt_bytes <= ws_size);
    char* scr = fused_pad ? w : (char*)kp;
    unsigned short* kb16  = (unsigned short*)scr;
    unsigned short* vt_blk = (unsigned short*)(scr + kb16_bytes);

    int prepBlocks = B * H * NB;
    int cmpAttnBlocks = B * H * 16;
    int slcBlocks  = B * H * 16 * MC * 2;
    int padBlocks  = (B * NMAX * HD / 4) / 256;

    prep_kernel<<<prepBlocks, 256, 0, stream>>>(q, k, v, Wg, bg, offs, kb16, vt_blk,
                                                g, kc0, kc1, kc2, vt_cmp, o_slc_j,
                                                fused_pad ? qp : nullptr,
                                                fused_pad ? kp : nullptr);
    cmp_attn<<<cmpAttnBlocks, 256, 0, stream>>>(q, kc0, kc1, kc2, vt_cmp, g,
                                                offs, ms_g, o_cmp_j);
    slc_attn<<<slcBlocks, 256, 0, stream>>>(q, kb16, vt_blk, g, offs, ms_g, o_slc_j);
    if (!fused_pad)
        pad_qk_kernel<<<padBlocks, 256, 0, stream>>>(q, k, offs, qp, kp);
    ln_combine_kernel<<<T, 256, 0, stream>>>(o_cmp_j, o_slc_j, u, out);
}